// Round 7
// baseline (418.754 us; speedup 1.0000x reference)
//
#include <hip/hip_runtime.h>
#include <hip/hip_bf16.h>
#include <hip/hip_fp16.h>

#define S_LEN  2048
#define BATCH  2
#define DMODEL 1024
#define NHEADS 16
#define HD     64
#define MROWS  4096   // S*B
#define LD     68     // K/V/P LDS stride: 34 dwords -> 4-way max bank aliasing

using f16 = _Float16;
typedef __attribute__((ext_vector_type(8))) _Float16 f16x8;
typedef __attribute__((ext_vector_type(4))) _Float16 f16x4;
typedef __attribute__((ext_vector_type(4))) float    f32x4;

// ---------------- RoPE cos/sin table: [S][16] ----------------
__global__ __launch_bounds__(256) void rope_table(float* __restrict__ rc, float* __restrict__ rs)
{
    int idx = blockIdx.x * 256 + threadIdx.x;   // S*16 threads
    int s = idx >> 4, i = idx & 15;
    float inv = powf(10000.0f, -(float)(2 * i) / 32.0f);
    float ang = (float)s * inv;
    rc[idx] = cosf(ang);
    rs[idx] = sinf(ang);
}

// ---------------- batched projection GEMM + bias + RoPE + head-split ----------------
// X, W are fp32 in global; converted to f16 during LDS staging.
// q scaled by (1/8)*log2(e) so attention scores live in the base-2 domain.
// q,k stored (B,H,S,hd); v stored transposed (B,H,hd,S)
__global__ __launch_bounds__(256) void proj_gemm(
    const float* __restrict__ Xq, const float* __restrict__ Xk, const float* __restrict__ Xv,
    const float* __restrict__ Wq, const float* __restrict__ Wk, const float* __restrict__ Wv,
    const float* __restrict__ bq, const float* __restrict__ bk, const float* __restrict__ bv,
    f16* __restrict__ qo, f16* __restrict__ ko, f16* __restrict__ vo,
    const float* __restrict__ rc, const float* __restrict__ rs)
{
    const int mode = blockIdx.z;            // 0=q 1=k 2=v
    const float* X    = (mode == 0) ? Xq : (mode == 1) ? Xk : Xv;
    const float* W    = (mode == 0) ? Wq : (mode == 1) ? Wk : Wv;
    const float* bias = (mode == 0) ? bq : (mode == 1) ? bk : bv;

    __shared__ f16 Al[128 * 40];   // stride 40 elems (80B): 2-way bank aliasing only (free)
    __shared__ f16 Bl[128 * 40];

    const int t = threadIdx.x;
    const int lane = t & 63, wid = t >> 6;
    const int wr = wid >> 1, wc = wid & 1;
    const int m0 = blockIdx.x * 128, n0 = blockIdx.y * 128;

    f32x4 acc[4][4];
    #pragma unroll
    for (int m = 0; m < 4; m++)
        #pragma unroll
        for (int n = 0; n < 4; n++)
            acc[m][n] = f32x4{0.f, 0.f, 0.f, 0.f};

    for (int k0 = 0; k0 < DMODEL; k0 += 32) {
        __syncthreads();
        #pragma unroll
        for (int i = 0; i < 2; i++) {
            int e = (i * 256 + t) * 8;       // elem index in 128x32 tile
            int r = e >> 5, c = e & 31;
            {
                const float* src = &X[(size_t)(m0 + r) * DMODEL + k0 + c];
                float4 v0 = *reinterpret_cast<const float4*>(src);
                float4 v1 = *reinterpret_cast<const float4*>(src + 4);
                f16x8 h = { (f16)v0.x, (f16)v0.y, (f16)v0.z, (f16)v0.w,
                            (f16)v1.x, (f16)v1.y, (f16)v1.z, (f16)v1.w };
                *reinterpret_cast<f16x8*>(&Al[r * 40 + c]) = h;
            }
            {
                const float* src = &W[(size_t)(n0 + r) * DMODEL + k0 + c];
                float4 v0 = *reinterpret_cast<const float4*>(src);
                float4 v1 = *reinterpret_cast<const float4*>(src + 4);
                f16x8 h = { (f16)v0.x, (f16)v0.y, (f16)v0.z, (f16)v0.w,
                            (f16)v1.x, (f16)v1.y, (f16)v1.z, (f16)v1.w };
                *reinterpret_cast<f16x8*>(&Bl[r * 40 + c]) = h;
            }
        }
        __syncthreads();
        f16x8 a[4], b[4];
        #pragma unroll
        for (int m = 0; m < 4; m++)
            a[m] = *reinterpret_cast<const f16x8*>(&Al[(wr * 64 + m * 16 + (lane & 15)) * 40 + (lane >> 4) * 8]);
        #pragma unroll
        for (int n = 0; n < 4; n++)
            b[n] = *reinterpret_cast<const f16x8*>(&Bl[(wc * 64 + n * 16 + (lane & 15)) * 40 + (lane >> 4) * 8]);
        #pragma unroll
        for (int m = 0; m < 4; m++)
            #pragma unroll
            for (int n = 0; n < 4; n++)
                acc[m][n] = __builtin_amdgcn_mfma_f32_16x16x32_f16(a[m], b[n], acc[m][n], 0, 0, 0);
    }

    const int rowb = m0 + wr * 64, colb = n0 + wc * 64;
    #pragma unroll
    for (int n = 0; n < 4; n++) {
        int cN = colb + n * 16 + (lane & 15);
        float bvv = bias[cN];
        int h = cN >> 6, d = cN & 63;
        #pragma unroll
        for (int m = 0; m < 4; m++) {
            #pragma unroll
            for (int rg = 0; rg < 4; rg++) {
                int r = rowb + m * 16 + (lane >> 4) * 4 + rg;
                int s = r >> 1, bi = r & 1;                 // row = s*B + b, B=2
                float val = acc[m][n][rg] + bvv;
                if (mode < 2) {
                    float pv = __shfl_xor(val, 1);          // partner col cN^1 == lane^1
                    if (d < 32) {
                        int fi = d >> 1;
                        float cc = rc[s * 16 + fi], ss = rs[s * 16 + fi];
                        val = ((d & 1) == 0) ? val * cc - pv * ss : val * cc + pv * ss;
                    }
                    if (mode == 0) val *= 0.18033688f;      // (1/8)*log2(e): base-2 softmax domain
                    ((mode == 0) ? qo : ko)[(((size_t)bi * NHEADS + h) * S_LEN + s) * HD + d] = (f16)val;
                } else {
                    vo[(((size_t)bi * NHEADS + h) * HD + d) * S_LEN + s] = (f16)val;
                }
            }
        }
    }
}

// ---------------- flash attention (swapped MFMA, double-buffered K/V) ----------------
// grid (S/64, B*H); 4 waves x 16 q-rows each.
// Per iter: issue next tile's global loads -> compute on cur buf -> ds_write next buf
// -> ONE barrier. Load latency hides under QK/softmax/PV.
__global__ __launch_bounds__(256) void attn_fwd(
    const f16* __restrict__ qb, const f16* __restrict__ kb,
    const f16* __restrict__ vt, f16* __restrict__ ctx)
{
    __shared__ f16 Kl[2][64 * LD];
    __shared__ f16 Vl[2][64 * LD];
    __shared__ f16 Pl[4 * 16 * LD];

    const int t = threadIdx.x, lane = t & 63, wid = t >> 6;
    const int q15 = lane & 15, g = lane >> 4;
    const int bh = blockIdx.y;
    const int q0 = blockIdx.x * 64 + wid * 16;

    // Q B-frag: lane holds Q[q15][g*8..+7] and +32
    const f16* qptr = qb + ((size_t)bh * S_LEN + q0) * HD;
    f16x8 qf0 = *reinterpret_cast<const f16x8*>(&qptr[q15 * HD + g * 8]);
    f16x8 qf1 = *reinterpret_cast<const f16x8*>(&qptr[q15 * HD + g * 8 + 32]);

    f32x4 ctxa[4];                          // [n][rg]: row d=16n+4g+rg, col q=q15
    #pragma unroll
    for (int i = 0; i < 4; i++) ctxa[i] = f32x4{0.f, 0.f, 0.f, 0.f};
    float mrun = -3.0e38f, lrun = 0.f;

    // staging map: 256 threads cover a 64x64 f16 tile with TWO 16B stores each
    const int r_st = t >> 2, c_st = (t & 3) * 16;
    const f16* kgb = kb + (size_t)bh * S_LEN * HD + (size_t)r_st * HD + c_st;
    const f16* vgb = vt + (size_t)bh * HD * S_LEN + (size_t)r_st * S_LEN + c_st;
    const int st_off = r_st * LD + c_st;
    f16* pbase = &Pl[wid * (16 * LD)];

    // prologue: tile 0 -> regs -> buf0
    uint4 kr0 = *reinterpret_cast<const uint4*>(kgb);
    uint4 kr1 = *reinterpret_cast<const uint4*>(kgb + 8);
    uint4 vr0 = *reinterpret_cast<const uint4*>(vgb);
    uint4 vr1 = *reinterpret_cast<const uint4*>(vgb + 8);
    *reinterpret_cast<uint4*>(&Kl[0][st_off])     = kr0;
    *reinterpret_cast<uint4*>(&Kl[0][st_off + 8]) = kr1;
    *reinterpret_cast<uint4*>(&Vl[0][st_off])     = vr0;
    *reinterpret_cast<uint4*>(&Vl[0][st_off + 8]) = vr1;
    __syncthreads();
    int cur = 0;

    for (int kt = 0; kt < S_LEN / 64; kt++) {
        const bool pf = (kt + 1 < S_LEN / 64);
        if (pf) {                           // issue-early: next tile -> regs
            const f16* kp = kgb + (size_t)(kt + 1) * 64 * HD;
            const f16* vp = vgb + (size_t)(kt + 1) * 64;
            kr0 = *reinterpret_cast<const uint4*>(kp);
            kr1 = *reinterpret_cast<const uint4*>(kp + 8);
            vr0 = *reinterpret_cast<const uint4*>(vp);
            vr1 = *reinterpret_cast<const uint4*>(vp + 8);
        }
        const f16* Kc = Kl[cur];
        const f16* Vc = Vl[cur];

        // QK^T swapped: sc[f][rg] = score(k = kt*64+16f+4g+rg, q = q0+q15)
        f32x4 sc[4];
        #pragma unroll
        for (int f = 0; f < 4; f++) {
            f16x8 kf0 = *reinterpret_cast<const f16x8*>(&Kc[(f * 16 + q15) * LD + g * 8]);
            f16x8 kf1 = *reinterpret_cast<const f16x8*>(&Kc[(f * 16 + q15) * LD + g * 8 + 32]);
            f32x4 z = {0.f, 0.f, 0.f, 0.f};
            z = __builtin_amdgcn_mfma_f32_16x16x32_f16(kf0, qf0, z, 0, 0, 0);
            sc[f] = __builtin_amdgcn_mfma_f32_16x16x32_f16(kf1, qf1, z, 0, 0, 0);
        }

        // online softmax (base-2); all stats lane-local for q = q15
        float pmf[4];
        #pragma unroll
        for (int f = 0; f < 4; f++)
            pmf[f] = fmaxf(fmaxf(sc[f][0], sc[f][1]), fmaxf(sc[f][2], sc[f][3]));
        float pmax = fmaxf(fmaxf(pmf[0], pmf[1]), fmaxf(pmf[2], pmf[3]));
        pmax = fmaxf(pmax, __shfl_xor(pmax, 16));
        pmax = fmaxf(pmax, __shfl_xor(pmax, 32));
        float mnew = fmaxf(mrun, pmax);
        float scale = __builtin_amdgcn_exp2f(mrun - mnew);
        float tsum = 0.f;
        #pragma unroll
        for (int f = 0; f < 4; f++)
            #pragma unroll
            for (int rg = 0; rg < 4; rg++) {
                float p = __builtin_amdgcn_exp2f(sc[f][rg] - mnew);
                sc[f][rg] = p;
                tsum += p;
            }
        tsum += __shfl_xor(tsum, 16);
        tsum += __shfl_xor(tsum, 32);
        lrun = lrun * scale + tsum;
        mrun = mnew;
        #pragma unroll
        for (int n = 0; n < 4; n++) {
            ctxa[n][0] *= scale; ctxa[n][1] *= scale;
            ctxa[n][2] *= scale; ctxa[n][3] *= scale;
        }

        // P -> per-wave LDS: lane q15 owns row q, writes 4 contiguous k per f (b64)
        #pragma unroll
        for (int f = 0; f < 4; f++) {
            f16x4 pw = { (f16)sc[f][0], (f16)sc[f][1], (f16)sc[f][2], (f16)sc[f][3] };
            *reinterpret_cast<f16x4*>(&pbase[q15 * LD + f * 16 + g * 4]) = pw;
        }
        // same-wave visibility: drain LDS writes, pin ordering (no block barrier needed)
        asm volatile("s_waitcnt lgkmcnt(0)" ::: "memory");
        __builtin_amdgcn_sched_barrier(0);

        // PV swapped: ctx[d][q] += V^T[d][s] * P[q][s]
        #pragma unroll
        for (int c = 0; c < 2; c++) {
            f16x8 pfr = *reinterpret_cast<const f16x8*>(&pbase[q15 * LD + g * 8 + c * 32]);
            #pragma unroll
            for (int n = 0; n < 4; n++) {
                f16x8 vf = *reinterpret_cast<const f16x8*>(&Vc[(n * 16 + q15) * LD + g * 8 + c * 32]);
                ctxa[n] = __builtin_amdgcn_mfma_f32_16x16x32_f16(vf, pfr, ctxa[n], 0, 0, 0);
            }
        }

        if (pf) {                           // write-late: regs -> other buf, one barrier
            f16* kd = &Kl[cur ^ 1][st_off];
            f16* vd = &Vl[cur ^ 1][st_off];
            *reinterpret_cast<uint4*>(kd)     = kr0;
            *reinterpret_cast<uint4*>(kd + 8) = kr1;
            *reinterpret_cast<uint4*>(vd)     = vr0;
            *reinterpret_cast<uint4*>(vd + 8) = vr1;
            __syncthreads();
            cur ^= 1;
        }
    }

    // epilogue: lane-local 1/l, packed b64 stores (d = 16n+4g+rg contiguous in rg)
    const int bi = bh >> 4, h = bh & 15;
    const int s = q0 + q15;
    float inv = 1.0f / lrun;
    f16* outp = &ctx[((size_t)s * BATCH + bi) * DMODEL + h * HD];
    #pragma unroll
    for (int n = 0; n < 4; n++) {
        f16x4 o = { (f16)(ctxa[n][0] * inv), (f16)(ctxa[n][1] * inv),
                    (f16)(ctxa[n][2] * inv), (f16)(ctxa[n][3] * inv) };
        *reinterpret_cast<f16x4*>(&outp[n * 16 + g * 4]) = o;
    }
}

// ---------------- output projection: f16 X (ws), fp32 W (global), fp32 out ----------------
__global__ __launch_bounds__(256) void out_gemm(
    const f16* __restrict__ X, const float* __restrict__ W,
    const float* __restrict__ bias, float* __restrict__ out)
{
    __shared__ f16 Al[128 * 40];
    __shared__ f16 Bl[128 * 40];

    const int t = threadIdx.x;
    const int lane = t & 63, wid = t >> 6;
    const int wr = wid >> 1, wc = wid & 1;
    const int m0 = blockIdx.x * 128, n0 = blockIdx.y * 128;

    f32x4 acc[4][4];
    #pragma unroll
    for (int m = 0; m < 4; m++)
        #pragma unroll
        for (int n = 0; n < 4; n++)
            acc[m][n] = f32x4{0.f, 0.f, 0.f, 0.f};

    for (int k0 = 0; k0 < DMODEL; k0 += 32) {
        __syncthreads();
        #pragma unroll
        for (int i = 0; i < 2; i++) {
            int e = (i * 256 + t) * 8;
            int r = e >> 5, c = e & 31;
            *reinterpret_cast<uint4*>(&Al[r * 40 + c]) =
                *reinterpret_cast<const uint4*>(&X[(size_t)(m0 + r) * DMODEL + k0 + c]);
            {
                const float* src = &W[(size_t)(n0 + r) * DMODEL + k0 + c];
                float4 v0 = *reinterpret_cast<const float4*>(src);
                float4 v1 = *reinterpret_cast<const float4*>(src + 4);
                f16x8 h = { (f16)v0.x, (f16)v0.y, (f16)v0.z, (f16)v0.w,
                            (f16)v1.x, (f16)v1.y, (f16)v1.z, (f16)v1.w };
                *reinterpret_cast<f16x8*>(&Bl[r * 40 + c]) = h;
            }
        }
        __syncthreads();
        f16x8 a[4], b[4];
        #pragma unroll
        for (int m = 0; m < 4; m++)
            a[m] = *reinterpret_cast<const f16x8*>(&Al[(wr * 64 + m * 16 + (lane & 15)) * 40 + (lane >> 4) * 8]);
        #pragma unroll
        for (int n = 0; n < 4; n++)
            b[n] = *reinterpret_cast<const f16x8*>(&Bl[(wc * 64 + n * 16 + (lane & 15)) * 40 + (lane >> 4) * 8]);
        #pragma unroll
        for (int m = 0; m < 4; m++)
            #pragma unroll
            for (int n = 0; n < 4; n++)
                acc[m][n] = __builtin_amdgcn_mfma_f32_16x16x32_f16(a[m], b[n], acc[m][n], 0, 0, 0);
    }

    const int rowb = m0 + wr * 64, colb = n0 + wc * 64;
    #pragma unroll
    for (int n = 0; n < 4; n++) {
        int cN = colb + n * 16 + (lane & 15);
        float bvv = bias[cN];
        #pragma unroll
        for (int m = 0; m < 4; m++) {
            #pragma unroll
            for (int rg = 0; rg < 4; rg++) {
                int r = rowb + m * 16 + (lane >> 4) * 4 + rg;
                out[(size_t)r * DMODEL + cN] = acc[m][n][rg] + bvv;
            }
        }
    }
}

// ---------------- launch ----------------
extern "C" void kernel_launch(void* const* d_in, const int* in_sizes, int n_in,
                              void* d_out, int out_size, void* d_ws, size_t ws_size,
                              hipStream_t stream)
{
    const float* Q  = (const float*)d_in[0];
    const float* K  = (const float*)d_in[1];
    const float* V  = (const float*)d_in[2];
    const float* Wq = (const float*)d_in[3];
    const float* bq = (const float*)d_in[4];
    const float* Wk = (const float*)d_in[5];
    const float* bk = (const float*)d_in[6];
    const float* Wv = (const float*)d_in[7];
    const float* bv = (const float*)d_in[8];
    const float* Wo = (const float*)d_in[9];
    const float* bo = (const float*)d_in[10];
    float* out = (float*)d_out;

    // workspace layout (total 32.25 MiB):
    //   [0,128K)    rc    [128K,256K) rs
    //   [256K, +8M) qbuf  (B,H,S,hd) f16
    //   [+8M,+16M)  kbuf  (B,H,S,hd) f16
    //   [+16M,+24M) vtb   (B,H,hd,S) f16
    //   [+24M,+32M) ctxb  (S*B, D)   f16
    char* w = (char*)d_ws;
    const size_t szT = (size_t)S_LEN * 16 * sizeof(float);     // 128 KiB
    const size_t szQ = (size_t)MROWS * DMODEL * sizeof(f16);   // 8 MiB
    float* rc  = (float*)(w);
    float* rs  = (float*)(w + szT);
    f16* qbuf = (f16*)(w + 2 * szT);
    f16* kbuf = (f16*)(w + 2 * szT + szQ);
    f16* vtb  = (f16*)(w + 2 * szT + 2 * szQ);
    f16* ctxb = (f16*)(w + 2 * szT + 3 * szQ);

    rope_table<<<(S_LEN * 16) / 256, 256, 0, stream>>>(rc, rs);

    proj_gemm<<<dim3(MROWS / 128, DMODEL / 128, 3), 256, 0, stream>>>(
        Q, K, V, Wq, Wk, Wv, bq, bk, bv, qbuf, kbuf, vtb, rc, rs);

    attn_fwd<<<dim3(S_LEN / 64, BATCH * NHEADS), 256, 0, stream>>>(qbuf, kbuf, vtb, ctxb);

    out_gemm<<<dim3(MROWS / 128, DMODEL / 128), 256, 0, stream>>>(ctxb, Wo, bo, out);
}

// Round 8
// 239.337 us; speedup vs baseline: 1.7496x; 1.7496x over previous
//
#include <hip/hip_runtime.h>
#include <hip/hip_bf16.h>
#include <hip/hip_fp16.h>

#define S_LEN  2048
#define BATCH  2
#define DMODEL 1024
#define NHEADS 16
#define HD     64
#define MROWS  4096   // S*B
#define LD     68     // K/V/P LDS stride: 34 dwords -> measured 0 bank conflicts (r7)

using f16 = _Float16;
typedef __attribute__((ext_vector_type(8))) _Float16 f16x8;
typedef __attribute__((ext_vector_type(4))) _Float16 f16x4;
typedef __attribute__((ext_vector_type(4))) float    f32x4;

// ---------------- RoPE cos/sin table: [S][16] ----------------
__global__ __launch_bounds__(256) void rope_table(float* __restrict__ rc, float* __restrict__ rs)
{
    int idx = blockIdx.x * 256 + threadIdx.x;   // S*16 threads
    int s = idx >> 4, i = idx & 15;
    float inv = powf(10000.0f, -(float)(2 * i) / 32.0f);
    float ang = (float)s * inv;
    rc[idx] = cosf(ang);
    rs[idx] = sinf(ang);
}

// ---------------- batched projection GEMM + bias + RoPE + head-split ----------------
// X, W are fp32 in global; converted to f16 during LDS staging.
// q scaled by (1/8)*log2(e) so attention scores live in the base-2 domain.
// q,k stored (B,H,S,hd); v stored transposed (B,H,hd,S)
__global__ __launch_bounds__(256) void proj_gemm(
    const float* __restrict__ Xq, const float* __restrict__ Xk, const float* __restrict__ Xv,
    const float* __restrict__ Wq, const float* __restrict__ Wk, const float* __restrict__ Wv,
    const float* __restrict__ bq, const float* __restrict__ bk, const float* __restrict__ bv,
    f16* __restrict__ qo, f16* __restrict__ ko, f16* __restrict__ vo,
    const float* __restrict__ rc, const float* __restrict__ rs)
{
    const int mode = blockIdx.z;            // 0=q 1=k 2=v
    const float* X    = (mode == 0) ? Xq : (mode == 1) ? Xk : Xv;
    const float* W    = (mode == 0) ? Wq : (mode == 1) ? Wk : Wv;
    const float* bias = (mode == 0) ? bq : (mode == 1) ? bk : bv;

    __shared__ f16 Al[128 * 40];   // stride 40 elems (80B): 2-way bank aliasing only (free)
    __shared__ f16 Bl[128 * 40];

    const int t = threadIdx.x;
    const int lane = t & 63, wid = t >> 6;
    const int wr = wid >> 1, wc = wid & 1;
    const int m0 = blockIdx.x * 128, n0 = blockIdx.y * 128;

    f32x4 acc[4][4];
    #pragma unroll
    for (int m = 0; m < 4; m++)
        #pragma unroll
        for (int n = 0; n < 4; n++)
            acc[m][n] = f32x4{0.f, 0.f, 0.f, 0.f};

    for (int k0 = 0; k0 < DMODEL; k0 += 32) {
        __syncthreads();
        #pragma unroll
        for (int i = 0; i < 2; i++) {
            int e = (i * 256 + t) * 8;       // elem index in 128x32 tile
            int r = e >> 5, c = e & 31;
            {
                const float* src = &X[(size_t)(m0 + r) * DMODEL + k0 + c];
                float4 v0 = *reinterpret_cast<const float4*>(src);
                float4 v1 = *reinterpret_cast<const float4*>(src + 4);
                f16x8 h = { (f16)v0.x, (f16)v0.y, (f16)v0.z, (f16)v0.w,
                            (f16)v1.x, (f16)v1.y, (f16)v1.z, (f16)v1.w };
                *reinterpret_cast<f16x8*>(&Al[r * 40 + c]) = h;
            }
            {
                const float* src = &W[(size_t)(n0 + r) * DMODEL + k0 + c];
                float4 v0 = *reinterpret_cast<const float4*>(src);
                float4 v1 = *reinterpret_cast<const float4*>(src + 4);
                f16x8 h = { (f16)v0.x, (f16)v0.y, (f16)v0.z, (f16)v0.w,
                            (f16)v1.x, (f16)v1.y, (f16)v1.z, (f16)v1.w };
                *reinterpret_cast<f16x8*>(&Bl[r * 40 + c]) = h;
            }
        }
        __syncthreads();
        f16x8 a[4], b[4];
        #pragma unroll
        for (int m = 0; m < 4; m++)
            a[m] = *reinterpret_cast<const f16x8*>(&Al[(wr * 64 + m * 16 + (lane & 15)) * 40 + (lane >> 4) * 8]);
        #pragma unroll
        for (int n = 0; n < 4; n++)
            b[n] = *reinterpret_cast<const f16x8*>(&Bl[(wc * 64 + n * 16 + (lane & 15)) * 40 + (lane >> 4) * 8]);
        #pragma unroll
        for (int m = 0; m < 4; m++)
            #pragma unroll
            for (int n = 0; n < 4; n++)
                acc[m][n] = __builtin_amdgcn_mfma_f32_16x16x32_f16(a[m], b[n], acc[m][n], 0, 0, 0);
    }

    const int rowb = m0 + wr * 64, colb = n0 + wc * 64;
    #pragma unroll
    for (int n = 0; n < 4; n++) {
        int cN = colb + n * 16 + (lane & 15);
        float bvv = bias[cN];
        int h = cN >> 6, d = cN & 63;
        #pragma unroll
        for (int m = 0; m < 4; m++) {
            #pragma unroll
            for (int rg = 0; rg < 4; rg++) {
                int r = rowb + m * 16 + (lane >> 4) * 4 + rg;
                int s = r >> 1, bi = r & 1;                 // row = s*B + b, B=2
                float val = acc[m][n][rg] + bvv;
                if (mode < 2) {
                    float pv = __shfl_xor(val, 1);          // partner col cN^1 == lane^1
                    if (d < 32) {
                        int fi = d >> 1;
                        float cc = rc[s * 16 + fi], ss = rs[s * 16 + fi];
                        val = ((d & 1) == 0) ? val * cc - pv * ss : val * cc + pv * ss;
                    }
                    if (mode == 0) val *= 0.18033688f;      // (1/8)*log2(e): base-2 softmax domain
                    ((mode == 0) ? qo : ko)[(((size_t)bi * NHEADS + h) * S_LEN + s) * HD + d] = (f16)val;
                } else {
                    vo[(((size_t)bi * NHEADS + h) * HD + d) * S_LEN + s] = (f16)val;
                }
            }
        }
    }
}

// ---------------- flash attention (swapped-operand MFMA, r6 structure + LD=68) ----------------
// grid (S/64, B*H); 4 waves x 16 q-rows each.
// QK: mfma(K,Q) -> score col = q = lane&15 (lane-local softmax rows)
// PV: mfma(V^T,P) -> ctx col = q = lane&15 (lane-local rescale & epilogue)
__global__ __launch_bounds__(256) void attn_fwd(
    const f16* __restrict__ qb, const f16* __restrict__ kb,
    const f16* __restrict__ vt, f16* __restrict__ ctx)
{
    __shared__ f16 Kl[64 * LD];
    __shared__ f16 Vl[64 * LD];
    __shared__ f16 Pl[4 * 16 * LD];

    const int t = threadIdx.x, lane = t & 63, wid = t >> 6;
    const int q15 = lane & 15, g = lane >> 4;
    const int bh = blockIdx.y;
    const int q0 = blockIdx.x * 64 + wid * 16;

    // Q B-frag: lane holds Q[q15][g*8..+7] and +32
    const f16* qptr = qb + ((size_t)bh * S_LEN + q0) * HD;
    f16x8 qf0 = *reinterpret_cast<const f16x8*>(&qptr[q15 * HD + g * 8]);
    f16x8 qf1 = *reinterpret_cast<const f16x8*>(&qptr[q15 * HD + g * 8 + 32]);

    f32x4 ctxa[4];                          // [n][rg]: row d=16n+4g+rg, col q=q15
    #pragma unroll
    for (int i = 0; i < 4; i++) ctxa[i] = f32x4{0.f, 0.f, 0.f, 0.f};
    float mrun = -3.0e38f, lrun = 0.f;

    // staging map: 256 threads cover a 64x64 f16 tile with TWO 16B stores each
    const int r_st = t >> 2, c_st = (t & 3) * 16;
    const f16* kg = kb + (size_t)bh * S_LEN * HD + (size_t)r_st * HD + c_st;
    const f16* vg = vt + (size_t)bh * HD * S_LEN + (size_t)r_st * S_LEN + c_st;
    f16* kl_st = &Kl[r_st * LD + c_st];
    f16* vl_st = &Vl[r_st * LD + c_st];
    f16* pbase = &Pl[wid * (16 * LD)];

    for (int kt = 0; kt < S_LEN / 64; kt++) {
        __syncthreads();                    // prior-iter PV reads of Vl done
        *reinterpret_cast<uint4*>(kl_st)     = *reinterpret_cast<const uint4*>(kg);
        *reinterpret_cast<uint4*>(kl_st + 8) = *reinterpret_cast<const uint4*>(kg + 8);
        *reinterpret_cast<uint4*>(vl_st)     = *reinterpret_cast<const uint4*>(vg);
        *reinterpret_cast<uint4*>(vl_st + 8) = *reinterpret_cast<const uint4*>(vg + 8);
        kg += 64 * HD;
        vg += 64;
        __syncthreads();

        // QK^T swapped: sc[f][rg] = score(k = kt*64+16f+4g+rg, q = q0+q15)
        f32x4 sc[4];
        #pragma unroll
        for (int f = 0; f < 4; f++) {
            f16x8 kf0 = *reinterpret_cast<const f16x8*>(&Kl[(f * 16 + q15) * LD + g * 8]);
            f16x8 kf1 = *reinterpret_cast<const f16x8*>(&Kl[(f * 16 + q15) * LD + g * 8 + 32]);
            f32x4 z = {0.f, 0.f, 0.f, 0.f};
            z = __builtin_amdgcn_mfma_f32_16x16x32_f16(kf0, qf0, z, 0, 0, 0);
            sc[f] = __builtin_amdgcn_mfma_f32_16x16x32_f16(kf1, qf1, z, 0, 0, 0);
        }

        // online softmax (base-2); all stats lane-local for q = q15
        float pmf[4];
        #pragma unroll
        for (int f = 0; f < 4; f++)
            pmf[f] = fmaxf(fmaxf(sc[f][0], sc[f][1]), fmaxf(sc[f][2], sc[f][3]));
        float pmax = fmaxf(fmaxf(pmf[0], pmf[1]), fmaxf(pmf[2], pmf[3]));
        pmax = fmaxf(pmax, __shfl_xor(pmax, 16));
        pmax = fmaxf(pmax, __shfl_xor(pmax, 32));
        float mnew = fmaxf(mrun, pmax);
        float scale = __builtin_amdgcn_exp2f(mrun - mnew);
        float tsum = 0.f;
        #pragma unroll
        for (int f = 0; f < 4; f++)
            #pragma unroll
            for (int rg = 0; rg < 4; rg++) {
                float p = __builtin_amdgcn_exp2f(sc[f][rg] - mnew);
                sc[f][rg] = p;
                tsum += p;
            }
        tsum += __shfl_xor(tsum, 16);
        tsum += __shfl_xor(tsum, 32);
        lrun = lrun * scale + tsum;
        mrun = mnew;
        #pragma unroll
        for (int n = 0; n < 4; n++) {
            ctxa[n][0] *= scale; ctxa[n][1] *= scale;
            ctxa[n][2] *= scale; ctxa[n][3] *= scale;
        }

        // P -> per-wave LDS: lane q15 owns row q, writes 4 contiguous k per f (b64)
        #pragma unroll
        for (int f = 0; f < 4; f++) {
            f16x4 pw = { (f16)sc[f][0], (f16)sc[f][1], (f16)sc[f][2], (f16)sc[f][3] };
            *reinterpret_cast<f16x4*>(&pbase[q15 * LD + f * 16 + g * 4]) = pw;
        }
        // same-wave visibility: drain LDS writes, pin ordering (no block barrier needed)
        asm volatile("s_waitcnt lgkmcnt(0)" ::: "memory");
        __builtin_amdgcn_sched_barrier(0);

        // PV swapped: ctx[d][q] += V^T[d][s] * P[q][s]
        #pragma unroll
        for (int c = 0; c < 2; c++) {
            f16x8 pfr = *reinterpret_cast<const f16x8*>(&pbase[q15 * LD + g * 8 + c * 32]);
            #pragma unroll
            for (int n = 0; n < 4; n++) {
                f16x8 vf = *reinterpret_cast<const f16x8*>(&Vl[(n * 16 + q15) * LD + g * 8 + c * 32]);
                ctxa[n] = __builtin_amdgcn_mfma_f32_16x16x32_f16(vf, pfr, ctxa[n], 0, 0, 0);
            }
        }
    }

    // epilogue: lane-local 1/l, packed b64 stores (d = 16n+4g+rg contiguous in rg)
    const int bi = bh >> 4, h = bh & 15;
    const int s = q0 + q15;
    float inv = 1.0f / lrun;
    f16* outp = &ctx[((size_t)s * BATCH + bi) * DMODEL + h * HD];
    #pragma unroll
    for (int n = 0; n < 4; n++) {
        f16x4 o = { (f16)(ctxa[n][0] * inv), (f16)(ctxa[n][1] * inv),
                    (f16)(ctxa[n][2] * inv), (f16)(ctxa[n][3] * inv) };
        *reinterpret_cast<f16x4*>(&outp[n * 16 + g * 4]) = o;
    }
}

// ---------------- output projection: f16 X (ws), fp32 W (global), fp32 out ----------------
__global__ __launch_bounds__(256) void out_gemm(
    const f16* __restrict__ X, const float* __restrict__ W,
    const float* __restrict__ bias, float* __restrict__ out)
{
    __shared__ f16 Al[128 * 40];
    __shared__ f16 Bl[128 * 40];

    const int t = threadIdx.x;
    const int lane = t & 63, wid = t >> 6;
    const int wr = wid >> 1, wc = wid & 1;
    const int m0 = blockIdx.x * 128, n0 = blockIdx.y * 128;

    f32x4 acc[4][4];
    #pragma unroll
    for (int m = 0; m < 4; m++)
        #pragma unroll
        for (int n = 0; n < 4; n++)
            acc[m][n] = f32x4{0.f, 0.f, 0.f, 0.f};

    for (int k0 = 0; k0 < DMODEL; k0 += 32) {
        __syncthreads();
        #pragma unroll
        for (int i = 0; i < 2; i++) {
            int e = (i * 256 + t) * 8;
            int r = e >> 5, c = e & 31;
            *reinterpret_cast<uint4*>(&Al[r * 40 + c]) =
                *reinterpret_cast<const uint4*>(&X[(size_t)(m0 + r) * DMODEL + k0 + c]);
            {
                const float* src = &W[(size_t)(n0 + r) * DMODEL + k0 + c];
                float4 v0 = *reinterpret_cast<const float4*>(src);
                float4 v1 = *reinterpret_cast<const float4*>(src + 4);
                f16x8 h = { (f16)v0.x, (f16)v0.y, (f16)v0.z, (f16)v0.w,
                            (f16)v1.x, (f16)v1.y, (f16)v1.z, (f16)v1.w };
                *reinterpret_cast<f16x8*>(&Bl[r * 40 + c]) = h;
            }
        }
        __syncthreads();
        f16x8 a[4], b[4];
        #pragma unroll
        for (int m = 0; m < 4; m++)
            a[m] = *reinterpret_cast<const f16x8*>(&Al[(wr * 64 + m * 16 + (lane & 15)) * 40 + (lane >> 4) * 8]);
        #pragma unroll
        for (int n = 0; n < 4; n++)
            b[n] = *reinterpret_cast<const f16x8*>(&Bl[(wc * 64 + n * 16 + (lane & 15)) * 40 + (lane >> 4) * 8]);
        #pragma unroll
        for (int m = 0; m < 4; m++)
            #pragma unroll
            for (int n = 0; n < 4; n++)
                acc[m][n] = __builtin_amdgcn_mfma_f32_16x16x32_f16(a[m], b[n], acc[m][n], 0, 0, 0);
    }

    const int rowb = m0 + wr * 64, colb = n0 + wc * 64;
    #pragma unroll
    for (int n = 0; n < 4; n++) {
        int cN = colb + n * 16 + (lane & 15);
        float bvv = bias[cN];
        #pragma unroll
        for (int m = 0; m < 4; m++) {
            #pragma unroll
            for (int rg = 0; rg < 4; rg++) {
                int r = rowb + m * 16 + (lane >> 4) * 4 + rg;
                out[(size_t)r * DMODEL + cN] = acc[m][n][rg] + bvv;
            }
        }
    }
}

// ---------------- launch ----------------
extern "C" void kernel_launch(void* const* d_in, const int* in_sizes, int n_in,
                              void* d_out, int out_size, void* d_ws, size_t ws_size,
                              hipStream_t stream)
{
    const float* Q  = (const float*)d_in[0];
    const float* K  = (const float*)d_in[1];
    const float* V  = (const float*)d_in[2];
    const float* Wq = (const float*)d_in[3];
    const float* bq = (const float*)d_in[4];
    const float* Wk = (const float*)d_in[5];
    const float* bk = (const float*)d_in[6];
    const float* Wv = (const float*)d_in[7];
    const float* bv = (const float*)d_in[8];
    const float* Wo = (const float*)d_in[9];
    const float* bo = (const float*)d_in[10];
    float* out = (float*)d_out;

    // workspace layout (total 32.25 MiB):
    //   [0,128K)    rc    [128K,256K) rs
    //   [256K, +8M) qbuf  (B,H,S,hd) f16
    //   [+8M,+16M)  kbuf  (B,H,S,hd) f16
    //   [+16M,+24M) vtb   (B,H,hd,S) f16
    //   [+24M,+32M) ctxb  (S*B, D)   f16
    char* w = (char*)d_ws;
    const size_t szT = (size_t)S_LEN * 16 * sizeof(float);     // 128 KiB
    const size_t szQ = (size_t)MROWS * DMODEL * sizeof(f16);   // 8 MiB
    float* rc  = (float*)(w);
    float* rs  = (float*)(w + szT);
    f16* qbuf = (f16*)(w + 2 * szT);
    f16* kbuf = (f16*)(w + 2 * szT + szQ);
    f16* vtb  = (f16*)(w + 2 * szT + 2 * szQ);
    f16* ctxb = (f16*)(w + 2 * szT + 3 * szQ);

    rope_table<<<(S_LEN * 16) / 256, 256, 0, stream>>>(rc, rs);

    proj_gemm<<<dim3(MROWS / 128, DMODEL / 128, 3), 256, 0, stream>>>(
        Q, K, V, Wq, Wk, Wv, bq, bk, bv, qbuf, kbuf, vtb, rc, rs);

    attn_fwd<<<dim3(S_LEN / 64, BATCH * NHEADS), 256, 0, stream>>>(qbuf, kbuf, vtb, ctxb);

    out_gemm<<<dim3(MROWS / 128, DMODEL / 128), 256, 0, stream>>>(ctxb, Wo, bo, out);
}

// Round 9
// 174.821 us; speedup vs baseline: 2.3953x; 1.3690x over previous
//
#include <hip/hip_runtime.h>
#include <hip/hip_bf16.h>
#include <hip/hip_fp16.h>

#define S_LEN  2048
#define BATCH  2
#define DMODEL 1024
#define NHEADS 16
#define HD     64
#define MROWS  4096   // S*B
#define LD     72     // K/V/P LDS stride: 144B rows, 16B-aligned (r8 lesson: must stay 16B-multiple)

using f16 = _Float16;
typedef __attribute__((ext_vector_type(8))) _Float16 f16x8;
typedef __attribute__((ext_vector_type(4))) _Float16 f16x4;
typedef __attribute__((ext_vector_type(4))) float    f32x4;

// ---------------- RoPE cos/sin table: [S][16] ----------------
__global__ __launch_bounds__(256) void rope_table(float* __restrict__ rc, float* __restrict__ rs)
{
    int idx = blockIdx.x * 256 + threadIdx.x;   // S*16 threads
    int s = idx >> 4, i = idx & 15;
    float inv = powf(10000.0f, -(float)(2 * i) / 32.0f);
    float ang = (float)s * inv;
    rc[idx] = cosf(ang);
    rs[idx] = sinf(ang);
}

// ---------------- batched projection GEMM + bias + RoPE + head-split ----------------
// X, W are fp32 in global; converted to f16 during LDS staging.
// q scaled by (1/8)*log2(e) so attention scores live in the base-2 domain.
// q,k stored (B,H,S,hd); v stored transposed (B,H,hd,S)
__global__ __launch_bounds__(256) void proj_gemm(
    const float* __restrict__ Xq, const float* __restrict__ Xk, const float* __restrict__ Xv,
    const float* __restrict__ Wq, const float* __restrict__ Wk, const float* __restrict__ Wv,
    const float* __restrict__ bq, const float* __restrict__ bk, const float* __restrict__ bv,
    f16* __restrict__ qo, f16* __restrict__ ko, f16* __restrict__ vo,
    const float* __restrict__ rc, const float* __restrict__ rs)
{
    const int mode = blockIdx.z;            // 0=q 1=k 2=v
    const float* X    = (mode == 0) ? Xq : (mode == 1) ? Xk : Xv;
    const float* W    = (mode == 0) ? Wq : (mode == 1) ? Wk : Wv;
    const float* bias = (mode == 0) ? bq : (mode == 1) ? bk : bv;

    __shared__ f16 Al[128 * 40];   // stride 40 elems (80B): 2-way bank aliasing only (free)
    __shared__ f16 Bl[128 * 40];

    const int t = threadIdx.x;
    const int lane = t & 63, wid = t >> 6;
    const int wr = wid >> 1, wc = wid & 1;
    const int m0 = blockIdx.x * 128, n0 = blockIdx.y * 128;

    f32x4 acc[4][4];
    #pragma unroll
    for (int m = 0; m < 4; m++)
        #pragma unroll
        for (int n = 0; n < 4; n++)
            acc[m][n] = f32x4{0.f, 0.f, 0.f, 0.f};

    for (int k0 = 0; k0 < DMODEL; k0 += 32) {
        __syncthreads();
        #pragma unroll
        for (int i = 0; i < 2; i++) {
            int e = (i * 256 + t) * 8;       // elem index in 128x32 tile
            int r = e >> 5, c = e & 31;
            {
                const float* src = &X[(size_t)(m0 + r) * DMODEL + k0 + c];
                float4 v0 = *reinterpret_cast<const float4*>(src);
                float4 v1 = *reinterpret_cast<const float4*>(src + 4);
                f16x8 h = { (f16)v0.x, (f16)v0.y, (f16)v0.z, (f16)v0.w,
                            (f16)v1.x, (f16)v1.y, (f16)v1.z, (f16)v1.w };
                *reinterpret_cast<f16x8*>(&Al[r * 40 + c]) = h;
            }
            {
                const float* src = &W[(size_t)(n0 + r) * DMODEL + k0 + c];
                float4 v0 = *reinterpret_cast<const float4*>(src);
                float4 v1 = *reinterpret_cast<const float4*>(src + 4);
                f16x8 h = { (f16)v0.x, (f16)v0.y, (f16)v0.z, (f16)v0.w,
                            (f16)v1.x, (f16)v1.y, (f16)v1.z, (f16)v1.w };
                *reinterpret_cast<f16x8*>(&Bl[r * 40 + c]) = h;
            }
        }
        __syncthreads();
        f16x8 a[4], b[4];
        #pragma unroll
        for (int m = 0; m < 4; m++)
            a[m] = *reinterpret_cast<const f16x8*>(&Al[(wr * 64 + m * 16 + (lane & 15)) * 40 + (lane >> 4) * 8]);
        #pragma unroll
        for (int n = 0; n < 4; n++)
            b[n] = *reinterpret_cast<const f16x8*>(&Bl[(wc * 64 + n * 16 + (lane & 15)) * 40 + (lane >> 4) * 8]);
        #pragma unroll
        for (int m = 0; m < 4; m++)
            #pragma unroll
            for (int n = 0; n < 4; n++)
                acc[m][n] = __builtin_amdgcn_mfma_f32_16x16x32_f16(a[m], b[n], acc[m][n], 0, 0, 0);
    }

    const int rowb = m0 + wr * 64, colb = n0 + wc * 64;
    #pragma unroll
    for (int n = 0; n < 4; n++) {
        int cN = colb + n * 16 + (lane & 15);
        float bvv = bias[cN];
        int h = cN >> 6, d = cN & 63;
        #pragma unroll
        for (int m = 0; m < 4; m++) {
            #pragma unroll
            for (int rg = 0; rg < 4; rg++) {
                int r = rowb + m * 16 + (lane >> 4) * 4 + rg;
                int s = r >> 1, bi = r & 1;                 // row = s*B + b, B=2
                float val = acc[m][n][rg] + bvv;
                if (mode < 2) {
                    float pv = __shfl_xor(val, 1);          // partner col cN^1 == lane^1
                    if (d < 32) {
                        int fi = d >> 1;
                        float cc = rc[s * 16 + fi], ss = rs[s * 16 + fi];
                        val = ((d & 1) == 0) ? val * cc - pv * ss : val * cc + pv * ss;
                    }
                    if (mode == 0) val *= 0.18033688f;      // (1/8)*log2(e): base-2 softmax domain
                    ((mode == 0) ? qo : ko)[(((size_t)bi * NHEADS + h) * S_LEN + s) * HD + d] = (f16)val;
                } else {
                    vo[(((size_t)bi * NHEADS + h) * HD + d) * S_LEN + s] = (f16)val;
                }
            }
        }
    }
}

// ---------------- flash attention: 32 q-rows per wave (2 Q-frags), r6 sync structure ----------------
// grid (S/128, B*H); 4 waves, each owns q rows [q0, q0+32).
// QK: mfma(K,Q) -> score col = q (lane-local softmax); PV: mfma(V^T,P) -> ctx col = q.
__device__ __forceinline__ void online_sm(f32x4 sc[4], float& mrun, float& lrun, f32x4 ctxa[4])
{
    float pmf[4];
    #pragma unroll
    for (int f = 0; f < 4; f++)
        pmf[f] = fmaxf(fmaxf(sc[f][0], sc[f][1]), fmaxf(sc[f][2], sc[f][3]));
    float pmax = fmaxf(fmaxf(pmf[0], pmf[1]), fmaxf(pmf[2], pmf[3]));
    pmax = fmaxf(pmax, __shfl_xor(pmax, 16));
    pmax = fmaxf(pmax, __shfl_xor(pmax, 32));
    float mnew = fmaxf(mrun, pmax);
    float scale = __builtin_amdgcn_exp2f(mrun - mnew);
    float tsum = 0.f;
    #pragma unroll
    for (int f = 0; f < 4; f++)
        #pragma unroll
        for (int rg = 0; rg < 4; rg++) {
            float p = __builtin_amdgcn_exp2f(sc[f][rg] - mnew);
            sc[f][rg] = p;
            tsum += p;
        }
    tsum += __shfl_xor(tsum, 16);
    tsum += __shfl_xor(tsum, 32);
    lrun = lrun * scale + tsum;
    mrun = mnew;
    #pragma unroll
    for (int n = 0; n < 4; n++) {
        ctxa[n][0] *= scale; ctxa[n][1] *= scale;
        ctxa[n][2] *= scale; ctxa[n][3] *= scale;
    }
}

__global__ __launch_bounds__(256) void attn_fwd(
    const f16* __restrict__ qb, const f16* __restrict__ kb,
    const f16* __restrict__ vt, f16* __restrict__ ctx)
{
    __shared__ f16 Kl[64 * LD];
    __shared__ f16 Vl[64 * LD];
    __shared__ f16 Pl[8 * 16 * LD];        // [wave][sub][16][LD]

    const int t = threadIdx.x, lane = t & 63, wid = t >> 6;
    const int q15 = lane & 15, g = lane >> 4;
    const int bh = blockIdx.y;
    const int q0 = blockIdx.x * 128 + wid * 32;

    // two Q B-frags per wave: rows q0+q15 (A) and q0+16+q15 (B)
    const f16* qptr = qb + ((size_t)bh * S_LEN + q0) * HD;
    f16x8 qA0 = *reinterpret_cast<const f16x8*>(&qptr[q15 * HD + g * 8]);
    f16x8 qA1 = *reinterpret_cast<const f16x8*>(&qptr[q15 * HD + g * 8 + 32]);
    f16x8 qB0 = *reinterpret_cast<const f16x8*>(&qptr[(16 + q15) * HD + g * 8]);
    f16x8 qB1 = *reinterpret_cast<const f16x8*>(&qptr[(16 + q15) * HD + g * 8 + 32]);

    f32x4 cA[4], cB[4];
    #pragma unroll
    for (int i = 0; i < 4; i++) { cA[i] = f32x4{0.f,0.f,0.f,0.f}; cB[i] = f32x4{0.f,0.f,0.f,0.f}; }
    float mA = -3.0e38f, lA = 0.f, mB = -3.0e38f, lB = 0.f;

    // staging map: 256 threads cover a 64x64 f16 tile with TWO 16B stores each
    const int r_st = t >> 2, c_st = (t & 3) * 16;
    const f16* kg = kb + (size_t)bh * S_LEN * HD + (size_t)r_st * HD + c_st;
    const f16* vg = vt + (size_t)bh * HD * S_LEN + (size_t)r_st * S_LEN + c_st;
    f16* kl_st = &Kl[r_st * LD + c_st];
    f16* vl_st = &Vl[r_st * LD + c_st];
    f16* pA = &Pl[(wid * 2 + 0) * (16 * LD)];
    f16* pB = &Pl[(wid * 2 + 1) * (16 * LD)];

    for (int kt = 0; kt < S_LEN / 64; kt++) {
        __syncthreads();                    // prior-iter PV reads of Vl done
        *reinterpret_cast<uint4*>(kl_st)     = *reinterpret_cast<const uint4*>(kg);
        *reinterpret_cast<uint4*>(kl_st + 8) = *reinterpret_cast<const uint4*>(kg + 8);
        *reinterpret_cast<uint4*>(vl_st)     = *reinterpret_cast<const uint4*>(vg);
        *reinterpret_cast<uint4*>(vl_st + 8) = *reinterpret_cast<const uint4*>(vg + 8);
        kg += 64 * HD;
        vg += 64;
        __syncthreads();

        // QK^T swapped, both subtiles share each K-frag read
        f32x4 sA[4], sB[4];
        __builtin_amdgcn_s_setprio(1);
        #pragma unroll
        for (int f = 0; f < 4; f++) {
            f16x8 kf0 = *reinterpret_cast<const f16x8*>(&Kl[(f * 16 + q15) * LD + g * 8]);
            f16x8 kf1 = *reinterpret_cast<const f16x8*>(&Kl[(f * 16 + q15) * LD + g * 8 + 32]);
            f32x4 z = {0.f, 0.f, 0.f, 0.f};
            z = __builtin_amdgcn_mfma_f32_16x16x32_f16(kf0, qA0, z, 0, 0, 0);
            sA[f] = __builtin_amdgcn_mfma_f32_16x16x32_f16(kf1, qA1, z, 0, 0, 0);
            f32x4 z2 = {0.f, 0.f, 0.f, 0.f};
            z2 = __builtin_amdgcn_mfma_f32_16x16x32_f16(kf0, qB0, z2, 0, 0, 0);
            sB[f] = __builtin_amdgcn_mfma_f32_16x16x32_f16(kf1, qB1, z2, 0, 0, 0);
        }
        __builtin_amdgcn_s_setprio(0);

        online_sm(sA, mA, lA, cA);
        online_sm(sB, mB, lB, cB);

        // P -> per-wave-per-subtile LDS (b64 packs)
        #pragma unroll
        for (int f = 0; f < 4; f++) {
            f16x4 pwA = { (f16)sA[f][0], (f16)sA[f][1], (f16)sA[f][2], (f16)sA[f][3] };
            *reinterpret_cast<f16x4*>(&pA[q15 * LD + f * 16 + g * 4]) = pwA;
            f16x4 pwB = { (f16)sB[f][0], (f16)sB[f][1], (f16)sB[f][2], (f16)sB[f][3] };
            *reinterpret_cast<f16x4*>(&pB[q15 * LD + f * 16 + g * 4]) = pwB;
        }
        // same-wave visibility: drain LDS writes, pin ordering (no block barrier needed)
        asm volatile("s_waitcnt lgkmcnt(0)" ::: "memory");
        __builtin_amdgcn_sched_barrier(0);

        // PV swapped: each V-frag read feeds both subtiles' MFMA
        __builtin_amdgcn_s_setprio(1);
        #pragma unroll
        for (int c = 0; c < 2; c++) {
            f16x8 pfA = *reinterpret_cast<const f16x8*>(&pA[q15 * LD + g * 8 + c * 32]);
            f16x8 pfB = *reinterpret_cast<const f16x8*>(&pB[q15 * LD + g * 8 + c * 32]);
            #pragma unroll
            for (int n = 0; n < 4; n++) {
                f16x8 vf = *reinterpret_cast<const f16x8*>(&Vl[(n * 16 + q15) * LD + g * 8 + c * 32]);
                cA[n] = __builtin_amdgcn_mfma_f32_16x16x32_f16(vf, pfA, cA[n], 0, 0, 0);
                cB[n] = __builtin_amdgcn_mfma_f32_16x16x32_f16(vf, pfB, cB[n], 0, 0, 0);
            }
        }
        __builtin_amdgcn_s_setprio(0);
    }

    // epilogue: lane-local 1/l, packed b64 stores (d = 16n+4g+rg contiguous in rg)
    const int bi = bh >> 4, h = bh & 15;
    {
        const int s = q0 + q15;
        float inv = 1.0f / lA;
        f16* outp = &ctx[((size_t)s * BATCH + bi) * DMODEL + h * HD];
        #pragma unroll
        for (int n = 0; n < 4; n++) {
            f16x4 o = { (f16)(cA[n][0] * inv), (f16)(cA[n][1] * inv),
                        (f16)(cA[n][2] * inv), (f16)(cA[n][3] * inv) };
            *reinterpret_cast<f16x4*>(&outp[n * 16 + g * 4]) = o;
        }
    }
    {
        const int s = q0 + 16 + q15;
        float inv = 1.0f / lB;
        f16* outp = &ctx[((size_t)s * BATCH + bi) * DMODEL + h * HD];
        #pragma unroll
        for (int n = 0; n < 4; n++) {
            f16x4 o = { (f16)(cB[n][0] * inv), (f16)(cB[n][1] * inv),
                        (f16)(cB[n][2] * inv), (f16)(cB[n][3] * inv) };
            *reinterpret_cast<f16x4*>(&outp[n * 16 + g * 4]) = o;
        }
    }
}

// ---------------- output projection: f16 X (ws), fp32 W (global), fp32 out ----------------
__global__ __launch_bounds__(256) void out_gemm(
    const f16* __restrict__ X, const float* __restrict__ W,
    const float* __restrict__ bias, float* __restrict__ out)
{
    __shared__ f16 Al[128 * 40];
    __shared__ f16 Bl[128 * 40];

    const int t = threadIdx.x;
    const int lane = t & 63, wid = t >> 6;
    const int wr = wid >> 1, wc = wid & 1;
    const int m0 = blockIdx.x * 128, n0 = blockIdx.y * 128;

    f32x4 acc[4][4];
    #pragma unroll
    for (int m = 0; m < 4; m++)
        #pragma unroll
        for (int n = 0; n < 4; n++)
            acc[m][n] = f32x4{0.f, 0.f, 0.f, 0.f};

    for (int k0 = 0; k0 < DMODEL; k0 += 32) {
        __syncthreads();
        #pragma unroll
        for (int i = 0; i < 2; i++) {
            int e = (i * 256 + t) * 8;
            int r = e >> 5, c = e & 31;
            *reinterpret_cast<uint4*>(&Al[r * 40 + c]) =
                *reinterpret_cast<const uint4*>(&X[(size_t)(m0 + r) * DMODEL + k0 + c]);
            {
                const float* src = &W[(size_t)(n0 + r) * DMODEL + k0 + c];
                float4 v0 = *reinterpret_cast<const float4*>(src);
                float4 v1 = *reinterpret_cast<const float4*>(src + 4);
                f16x8 h = { (f16)v0.x, (f16)v0.y, (f16)v0.z, (f16)v0.w,
                            (f16)v1.x, (f16)v1.y, (f16)v1.z, (f16)v1.w };
                *reinterpret_cast<f16x8*>(&Bl[r * 40 + c]) = h;
            }
        }
        __syncthreads();
        f16x8 a[4], b[4];
        #pragma unroll
        for (int m = 0; m < 4; m++)
            a[m] = *reinterpret_cast<const f16x8*>(&Al[(wr * 64 + m * 16 + (lane & 15)) * 40 + (lane >> 4) * 8]);
        #pragma unroll
        for (int n = 0; n < 4; n++)
            b[n] = *reinterpret_cast<const f16x8*>(&Bl[(wc * 64 + n * 16 + (lane & 15)) * 40 + (lane >> 4) * 8]);
        #pragma unroll
        for (int m = 0; m < 4; m++)
            #pragma unroll
            for (int n = 0; n < 4; n++)
                acc[m][n] = __builtin_amdgcn_mfma_f32_16x16x32_f16(a[m], b[n], acc[m][n], 0, 0, 0);
    }

    const int rowb = m0 + wr * 64, colb = n0 + wc * 64;
    #pragma unroll
    for (int n = 0; n < 4; n++) {
        int cN = colb + n * 16 + (lane & 15);
        float bvv = bias[cN];
        #pragma unroll
        for (int m = 0; m < 4; m++) {
            #pragma unroll
            for (int rg = 0; rg < 4; rg++) {
                int r = rowb + m * 16 + (lane >> 4) * 4 + rg;
                out[(size_t)r * DMODEL + cN] = acc[m][n][rg] + bvv;
            }
        }
    }
}

// ---------------- launch ----------------
extern "C" void kernel_launch(void* const* d_in, const int* in_sizes, int n_in,
                              void* d_out, int out_size, void* d_ws, size_t ws_size,
                              hipStream_t stream)
{
    const float* Q  = (const float*)d_in[0];
    const float* K  = (const float*)d_in[1];
    const float* V  = (const float*)d_in[2];
    const float* Wq = (const float*)d_in[3];
    const float* bq = (const float*)d_in[4];
    const float* Wk = (const float*)d_in[5];
    const float* bk = (const float*)d_in[6];
    const float* Wv = (const float*)d_in[7];
    const float* bv = (const float*)d_in[8];
    const float* Wo = (const float*)d_in[9];
    const float* bo = (const float*)d_in[10];
    float* out = (float*)d_out;

    // workspace layout (total 32.25 MiB):
    //   [0,128K)    rc    [128K,256K) rs
    //   [256K, +8M) qbuf  (B,H,S,hd) f16
    //   [+8M,+16M)  kbuf  (B,H,S,hd) f16
    //   [+16M,+24M) vtb   (B,H,hd,S) f16
    //   [+24M,+32M) ctxb  (S*B, D)   f16
    char* w = (char*)d_ws;
    const size_t szT = (size_t)S_LEN * 16 * sizeof(float);     // 128 KiB
    const size_t szQ = (size_t)MROWS * DMODEL * sizeof(f16);   // 8 MiB
    float* rc  = (float*)(w);
    float* rs  = (float*)(w + szT);
    f16* qbuf = (f16*)(w + 2 * szT);
    f16* kbuf = (f16*)(w + 2 * szT + szQ);
    f16* vtb  = (f16*)(w + 2 * szT + 2 * szQ);
    f16* ctxb = (f16*)(w + 2 * szT + 3 * szQ);

    rope_table<<<(S_LEN * 16) / 256, 256, 0, stream>>>(rc, rs);

    proj_gemm<<<dim3(MROWS / 128, DMODEL / 128, 3), 256, 0, stream>>>(
        Q, K, V, Wq, Wk, Wv, bq, bk, bv, qbuf, kbuf, vtb, rc, rs);

    attn_fwd<<<dim3(S_LEN / 128, BATCH * NHEADS), 256, 0, stream>>>(qbuf, kbuf, vtb, ctxb);

    out_gemm<<<dim3(MROWS / 128, DMODEL / 128), 256, 0, stream>>>(ctxb, Wo, bo, out);
}

// Round 11
// 168.973 us; speedup vs baseline: 2.4782x; 1.0346x over previous
//
#include <hip/hip_runtime.h>
#include <hip/hip_bf16.h>
#include <hip/hip_fp16.h>

#define S_LEN  2048
#define BATCH  2
#define DMODEL 1024
#define NHEADS 16
#define HD     64
#define MROWS  4096   // S*B
#define LD     72     // K/V/P LDS stride: 144B rows, 16B-aligned (r8: must stay 16B-multiple)

using f16 = _Float16;
typedef __attribute__((ext_vector_type(8))) _Float16 f16x8;
typedef __attribute__((ext_vector_type(4))) _Float16 f16x4;
typedef __attribute__((ext_vector_type(4))) float    f32x4;

// ---------------- RoPE cos/sin table: [S][16] ----------------
__global__ __launch_bounds__(256) void rope_table(float* __restrict__ rc, float* __restrict__ rs)
{
    int idx = blockIdx.x * 256 + threadIdx.x;   // S*16 threads
    int s = idx >> 4, i = idx & 15;
    float inv = powf(10000.0f, -(float)(2 * i) / 32.0f);
    float ang = (float)s * inv;
    rc[idx] = cosf(ang);
    rs[idx] = sinf(ang);
}

// ---------------- batched projection GEMM + bias + RoPE + head-split ----------------
// X, W are fp32 in global; converted to f16 during LDS staging.
// q scaled by (1/8)*log2(e) so attention scores live in the base-2 domain.
// q,k stored (B,H,S,hd); v stored transposed (B,H,hd,S)
__global__ __launch_bounds__(256) void proj_gemm(
    const float* __restrict__ Xq, const float* __restrict__ Xk, const float* __restrict__ Xv,
    const float* __restrict__ Wq, const float* __restrict__ Wk, const float* __restrict__ Wv,
    const float* __restrict__ bq, const float* __restrict__ bk, const float* __restrict__ bv,
    f16* __restrict__ qo, f16* __restrict__ ko, f16* __restrict__ vo,
    const float* __restrict__ rc, const float* __restrict__ rs)
{
    const int mode = blockIdx.z;            // 0=q 1=k 2=v
    const float* X    = (mode == 0) ? Xq : (mode == 1) ? Xk : Xv;
    const float* W    = (mode == 0) ? Wq : (mode == 1) ? Wk : Wv;
    const float* bias = (mode == 0) ? bq : (mode == 1) ? bk : bv;

    __shared__ f16 Al[128 * 40];   // stride 40 elems (80B): 2-way bank aliasing only (free)
    __shared__ f16 Bl[128 * 40];

    const int t = threadIdx.x;
    const int lane = t & 63, wid = t >> 6;
    const int wr = wid >> 1, wc = wid & 1;
    const int m0 = blockIdx.x * 128, n0 = blockIdx.y * 128;

    f32x4 acc[4][4];
    #pragma unroll
    for (int m = 0; m < 4; m++)
        #pragma unroll
        for (int n = 0; n < 4; n++)
            acc[m][n] = f32x4{0.f, 0.f, 0.f, 0.f};

    for (int k0 = 0; k0 < DMODEL; k0 += 32) {
        __syncthreads();
        #pragma unroll
        for (int i = 0; i < 2; i++) {
            int e = (i * 256 + t) * 8;       // elem index in 128x32 tile
            int r = e >> 5, c = e & 31;
            {
                const float* src = &X[(size_t)(m0 + r) * DMODEL + k0 + c];
                float4 v0 = *reinterpret_cast<const float4*>(src);
                float4 v1 = *reinterpret_cast<const float4*>(src + 4);
                f16x8 h = { (f16)v0.x, (f16)v0.y, (f16)v0.z, (f16)v0.w,
                            (f16)v1.x, (f16)v1.y, (f16)v1.z, (f16)v1.w };
                *reinterpret_cast<f16x8*>(&Al[r * 40 + c]) = h;
            }
            {
                const float* src = &W[(size_t)(n0 + r) * DMODEL + k0 + c];
                float4 v0 = *reinterpret_cast<const float4*>(src);
                float4 v1 = *reinterpret_cast<const float4*>(src + 4);
                f16x8 h = { (f16)v0.x, (f16)v0.y, (f16)v0.z, (f16)v0.w,
                            (f16)v1.x, (f16)v1.y, (f16)v1.z, (f16)v1.w };
                *reinterpret_cast<f16x8*>(&Bl[r * 40 + c]) = h;
            }
        }
        __syncthreads();
        f16x8 a[4], b[4];
        #pragma unroll
        for (int m = 0; m < 4; m++)
            a[m] = *reinterpret_cast<const f16x8*>(&Al[(wr * 64 + m * 16 + (lane & 15)) * 40 + (lane >> 4) * 8]);
        #pragma unroll
        for (int n = 0; n < 4; n++)
            b[n] = *reinterpret_cast<const f16x8*>(&Bl[(wc * 64 + n * 16 + (lane & 15)) * 40 + (lane >> 4) * 8]);
        #pragma unroll
        for (int m = 0; m < 4; m++)
            #pragma unroll
            for (int n = 0; n < 4; n++)
                acc[m][n] = __builtin_amdgcn_mfma_f32_16x16x32_f16(a[m], b[n], acc[m][n], 0, 0, 0);
    }

    const int rowb = m0 + wr * 64, colb = n0 + wc * 64;
    #pragma unroll
    for (int n = 0; n < 4; n++) {
        int cN = colb + n * 16 + (lane & 15);
        float bvv = bias[cN];
        int h = cN >> 6, d = cN & 63;
        #pragma unroll
        for (int m = 0; m < 4; m++) {
            #pragma unroll
            for (int rg = 0; rg < 4; rg++) {
                int r = rowb + m * 16 + (lane >> 4) * 4 + rg;
                int s = r >> 1, bi = r & 1;                 // row = s*B + b, B=2
                float val = acc[m][n][rg] + bvv;
                if (mode < 2) {
                    float pv = __shfl_xor(val, 1);          // partner col cN^1 == lane^1
                    if (d < 32) {
                        int fi = d >> 1;
                        float cc = rc[s * 16 + fi], ss = rs[s * 16 + fi];
                        val = ((d & 1) == 0) ? val * cc - pv * ss : val * cc + pv * ss;
                    }
                    if (mode == 0) val *= 0.18033688f;      // (1/8)*log2(e): base-2 softmax domain
                    ((mode == 0) ? qo : ko)[(((size_t)bi * NHEADS + h) * S_LEN + s) * HD + d] = (f16)val;
                } else {
                    vo[(((size_t)bi * NHEADS + h) * HD + d) * S_LEN + s] = (f16)val;
                }
            }
        }
    }
}

// ---------------- flash attention: 8 waves x 16 q-rows, QBLK=128, r6 per-wave structure ----------------
// grid (S/128, B*H); 512 threads. Staging amortized over 128 q-rows; 16 waves/CU resident.
__global__ __launch_bounds__(512) void attn_fwd(
    const f16* __restrict__ qb, const f16* __restrict__ kb,
    const f16* __restrict__ vt, f16* __restrict__ ctx)
{
    __shared__ f16 Kl[64 * LD];
    __shared__ f16 Vl[64 * LD];
    __shared__ f16 Pl[8 * 16 * LD];        // per-wave P

    const int t = threadIdx.x, lane = t & 63, wid = t >> 6;
    const int q15 = lane & 15, g = lane >> 4;
    const int bh = blockIdx.y;
    const int q0 = blockIdx.x * 128 + wid * 16;

    // Q B-frag: lane holds Q[q15][g*8..+7] and +32
    const f16* qptr = qb + ((size_t)bh * S_LEN + q0) * HD;
    f16x8 qf0 = *reinterpret_cast<const f16x8*>(&qptr[q15 * HD + g * 8]);
    f16x8 qf1 = *reinterpret_cast<const f16x8*>(&qptr[q15 * HD + g * 8 + 32]);

    f32x4 ctxa[4];                          // [n][rg]: row d=16n+4g+rg, col q=q15
    #pragma unroll
    for (int i = 0; i < 4; i++) ctxa[i] = f32x4{0.f, 0.f, 0.f, 0.f};
    float mrun = -3.0e38f, lrun = 0.f;

    // staging map: 512 threads cover a 64x64 f16 tile with ONE 16B store each
    const int r_st = t >> 3, c_st = (t & 7) * 8;
    const f16* kg = kb + (size_t)bh * S_LEN * HD + (size_t)r_st * HD + c_st;
    const f16* vg = vt + (size_t)bh * HD * S_LEN + (size_t)r_st * S_LEN + c_st;
    f16* kl_st = &Kl[r_st * LD + c_st];
    f16* vl_st = &Vl[r_st * LD + c_st];
    f16* pbase = &Pl[wid * (16 * LD)];

    for (int kt = 0; kt < S_LEN / 64; kt++) {
        __syncthreads();                    // prior-iter PV reads of Vl done
        *reinterpret_cast<uint4*>(kl_st) = *reinterpret_cast<const uint4*>(kg);
        *reinterpret_cast<uint4*>(vl_st) = *reinterpret_cast<const uint4*>(vg);
        kg += 64 * HD;
        vg += 64;
        __syncthreads();

        // QK^T swapped: sc[f][rg] = score(k = kt*64+16f+4g+rg, q = q0+q15)
        f32x4 sc[4];
        __builtin_amdgcn_s_setprio(1);
        #pragma unroll
        for (int f = 0; f < 4; f++) {
            f16x8 kf0 = *reinterpret_cast<const f16x8*>(&Kl[(f * 16 + q15) * LD + g * 8]);
            f16x8 kf1 = *reinterpret_cast<const f16x8*>(&Kl[(f * 16 + q15) * LD + g * 8 + 32]);
            f32x4 z = {0.f, 0.f, 0.f, 0.f};
            z = __builtin_amdgcn_mfma_f32_16x16x32_f16(kf0, qf0, z, 0, 0, 0);
            sc[f] = __builtin_amdgcn_mfma_f32_16x16x32_f16(kf1, qf1, z, 0, 0, 0);
        }
        __builtin_amdgcn_s_setprio(0);

        // online softmax (base-2); all stats lane-local for q = q15
        float pmf[4];
        #pragma unroll
        for (int f = 0; f < 4; f++)
            pmf[f] = fmaxf(fmaxf(sc[f][0], sc[f][1]), fmaxf(sc[f][2], sc[f][3]));
        float pmax = fmaxf(fmaxf(pmf[0], pmf[1]), fmaxf(pmf[2], pmf[3]));
        pmax = fmaxf(pmax, __shfl_xor(pmax, 16));
        pmax = fmaxf(pmax, __shfl_xor(pmax, 32));
        float mnew = fmaxf(mrun, pmax);
        float scale = __builtin_amdgcn_exp2f(mrun - mnew);
        float tsum = 0.f;
        #pragma unroll
        for (int f = 0; f < 4; f++)
            #pragma unroll
            for (int rg = 0; rg < 4; rg++) {
                float p = __builtin_amdgcn_exp2f(sc[f][rg] - mnew);
                sc[f][rg] = p;
                tsum += p;
            }
        tsum += __shfl_xor(tsum, 16);
        tsum += __shfl_xor(tsum, 32);
        lrun = lrun * scale + tsum;
        mrun = mnew;
        #pragma unroll
        for (int n = 0; n < 4; n++) {
            ctxa[n][0] *= scale; ctxa[n][1] *= scale;
            ctxa[n][2] *= scale; ctxa[n][3] *= scale;
        }

        // P -> per-wave LDS: lane q15 owns row q, writes 4 contiguous k per f (b64)
        #pragma unroll
        for (int f = 0; f < 4; f++) {
            f16x4 pw = { (f16)sc[f][0], (f16)sc[f][1], (f16)sc[f][2], (f16)sc[f][3] };
            *reinterpret_cast<f16x4*>(&pbase[q15 * LD + f * 16 + g * 4]) = pw;
        }
        // same-wave visibility: drain LDS writes, pin ordering (no block barrier needed)
        asm volatile("s_waitcnt lgkmcnt(0)" ::: "memory");
        __builtin_amdgcn_sched_barrier(0);

        // PV swapped: ctx[d][q] += V^T[d][s] * P[q][s]
        __builtin_amdgcn_s_setprio(1);
        #pragma unroll
        for (int c = 0; c < 2; c++) {
            f16x8 pfr = *reinterpret_cast<const f16x8*>(&pbase[q15 * LD + g * 8 + c * 32]);
            #pragma unroll
            for (int n = 0; n < 4; n++) {
                f16x8 vf = *reinterpret_cast<const f16x8*>(&Vl[(n * 16 + q15) * LD + g * 8 + c * 32]);
                ctxa[n] = __builtin_amdgcn_mfma_f32_16x16x32_f16(vf, pfr, ctxa[n], 0, 0, 0);
            }
        }
        __builtin_amdgcn_s_setprio(0);
    }

    // epilogue: lane-local 1/l, packed b64 stores (d = 16n+4g+rg contiguous in rg)
    const int bi = bh >> 4, h = bh & 15;
    const int s = q0 + q15;
    float inv = 1.0f / lrun;
    f16* outp = &ctx[((size_t)s * BATCH + bi) * DMODEL + h * HD];
    #pragma unroll
    for (int n = 0; n < 4; n++) {
        f16x4 o = { (f16)(ctxa[n][0] * inv), (f16)(ctxa[n][1] * inv),
                    (f16)(ctxa[n][2] * inv), (f16)(ctxa[n][3] * inv) };
        *reinterpret_cast<f16x4*>(&outp[n * 16 + g * 4]) = o;
    }
}

// ---------------- output projection: f16 X (ws), fp32 W (global), fp32 out ----------------
__global__ __launch_bounds__(256) void out_gemm(
    const f16* __restrict__ X, const float* __restrict__ W,
    const float* __restrict__ bias, float* __restrict__ out)
{
    __shared__ f16 Al[128 * 40];
    __shared__ f16 Bl[128 * 40];

    const int t = threadIdx.x;
    const int lane = t & 63, wid = t >> 6;
    const int wr = wid >> 1, wc = wid & 1;
    const int m0 = blockIdx.x * 128, n0 = blockIdx.y * 128;

    f32x4 acc[4][4];
    #pragma unroll
    for (int m = 0; m < 4; m++)
        #pragma unroll
        for (int n = 0; n < 4; n++)
            acc[m][n] = f32x4{0.f, 0.f, 0.f, 0.f};

    for (int k0 = 0; k0 < DMODEL; k0 += 32) {
        __syncthreads();
        #pragma unroll
        for (int i = 0; i < 2; i++) {
            int e = (i * 256 + t) * 8;
            int r = e >> 5, c = e & 31;
            *reinterpret_cast<uint4*>(&Al[r * 40 + c]) =
                *reinterpret_cast<const uint4*>(&X[(size_t)(m0 + r) * DMODEL + k0 + c]);
            {
                const float* src = &W[(size_t)(n0 + r) * DMODEL + k0 + c];
                float4 v0 = *reinterpret_cast<const float4*>(src);
                float4 v1 = *reinterpret_cast<const float4*>(src + 4);
                f16x8 h = { (f16)v0.x, (f16)v0.y, (f16)v0.z, (f16)v0.w,
                            (f16)v1.x, (f16)v1.y, (f16)v1.z, (f16)v1.w };
                *reinterpret_cast<f16x8*>(&Bl[r * 40 + c]) = h;
            }
        }
        __syncthreads();
        f16x8 a[4], b[4];
        #pragma unroll
        for (int m = 0; m < 4; m++)
            a[m] = *reinterpret_cast<const f16x8*>(&Al[(wr * 64 + m * 16 + (lane & 15)) * 40 + (lane >> 4) * 8]);
        #pragma unroll
        for (int n = 0; n < 4; n++)
            b[n] = *reinterpret_cast<const f16x8*>(&Bl[(wc * 64 + n * 16 + (lane & 15)) * 40 + (lane >> 4) * 8]);
        #pragma unroll
        for (int m = 0; m < 4; m++)
            #pragma unroll
            for (int n = 0; n < 4; n++)
                acc[m][n] = __builtin_amdgcn_mfma_f32_16x16x32_f16(a[m], b[n], acc[m][n], 0, 0, 0);
    }

    const int rowb = m0 + wr * 64, colb = n0 + wc * 64;
    #pragma unroll
    for (int n = 0; n < 4; n++) {
        int cN = colb + n * 16 + (lane & 15);
        float bvv = bias[cN];
        #pragma unroll
        for (int m = 0; m < 4; m++) {
            #pragma unroll
            for (int rg = 0; rg < 4; rg++) {
                int r = rowb + m * 16 + (lane >> 4) * 4 + rg;
                out[(size_t)r * DMODEL + cN] = acc[m][n][rg] + bvv;
            }
        }
    }
}

// ---------------- launch ----------------
extern "C" void kernel_launch(void* const* d_in, const int* in_sizes, int n_in,
                              void* d_out, int out_size, void* d_ws, size_t ws_size,
                              hipStream_t stream)
{
    const float* Q  = (const float*)d_in[0];
    const float* K  = (const float*)d_in[1];
    const float* V  = (const float*)d_in[2];
    const float* Wq = (const float*)d_in[3];
    const float* bq = (const float*)d_in[4];
    const float* Wk = (const float*)d_in[5];
    const float* bk = (const float*)d_in[6];
    const float* Wv = (const float*)d_in[7];
    const float* bv = (const float*)d_in[8];
    const float* Wo = (const float*)d_in[9];
    const float* bo = (const float*)d_in[10];
    float* out = (float*)d_out;

    // workspace layout (total 32.25 MiB):
    //   [0,128K)    rc    [128K,256K) rs
    //   [256K, +8M) qbuf  (B,H,S,hd) f16
    //   [+8M,+16M)  kbuf  (B,H,S,hd) f16
    //   [+16M,+24M) vtb   (B,H,hd,S) f16
    //   [+24M,+32M) ctxb  (S*B, D)   f16
    char* w = (char*)d_ws;
    const size_t szT = (size_t)S_LEN * 16 * sizeof(float);     // 128 KiB
    const size_t szQ = (size_t)MROWS * DMODEL * sizeof(f16);   // 8 MiB
    float* rc  = (float*)(w);
    float* rs  = (float*)(w + szT);
    f16* qbuf = (f16*)(w + 2 * szT);
    f16* kbuf = (f16*)(w + 2 * szT + szQ);
    f16* vtb  = (f16*)(w + 2 * szT + 2 * szQ);
    f16* ctxb = (f16*)(w + 2 * szT + 3 * szQ);

    rope_table<<<(S_LEN * 16) / 256, 256, 0, stream>>>(rc, rs);

    proj_gemm<<<dim3(MROWS / 128, DMODEL / 128, 3), 256, 0, stream>>>(
        Q, K, V, Wq, Wk, Wv, bq, bk, bv, qbuf, kbuf, vtb, rc, rs);

    attn_fwd<<<dim3(S_LEN / 128, BATCH * NHEADS), 512, 0, stream>>>(qbuf, kbuf, vtb, ctxb);

    out_gemm<<<dim3(MROWS / 128, DMODEL / 128), 256, 0, stream>>>(ctxb, Wo, bo, out);
}

// Round 12
// 158.949 us; speedup vs baseline: 2.6345x; 1.0631x over previous
//
#include <hip/hip_runtime.h>
#include <hip/hip_bf16.h>
#include <hip/hip_fp16.h>

#define S_LEN  2048
#define BATCH  2
#define DMODEL 1024
#define NHEADS 16
#define HD     64
#define MROWS  4096   // S*B
#define LD     72     // attn K/V/P LDS stride (16B-aligned; r8 lesson)

using f16 = _Float16;
typedef __attribute__((ext_vector_type(8))) _Float16 f16x8;
typedef __attribute__((ext_vector_type(4))) _Float16 f16x4;
typedef __attribute__((ext_vector_type(4))) float    f32x4;

// async global->LDS, 16B per lane; LDS dest = wave-uniform base + lane*16
__device__ __forceinline__ void gload16(const void* g, void* l)
{
    __builtin_amdgcn_global_load_lds((const __attribute__((address_space(1))) void*)g,
                                     (__attribute__((address_space(3))) void*)l, 16, 0, 0);
}

// ---------------- RoPE cos/sin table: [S][16] ----------------
__global__ __launch_bounds__(256) void rope_table(float* __restrict__ rc, float* __restrict__ rs)
{
    int idx = blockIdx.x * 256 + threadIdx.x;   // S*16 threads
    int s = idx >> 4, i = idx & 15;
    float inv = powf(10000.0f, -(float)(2 * i) / 32.0f);
    float ang = (float)s * inv;
    rc[idx] = cosf(ang);
    rs[idx] = sinf(ang);
}

// ---------------- fp32 -> f16 conversion of all 7 tensors into one ws block ----------------
// dst segments (f16 elems): Xq 0, Xk 4194304, Xv 8388608, Wq 12582912, Wk 13631488,
//                           Wv 14680064, Wo 15728640   (total 32 MiB)
__global__ __launch_bounds__(256) void cvt_all(
    const float* __restrict__ Q, const float* __restrict__ K, const float* __restrict__ V,
    const float* __restrict__ Wq, const float* __restrict__ Wk, const float* __restrict__ Wv,
    const float* __restrict__ Wo, f16* __restrict__ dst)
{
    const int z = blockIdx.y;
    const float* src; size_t off; int n8;
    switch (z) {
        case 0:  src = Q;  off = 0;        n8 = 524288; break;
        case 1:  src = K;  off = 4194304;  n8 = 524288; break;
        case 2:  src = V;  off = 8388608;  n8 = 524288; break;
        case 3:  src = Wq; off = 12582912; n8 = 131072; break;
        case 4:  src = Wk; off = 13631488; n8 = 131072; break;
        case 5:  src = Wv; off = 14680064; n8 = 131072; break;
        default: src = Wo; off = 15728640; n8 = 131072; break;
    }
    int i = blockIdx.x * 256 + threadIdx.x;     // f16x8 octet index
    if (i >= n8) return;
    const float4* s = reinterpret_cast<const float4*>(src) + (size_t)i * 2;
    float4 v0 = s[0], v1 = s[1];
    f16x8 h = { (f16)v0.x, (f16)v0.y, (f16)v0.z, (f16)v0.w,
                (f16)v1.x, (f16)v1.y, (f16)v1.z, (f16)v1.w };
    reinterpret_cast<f16x8*>(dst + off)[i] = h;
}

// ---------------- FAST: f16-input projection GEMM, global_load_lds staging (m97 structure) ---
// q scaled by (1/8)*log2(e); q,k stored (B,H,S,hd); v stored transposed (B,H,hd,S)
__global__ __launch_bounds__(256) void proj_gemm_h(
    const f16* __restrict__ Xq, const f16* __restrict__ Xk, const f16* __restrict__ Xv,
    const f16* __restrict__ Wq, const f16* __restrict__ Wk, const f16* __restrict__ Wv,
    const float* __restrict__ bq, const float* __restrict__ bk, const float* __restrict__ bv,
    f16* __restrict__ qo, f16* __restrict__ ko, f16* __restrict__ vo,
    const float* __restrict__ rc, const float* __restrict__ rs)
{
    const int mode = blockIdx.z;            // 0=q 1=k 2=v
    const f16* X     = (mode == 0) ? Xq : (mode == 1) ? Xk : Xv;
    const f16* W     = (mode == 0) ? Wq : (mode == 1) ? Wk : Wv;
    const float* bias = (mode == 0) ? bq : (mode == 1) ? bk : bv;

    __shared__ f16 Al[128 * 32];   // linear (gload_lds requires); 8 KiB
    __shared__ f16 Bl[128 * 32];

    const int t = threadIdx.x, lane = t & 63, wid = t >> 6;
    const int q15 = lane & 15, g = lane >> 4;
    const int wr = wid >> 1, wc = wid & 1;
    const int m0 = blockIdx.x * 128, n0 = blockIdx.y * 128;

    // staging: per wave, 2 insts/operand; inst covers 16 rows (4 lanes x 16B per 64B row)
    const int srow = wid * 16 + (lane >> 2);
    const int scol = (lane & 3) * 8;
    const f16* Xg = X + (size_t)(m0 + srow) * DMODEL + scol;
    const f16* Wg = W + (size_t)(n0 + srow) * DMODEL + scol;
    f16* al0 = &Al[(wid * 16) * 32];
    f16* al1 = &Al[(wid * 16 + 64) * 32];
    f16* bl0 = &Bl[(wid * 16) * 32];
    f16* bl1 = &Bl[(wid * 16 + 64) * 32];

    f32x4 acc[4][4];
    #pragma unroll
    for (int m = 0; m < 4; m++)
        #pragma unroll
        for (int n = 0; n < 4; n++)
            acc[m][n] = f32x4{0.f, 0.f, 0.f, 0.f};

    for (int k0 = 0; k0 < DMODEL; k0 += 32) {
        __syncthreads();                    // prior-iter LDS reads done
        gload16(Xg + k0, al0);
        gload16(Xg + (size_t)64 * DMODEL + k0, al1);
        gload16(Wg + k0, bl0);
        gload16(Wg + (size_t)64 * DMODEL + k0, bl1);
        __syncthreads();                    // drains vmcnt before any wave reads

        f16x8 a[4], b[4];
        #pragma unroll
        for (int m = 0; m < 4; m++)
            a[m] = *reinterpret_cast<const f16x8*>(&Al[(wr * 64 + m * 16 + q15) * 32 + g * 8]);
        #pragma unroll
        for (int n = 0; n < 4; n++)
            b[n] = *reinterpret_cast<const f16x8*>(&Bl[(wc * 64 + n * 16 + q15) * 32 + g * 8]);
        #pragma unroll
        for (int m = 0; m < 4; m++)
            #pragma unroll
            for (int n = 0; n < 4; n++)
                acc[m][n] = __builtin_amdgcn_mfma_f32_16x16x32_f16(a[m], b[n], acc[m][n], 0, 0, 0);
    }

    const int rowb = m0 + wr * 64, colb = n0 + wc * 64;
    #pragma unroll
    for (int n = 0; n < 4; n++) {
        int cN = colb + n * 16 + q15;
        float bvv = bias[cN];
        int h = cN >> 6, d = cN & 63;
        #pragma unroll
        for (int m = 0; m < 4; m++) {
            #pragma unroll
            for (int rg = 0; rg < 4; rg++) {
                int r = rowb + m * 16 + g * 4 + rg;
                int s = r >> 1, bi = r & 1;                 // row = s*B + b, B=2
                float val = acc[m][n][rg] + bvv;
                if (mode < 2) {
                    float pv = __shfl_xor(val, 1);          // partner col cN^1 == lane^1
                    if (d < 32) {
                        int fi = d >> 1;
                        float cc = rc[s * 16 + fi], ss = rs[s * 16 + fi];
                        val = ((d & 1) == 0) ? val * cc - pv * ss : val * cc + pv * ss;
                    }
                    if (mode == 0) val *= 0.18033688f;      // (1/8)*log2(e)
                    ((mode == 0) ? qo : ko)[(((size_t)bi * NHEADS + h) * S_LEN + s) * HD + d] = (f16)val;
                } else {
                    vo[(((size_t)bi * NHEADS + h) * HD + d) * S_LEN + s] = (f16)val;
                }
            }
        }
    }
}

// ---------------- FAST: f16-input output GEMM, global_load_lds staging ----------------
__global__ __launch_bounds__(256) void out_gemm_h(
    const f16* __restrict__ X, const f16* __restrict__ W,
    const float* __restrict__ bias, float* __restrict__ out)
{
    __shared__ f16 Al[128 * 32];
    __shared__ f16 Bl[128 * 32];

    const int t = threadIdx.x, lane = t & 63, wid = t >> 6;
    const int q15 = lane & 15, g = lane >> 4;
    const int wr = wid >> 1, wc = wid & 1;
    const int m0 = blockIdx.x * 128, n0 = blockIdx.y * 128;

    const int srow = wid * 16 + (lane >> 2);
    const int scol = (lane & 3) * 8;
    const f16* Xg = X + (size_t)(m0 + srow) * DMODEL + scol;
    const f16* Wg = W + (size_t)(n0 + srow) * DMODEL + scol;
    f16* al0 = &Al[(wid * 16) * 32];
    f16* al1 = &Al[(wid * 16 + 64) * 32];
    f16* bl0 = &Bl[(wid * 16) * 32];
    f16* bl1 = &Bl[(wid * 16 + 64) * 32];

    f32x4 acc[4][4];
    #pragma unroll
    for (int m = 0; m < 4; m++)
        #pragma unroll
        for (int n = 0; n < 4; n++)
            acc[m][n] = f32x4{0.f, 0.f, 0.f, 0.f};

    for (int k0 = 0; k0 < DMODEL; k0 += 32) {
        __syncthreads();
        gload16(Xg + k0, al0);
        gload16(Xg + (size_t)64 * DMODEL + k0, al1);
        gload16(Wg + k0, bl0);
        gload16(Wg + (size_t)64 * DMODEL + k0, bl1);
        __syncthreads();

        f16x8 a[4], b[4];
        #pragma unroll
        for (int m = 0; m < 4; m++)
            a[m] = *reinterpret_cast<const f16x8*>(&Al[(wr * 64 + m * 16 + q15) * 32 + g * 8]);
        #pragma unroll
        for (int n = 0; n < 4; n++)
            b[n] = *reinterpret_cast<const f16x8*>(&Bl[(wc * 64 + n * 16 + q15) * 32 + g * 8]);
        #pragma unroll
        for (int m = 0; m < 4; m++)
            #pragma unroll
            for (int n = 0; n < 4; n++)
                acc[m][n] = __builtin_amdgcn_mfma_f32_16x16x32_f16(a[m], b[n], acc[m][n], 0, 0, 0);
    }

    const int rowb = m0 + wr * 64, colb = n0 + wc * 64;
    #pragma unroll
    for (int n = 0; n < 4; n++) {
        int cN = colb + n * 16 + q15;
        float bvv = bias[cN];
        #pragma unroll
        for (int m = 0; m < 4; m++) {
            #pragma unroll
            for (int rg = 0; rg < 4; rg++) {
                int r = rowb + m * 16 + g * 4 + rg;
                out[(size_t)r * DMODEL + cN] = acc[m][n][rg] + bvv;
            }
        }
    }
}

// ---------------- FALLBACK: fp32-input projection GEMM (r11) ----------------
__global__ __launch_bounds__(256) void proj_gemm(
    const float* __restrict__ Xq, const float* __restrict__ Xk, const float* __restrict__ Xv,
    const float* __restrict__ Wq, const float* __restrict__ Wk, const float* __restrict__ Wv,
    const float* __restrict__ bq, const float* __restrict__ bk, const float* __restrict__ bv,
    f16* __restrict__ qo, f16* __restrict__ ko, f16* __restrict__ vo,
    const float* __restrict__ rc, const float* __restrict__ rs)
{
    const int mode = blockIdx.z;
    const float* X    = (mode == 0) ? Xq : (mode == 1) ? Xk : Xv;
    const float* W    = (mode == 0) ? Wq : (mode == 1) ? Wk : Wv;
    const float* bias = (mode == 0) ? bq : (mode == 1) ? bk : bv;

    __shared__ f16 Al[128 * 40];
    __shared__ f16 Bl[128 * 40];

    const int t = threadIdx.x;
    const int lane = t & 63, wid = t >> 6;
    const int wr = wid >> 1, wc = wid & 1;
    const int m0 = blockIdx.x * 128, n0 = blockIdx.y * 128;

    f32x4 acc[4][4];
    #pragma unroll
    for (int m = 0; m < 4; m++)
        #pragma unroll
        for (int n = 0; n < 4; n++)
            acc[m][n] = f32x4{0.f, 0.f, 0.f, 0.f};

    for (int k0 = 0; k0 < DMODEL; k0 += 32) {
        __syncthreads();
        #pragma unroll
        for (int i = 0; i < 2; i++) {
            int e = (i * 256 + t) * 8;
            int r = e >> 5, c = e & 31;
            {
                const float* src = &X[(size_t)(m0 + r) * DMODEL + k0 + c];
                float4 v0 = *reinterpret_cast<const float4*>(src);
                float4 v1 = *reinterpret_cast<const float4*>(src + 4);
                f16x8 h = { (f16)v0.x, (f16)v0.y, (f16)v0.z, (f16)v0.w,
                            (f16)v1.x, (f16)v1.y, (f16)v1.z, (f16)v1.w };
                *reinterpret_cast<f16x8*>(&Al[r * 40 + c]) = h;
            }
            {
                const float* src = &W[(size_t)(n0 + r) * DMODEL + k0 + c];
                float4 v0 = *reinterpret_cast<const float4*>(src);
                float4 v1 = *reinterpret_cast<const float4*>(src + 4);
                f16x8 h = { (f16)v0.x, (f16)v0.y, (f16)v0.z, (f16)v0.w,
                            (f16)v1.x, (f16)v1.y, (f16)v1.z, (f16)v1.w };
                *reinterpret_cast<f16x8*>(&Bl[r * 40 + c]) = h;
            }
        }
        __syncthreads();
        f16x8 a[4], b[4];
        #pragma unroll
        for (int m = 0; m < 4; m++)
            a[m] = *reinterpret_cast<const f16x8*>(&Al[(wr * 64 + m * 16 + (lane & 15)) * 40 + (lane >> 4) * 8]);
        #pragma unroll
        for (int n = 0; n < 4; n++)
            b[n] = *reinterpret_cast<const f16x8*>(&Bl[(wc * 64 + n * 16 + (lane & 15)) * 40 + (lane >> 4) * 8]);
        #pragma unroll
        for (int m = 0; m < 4; m++)
            #pragma unroll
            for (int n = 0; n < 4; n++)
                acc[m][n] = __builtin_amdgcn_mfma_f32_16x16x32_f16(a[m], b[n], acc[m][n], 0, 0, 0);
    }

    const int rowb = m0 + wr * 64, colb = n0 + wc * 64;
    #pragma unroll
    for (int n = 0; n < 4; n++) {
        int cN = colb + n * 16 + (lane & 15);
        float bvv = bias[cN];
        int h = cN >> 6, d = cN & 63;
        #pragma unroll
        for (int m = 0; m < 4; m++) {
            #pragma unroll
            for (int rg = 0; rg < 4; rg++) {
                int r = rowb + m * 16 + (lane >> 4) * 4 + rg;
                int s = r >> 1, bi = r & 1;
                float val = acc[m][n][rg] + bvv;
                if (mode < 2) {
                    float pv = __shfl_xor(val, 1);
                    if (d < 32) {
                        int fi = d >> 1;
                        float cc = rc[s * 16 + fi], ss = rs[s * 16 + fi];
                        val = ((d & 1) == 0) ? val * cc - pv * ss : val * cc + pv * ss;
                    }
                    if (mode == 0) val *= 0.18033688f;
                    ((mode == 0) ? qo : ko)[(((size_t)bi * NHEADS + h) * S_LEN + s) * HD + d] = (f16)val;
                } else {
                    vo[(((size_t)bi * NHEADS + h) * HD + d) * S_LEN + s] = (f16)val;
                }
            }
        }
    }
}

// ---------------- FALLBACK: output projection (r11) ----------------
__global__ __launch_bounds__(256) void out_gemm(
    const f16* __restrict__ X, const float* __restrict__ W,
    const float* __restrict__ bias, float* __restrict__ out)
{
    __shared__ f16 Al[128 * 40];
    __shared__ f16 Bl[128 * 40];

    const int t = threadIdx.x;
    const int lane = t & 63, wid = t >> 6;
    const int wr = wid >> 1, wc = wid & 1;
    const int m0 = blockIdx.x * 128, n0 = blockIdx.y * 128;

    f32x4 acc[4][4];
    #pragma unroll
    for (int m = 0; m < 4; m++)
        #pragma unroll
        for (int n = 0; n < 4; n++)
            acc[m][n] = f32x4{0.f, 0.f, 0.f, 0.f};

    for (int k0 = 0; k0 < DMODEL; k0 += 32) {
        __syncthreads();
        #pragma unroll
        for (int i = 0; i < 2; i++) {
            int e = (i * 256 + t) * 8;
            int r = e >> 5, c = e & 31;
            *reinterpret_cast<uint4*>(&Al[r * 40 + c]) =
                *reinterpret_cast<const uint4*>(&X[(size_t)(m0 + r) * DMODEL + k0 + c]);
            {
                const float* src = &W[(size_t)(n0 + r) * DMODEL + k0 + c];
                float4 v0 = *reinterpret_cast<const float4*>(src);
                float4 v1 = *reinterpret_cast<const float4*>(src + 4);
                f16x8 h = { (f16)v0.x, (f16)v0.y, (f16)v0.z, (f16)v0.w,
                            (f16)v1.x, (f16)v1.y, (f16)v1.z, (f16)v1.w };
                *reinterpret_cast<f16x8*>(&Bl[r * 40 + c]) = h;
            }
        }
        __syncthreads();
        f16x8 a[4], b[4];
        #pragma unroll
        for (int m = 0; m < 4; m++)
            a[m] = *reinterpret_cast<const f16x8*>(&Al[(wr * 64 + m * 16 + (lane & 15)) * 40 + (lane >> 4) * 8]);
        #pragma unroll
        for (int n = 0; n < 4; n++)
            b[n] = *reinterpret_cast<const f16x8*>(&Bl[(wc * 64 + n * 16 + (lane & 15)) * 40 + (lane >> 4) * 8]);
        #pragma unroll
        for (int m = 0; m < 4; m++)
            #pragma unroll
            for (int n = 0; n < 4; n++)
                acc[m][n] = __builtin_amdgcn_mfma_f32_16x16x32_f16(a[m], b[n], acc[m][n], 0, 0, 0);
    }

    const int rowb = m0 + wr * 64, colb = n0 + wc * 64;
    #pragma unroll
    for (int n = 0; n < 4; n++) {
        int cN = colb + n * 16 + (lane & 15);
        float bvv = bias[cN];
        #pragma unroll
        for (int m = 0; m < 4; m++) {
            #pragma unroll
            for (int rg = 0; rg < 4; rg++) {
                int r = rowb + m * 16 + (lane >> 4) * 4 + rg;
                out[(size_t)r * DMODEL + cN] = acc[m][n][rg] + bvv;
            }
        }
    }
}

// ---------------- flash attention: 8 waves x 16 q-rows, QBLK=128 (r11, unchanged) ----------------
__global__ __launch_bounds__(512) void attn_fwd(
    const f16* __restrict__ qb, const f16* __restrict__ kb,
    const f16* __restrict__ vt, f16* __restrict__ ctx)
{
    __shared__ f16 Kl[64 * LD];
    __shared__ f16 Vl[64 * LD];
    __shared__ f16 Pl[8 * 16 * LD];

    const int t = threadIdx.x, lane = t & 63, wid = t >> 6;
    const int q15 = lane & 15, g = lane >> 4;
    const int bh = blockIdx.y;
    const int q0 = blockIdx.x * 128 + wid * 16;

    const f16* qptr = qb + ((size_t)bh * S_LEN + q0) * HD;
    f16x8 qf0 = *reinterpret_cast<const f16x8*>(&qptr[q15 * HD + g * 8]);
    f16x8 qf1 = *reinterpret_cast<const f16x8*>(&qptr[q15 * HD + g * 8 + 32]);

    f32x4 ctxa[4];
    #pragma unroll
    for (int i = 0; i < 4; i++) ctxa[i] = f32x4{0.f, 0.f, 0.f, 0.f};
    float mrun = -3.0e38f, lrun = 0.f;

    const int r_st = t >> 3, c_st = (t & 7) * 8;
    const f16* kg = kb + (size_t)bh * S_LEN * HD + (size_t)r_st * HD + c_st;
    const f16* vg = vt + (size_t)bh * HD * S_LEN + (size_t)r_st * S_LEN + c_st;
    f16* kl_st = &Kl[r_st * LD + c_st];
    f16* vl_st = &Vl[r_st * LD + c_st];
    f16* pbase = &Pl[wid * (16 * LD)];

    for (int kt = 0; kt < S_LEN / 64; kt++) {
        __syncthreads();
        *reinterpret_cast<uint4*>(kl_st) = *reinterpret_cast<const uint4*>(kg);
        *reinterpret_cast<uint4*>(vl_st) = *reinterpret_cast<const uint4*>(vg);
        kg += 64 * HD;
        vg += 64;
        __syncthreads();

        f32x4 sc[4];
        __builtin_amdgcn_s_setprio(1);
        #pragma unroll
        for (int f = 0; f < 4; f++) {
            f16x8 kf0 = *reinterpret_cast<const f16x8*>(&Kl[(f * 16 + q15) * LD + g * 8]);
            f16x8 kf1 = *reinterpret_cast<const f16x8*>(&Kl[(f * 16 + q15) * LD + g * 8 + 32]);
            f32x4 z = {0.f, 0.f, 0.f, 0.f};
            z = __builtin_amdgcn_mfma_f32_16x16x32_f16(kf0, qf0, z, 0, 0, 0);
            sc[f] = __builtin_amdgcn_mfma_f32_16x16x32_f16(kf1, qf1, z, 0, 0, 0);
        }
        __builtin_amdgcn_s_setprio(0);

        float pmf[4];
        #pragma unroll
        for (int f = 0; f < 4; f++)
            pmf[f] = fmaxf(fmaxf(sc[f][0], sc[f][1]), fmaxf(sc[f][2], sc[f][3]));
        float pmax = fmaxf(fmaxf(pmf[0], pmf[1]), fmaxf(pmf[2], pmf[3]));
        pmax = fmaxf(pmax, __shfl_xor(pmax, 16));
        pmax = fmaxf(pmax, __shfl_xor(pmax, 32));
        float mnew = fmaxf(mrun, pmax);
        float scale = __builtin_amdgcn_exp2f(mrun - mnew);
        float tsum = 0.f;
        #pragma unroll
        for (int f = 0; f < 4; f++)
            #pragma unroll
            for (int rg = 0; rg < 4; rg++) {
                float p = __builtin_amdgcn_exp2f(sc[f][rg] - mnew);
                sc[f][rg] = p;
                tsum += p;
            }
        tsum += __shfl_xor(tsum, 16);
        tsum += __shfl_xor(tsum, 32);
        lrun = lrun * scale + tsum;
        mrun = mnew;
        #pragma unroll
        for (int n = 0; n < 4; n++) {
            ctxa[n][0] *= scale; ctxa[n][1] *= scale;
            ctxa[n][2] *= scale; ctxa[n][3] *= scale;
        }

        #pragma unroll
        for (int f = 0; f < 4; f++) {
            f16x4 pw = { (f16)sc[f][0], (f16)sc[f][1], (f16)sc[f][2], (f16)sc[f][3] };
            *reinterpret_cast<f16x4*>(&pbase[q15 * LD + f * 16 + g * 4]) = pw;
        }
        asm volatile("s_waitcnt lgkmcnt(0)" ::: "memory");
        __builtin_amdgcn_sched_barrier(0);

        __builtin_amdgcn_s_setprio(1);
        #pragma unroll
        for (int c = 0; c < 2; c++) {
            f16x8 pfr = *reinterpret_cast<const f16x8*>(&pbase[q15 * LD + g * 8 + c * 32]);
            #pragma unroll
            for (int n = 0; n < 4; n++) {
                f16x8 vf = *reinterpret_cast<const f16x8*>(&Vl[(n * 16 + q15) * LD + g * 8 + c * 32]);
                ctxa[n] = __builtin_amdgcn_mfma_f32_16x16x32_f16(vf, pfr, ctxa[n], 0, 0, 0);
            }
        }
        __builtin_amdgcn_s_setprio(0);
    }

    const int bi = bh >> 4, h = bh & 15;
    const int s = q0 + q15;
    float inv = 1.0f / lrun;
    f16* outp = &ctx[((size_t)s * BATCH + bi) * DMODEL + h * HD];
    #pragma unroll
    for (int n = 0; n < 4; n++) {
        f16x4 o = { (f16)(ctxa[n][0] * inv), (f16)(ctxa[n][1] * inv),
                    (f16)(ctxa[n][2] * inv), (f16)(ctxa[n][3] * inv) };
        *reinterpret_cast<f16x4*>(&outp[n * 16 + g * 4]) = o;
    }
}

// ---------------- launch ----------------
extern "C" void kernel_launch(void* const* d_in, const int* in_sizes, int n_in,
                              void* d_out, int out_size, void* d_ws, size_t ws_size,
                              hipStream_t stream)
{
    const float* Q  = (const float*)d_in[0];
    const float* K  = (const float*)d_in[1];
    const float* V  = (const float*)d_in[2];
    const float* Wq = (const float*)d_in[3];
    const float* bq = (const float*)d_in[4];
    const float* Wk = (const float*)d_in[5];
    const float* bk = (const float*)d_in[6];
    const float* Wv = (const float*)d_in[7];
    const float* bv = (const float*)d_in[8];
    const float* Wo = (const float*)d_in[9];
    const float* bo = (const float*)d_in[10];
    float* out = (float*)d_out;

    char* w = (char*)d_ws;
    const size_t MBc = 1024 * 1024;
    const size_t NEED_FAST = 56 * MBc + 256 * 1024;   // 56.25 MiB

    if (ws_size >= NEED_FAST) {
        // FAST layout:
        //   [0,32M)      f16 cvt block: Xq,Xk,Xv (8M ea) + Wq,Wk,Wv,Wo (2M ea)
        //   [32M,32.25M) rc, rs
        //   [32.25M,56.25M) qbuf, kbuf, vtb (8M ea)
        //   ctxb overlays Xqh [0,8M) (dead after proj)
        f16* cvtb = (f16*)w;
        f16* Xqh = cvtb;
        f16* Xkh = cvtb + 4194304;
        f16* Xvh = cvtb + 8388608;
        f16* Wqh = cvtb + 12582912;
        f16* Wkh = cvtb + 13631488;
        f16* Wvh = cvtb + 14680064;
        f16* Woh = cvtb + 15728640;
        float* rc = (float*)(w + 32 * MBc);
        float* rs = rc + 32768;
        f16* qbuf = (f16*)(w + 32 * MBc + 256 * 1024);
        f16* kbuf = qbuf + 4194304;
        f16* vtb  = kbuf + 4194304;
        f16* ctxb = Xqh;

        rope_table<<<(S_LEN * 16) / 256, 256, 0, stream>>>(rc, rs);
        cvt_all<<<dim3(2048, 7), 256, 0, stream>>>(Q, K, V, Wq, Wk, Wv, Wo, cvtb);
        proj_gemm_h<<<dim3(MROWS / 128, DMODEL / 128, 3), 256, 0, stream>>>(
            Xqh, Xkh, Xvh, Wqh, Wkh, Wvh, bq, bk, bv, qbuf, kbuf, vtb, rc, rs);
        attn_fwd<<<dim3(S_LEN / 128, BATCH * NHEADS), 512, 0, stream>>>(qbuf, kbuf, vtb, ctxb);
        out_gemm_h<<<dim3(MROWS / 128, DMODEL / 128), 256, 0, stream>>>(ctxb, Woh, bo, out);
    } else {
        // FALLBACK layout (r11): 32.25 MiB
        const size_t szT = (size_t)S_LEN * 16 * sizeof(float);
        const size_t szQ = (size_t)MROWS * DMODEL * sizeof(f16);
        float* rc  = (float*)(w);
        float* rs  = (float*)(w + szT);
        f16* qbuf = (f16*)(w + 2 * szT);
        f16* kbuf = (f16*)(w + 2 * szT + szQ);
        f16* vtb  = (f16*)(w + 2 * szT + 2 * szQ);
        f16* ctxb = (f16*)(w + 2 * szT + 3 * szQ);

        rope_table<<<(S_LEN * 16) / 256, 256, 0, stream>>>(rc, rs);
        proj_gemm<<<dim3(MROWS / 128, DMODEL / 128, 3), 256, 0, stream>>>(
            Q, K, V, Wq, Wk, Wv, bq, bk, bv, qbuf, kbuf, vtb, rc, rs);
        attn_fwd<<<dim3(S_LEN / 128, BATCH * NHEADS), 512, 0, stream>>>(qbuf, kbuf, vtb, ctxb);
        out_gemm<<<dim3(MROWS / 128, DMODEL / 128), 256, 0, stream>>>(ctxb, Wo, bo, out);
    }
}

// Round 13
// 156.381 us; speedup vs baseline: 2.6778x; 1.0164x over previous
//
#include <hip/hip_runtime.h>
#include <hip/hip_bf16.h>
#include <hip/hip_fp16.h>

#define S_LEN  2048
#define BATCH  2
#define DMODEL 1024
#define NHEADS 16
#define HD     64
#define MROWS  4096   // S*B
#define LD     72     // attn P LDS stride (padded, per-wave)

using f16 = _Float16;
typedef __attribute__((ext_vector_type(8))) _Float16 f16x8;
typedef __attribute__((ext_vector_type(4))) _Float16 f16x4;
typedef __attribute__((ext_vector_type(4))) float    f32x4;

// async global->LDS, 16B per lane; LDS dest = wave-uniform base + lane*16
__device__ __forceinline__ void gload16(const void* g, void* l)
{
    __builtin_amdgcn_global_load_lds((const __attribute__((address_space(1))) void*)g,
                                     (__attribute__((address_space(3))) void*)l, 16, 0, 0);
}

// ---------------- RoPE cos/sin table: [S][16] ----------------
__global__ __launch_bounds__(256) void rope_table(float* __restrict__ rc, float* __restrict__ rs)
{
    int idx = blockIdx.x * 256 + threadIdx.x;   // S*16 threads
    int s = idx >> 4, i = idx & 15;
    float inv = powf(10000.0f, -(float)(2 * i) / 32.0f);
    float ang = (float)s * inv;
    rc[idx] = cosf(ang);
    rs[idx] = sinf(ang);
}

// ---------------- fp32 -> f16 conversion of all 7 tensors into one ws block ----------------
__global__ __launch_bounds__(256) void cvt_all(
    const float* __restrict__ Q, const float* __restrict__ K, const float* __restrict__ V,
    const float* __restrict__ Wq, const float* __restrict__ Wk, const float* __restrict__ Wv,
    const float* __restrict__ Wo, f16* __restrict__ dst)
{
    const int z = blockIdx.y;
    const float* src; size_t off; int n8;
    switch (z) {
        case 0:  src = Q;  off = 0;        n8 = 524288; break;
        case 1:  src = K;  off = 4194304;  n8 = 524288; break;
        case 2:  src = V;  off = 8388608;  n8 = 524288; break;
        case 3:  src = Wq; off = 12582912; n8 = 131072; break;
        case 4:  src = Wk; off = 13631488; n8 = 131072; break;
        case 5:  src = Wv; off = 14680064; n8 = 131072; break;
        default: src = Wo; off = 15728640; n8 = 131072; break;
    }
    int i = blockIdx.x * 256 + threadIdx.x;
    if (i >= n8) return;
    const float4* s = reinterpret_cast<const float4*>(src) + (size_t)i * 2;
    float4 v0 = s[0], v1 = s[1];
    f16x8 h = { (f16)v0.x, (f16)v0.y, (f16)v0.z, (f16)v0.w,
                (f16)v1.x, (f16)v1.y, (f16)v1.z, (f16)v1.w };
    reinterpret_cast<f16x8*>(dst + off)[i] = h;
}

// ---------------- f16-input projection GEMM, global_load_lds staging ----------------
__global__ __launch_bounds__(256) void proj_gemm_h(
    const f16* __restrict__ Xq, const f16* __restrict__ Xk, const f16* __restrict__ Xv,
    const f16* __restrict__ Wq, const f16* __restrict__ Wk, const f16* __restrict__ Wv,
    const float* __restrict__ bq, const float* __restrict__ bk, const float* __restrict__ bv,
    f16* __restrict__ qo, f16* __restrict__ ko, f16* __restrict__ vo,
    const float* __restrict__ rc, const float* __restrict__ rs)
{
    const int mode = blockIdx.z;            // 0=q 1=k 2=v
    const f16* X     = (mode == 0) ? Xq : (mode == 1) ? Xk : Xv;
    const f16* W     = (mode == 0) ? Wq : (mode == 1) ? Wk : Wv;
    const float* bias = (mode == 0) ? bq : (mode == 1) ? bk : bv;

    __shared__ f16 Al[128 * 32];
    __shared__ f16 Bl[128 * 32];

    const int t = threadIdx.x, lane = t & 63, wid = t >> 6;
    const int q15 = lane & 15, g = lane >> 4;
    const int wr = wid >> 1, wc = wid & 1;
    const int m0 = blockIdx.x * 128, n0 = blockIdx.y * 128;

    const int srow = wid * 16 + (lane >> 2);
    const int scol = (lane & 3) * 8;
    const f16* Xg = X + (size_t)(m0 + srow) * DMODEL + scol;
    const f16* Wg = W + (size_t)(n0 + srow) * DMODEL + scol;
    f16* al0 = &Al[(wid * 16) * 32];
    f16* al1 = &Al[(wid * 16 + 64) * 32];
    f16* bl0 = &Bl[(wid * 16) * 32];
    f16* bl1 = &Bl[(wid * 16 + 64) * 32];

    f32x4 acc[4][4];
    #pragma unroll
    for (int m = 0; m < 4; m++)
        #pragma unroll
        for (int n = 0; n < 4; n++)
            acc[m][n] = f32x4{0.f, 0.f, 0.f, 0.f};

    for (int k0 = 0; k0 < DMODEL; k0 += 32) {
        __syncthreads();
        gload16(Xg + k0, al0);
        gload16(Xg + (size_t)64 * DMODEL + k0, al1);
        gload16(Wg + k0, bl0);
        gload16(Wg + (size_t)64 * DMODEL + k0, bl1);
        __syncthreads();

        f16x8 a[4], b[4];
        #pragma unroll
        for (int m = 0; m < 4; m++)
            a[m] = *reinterpret_cast<const f16x8*>(&Al[(wr * 64 + m * 16 + q15) * 32 + g * 8]);
        #pragma unroll
        for (int n = 0; n < 4; n++)
            b[n] = *reinterpret_cast<const f16x8*>(&Bl[(wc * 64 + n * 16 + q15) * 32 + g * 8]);
        #pragma unroll
        for (int m = 0; m < 4; m++)
            #pragma unroll
            for (int n = 0; n < 4; n++)
                acc[m][n] = __builtin_amdgcn_mfma_f32_16x16x32_f16(a[m], b[n], acc[m][n], 0, 0, 0);
    }

    const int rowb = m0 + wr * 64, colb = n0 + wc * 64;
    #pragma unroll
    for (int n = 0; n < 4; n++) {
        int cN = colb + n * 16 + q15;
        float bvv = bias[cN];
        int h = cN >> 6, d = cN & 63;
        #pragma unroll
        for (int m = 0; m < 4; m++) {
            #pragma unroll
            for (int rg = 0; rg < 4; rg++) {
                int r = rowb + m * 16 + g * 4 + rg;
                int s = r >> 1, bi = r & 1;
                float val = acc[m][n][rg] + bvv;
                if (mode < 2) {
                    float pv = __shfl_xor(val, 1);
                    if (d < 32) {
                        int fi = d >> 1;
                        float cc = rc[s * 16 + fi], ss = rs[s * 16 + fi];
                        val = ((d & 1) == 0) ? val * cc - pv * ss : val * cc + pv * ss;
                    }
                    if (mode == 0) val *= 0.18033688f;      // (1/8)*log2(e)
                    ((mode == 0) ? qo : ko)[(((size_t)bi * NHEADS + h) * S_LEN + s) * HD + d] = (f16)val;
                } else {
                    vo[(((size_t)bi * NHEADS + h) * HD + d) * S_LEN + s] = (f16)val;
                }
            }
        }
    }
}

// ---------------- f16-input output GEMM, global_load_lds staging ----------------
__global__ __launch_bounds__(256) void out_gemm_h(
    const f16* __restrict__ X, const f16* __restrict__ W,
    const float* __restrict__ bias, float* __restrict__ out)
{
    __shared__ f16 Al[128 * 32];
    __shared__ f16 Bl[128 * 32];

    const int t = threadIdx.x, lane = t & 63, wid = t >> 6;
    const int q15 = lane & 15, g = lane >> 4;
    const int wr = wid >> 1, wc = wid & 1;
    const int m0 = blockIdx.x * 128, n0 = blockIdx.y * 128;

    const int srow = wid * 16 + (lane >> 2);
    const int scol = (lane & 3) * 8;
    const f16* Xg = X + (size_t)(m0 + srow) * DMODEL + scol;
    const f16* Wg = W + (size_t)(n0 + srow) * DMODEL + scol;
    f16* al0 = &Al[(wid * 16) * 32];
    f16* al1 = &Al[(wid * 16 + 64) * 32];
    f16* bl0 = &Bl[(wid * 16) * 32];
    f16* bl1 = &Bl[(wid * 16 + 64) * 32];

    f32x4 acc[4][4];
    #pragma unroll
    for (int m = 0; m < 4; m++)
        #pragma unroll
        for (int n = 0; n < 4; n++)
            acc[m][n] = f32x4{0.f, 0.f, 0.f, 0.f};

    for (int k0 = 0; k0 < DMODEL; k0 += 32) {
        __syncthreads();
        gload16(Xg + k0, al0);
        gload16(Xg + (size_t)64 * DMODEL + k0, al1);
        gload16(Wg + k0, bl0);
        gload16(Wg + (size_t)64 * DMODEL + k0, bl1);
        __syncthreads();

        f16x8 a[4], b[4];
        #pragma unroll
        for (int m = 0; m < 4; m++)
            a[m] = *reinterpret_cast<const f16x8*>(&Al[(wr * 64 + m * 16 + q15) * 32 + g * 8]);
        #pragma unroll
        for (int n = 0; n < 4; n++)
            b[n] = *reinterpret_cast<const f16x8*>(&Bl[(wc * 64 + n * 16 + q15) * 32 + g * 8]);
        #pragma unroll
        for (int m = 0; m < 4; m++)
            #pragma unroll
            for (int n = 0; n < 4; n++)
                acc[m][n] = __builtin_amdgcn_mfma_f32_16x16x32_f16(a[m], b[n], acc[m][n], 0, 0, 0);
    }

    const int rowb = m0 + wr * 64, colb = n0 + wc * 64;
    #pragma unroll
    for (int n = 0; n < 4; n++) {
        int cN = colb + n * 16 + q15;
        float bvv = bias[cN];
        #pragma unroll
        for (int m = 0; m < 4; m++) {
            #pragma unroll
            for (int rg = 0; rg < 4; rg++) {
                int r = rowb + m * 16 + g * 4 + rg;
                out[(size_t)r * DMODEL + cN] = acc[m][n][rg] + bvv;
            }
        }
    }
}

// ---------------- FALLBACK: fp32-input projection GEMM ----------------
__global__ __launch_bounds__(256) void proj_gemm(
    const float* __restrict__ Xq, const float* __restrict__ Xk, const float* __restrict__ Xv,
    const float* __restrict__ Wq, const float* __restrict__ Wk, const float* __restrict__ Wv,
    const float* __restrict__ bq, const float* __restrict__ bk, const float* __restrict__ bv,
    f16* __restrict__ qo, f16* __restrict__ ko, f16* __restrict__ vo,
    const float* __restrict__ rc, const float* __restrict__ rs)
{
    const int mode = blockIdx.z;
    const float* X    = (mode == 0) ? Xq : (mode == 1) ? Xk : Xv;
    const float* W    = (mode == 0) ? Wq : (mode == 1) ? Wk : Wv;
    const float* bias = (mode == 0) ? bq : (mode == 1) ? bk : bv;

    __shared__ f16 Al[128 * 40];
    __shared__ f16 Bl[128 * 40];

    const int t = threadIdx.x;
    const int lane = t & 63, wid = t >> 6;
    const int wr = wid >> 1, wc = wid & 1;
    const int m0 = blockIdx.x * 128, n0 = blockIdx.y * 128;

    f32x4 acc[4][4];
    #pragma unroll
    for (int m = 0; m < 4; m++)
        #pragma unroll
        for (int n = 0; n < 4; n++)
            acc[m][n] = f32x4{0.f, 0.f, 0.f, 0.f};

    for (int k0 = 0; k0 < DMODEL; k0 += 32) {
        __syncthreads();
        #pragma unroll
        for (int i = 0; i < 2; i++) {
            int e = (i * 256 + t) * 8;
            int r = e >> 5, c = e & 31;
            {
                const float* src = &X[(size_t)(m0 + r) * DMODEL + k0 + c];
                float4 v0 = *reinterpret_cast<const float4*>(src);
                float4 v1 = *reinterpret_cast<const float4*>(src + 4);
                f16x8 h = { (f16)v0.x, (f16)v0.y, (f16)v0.z, (f16)v0.w,
                            (f16)v1.x, (f16)v1.y, (f16)v1.z, (f16)v1.w };
                *reinterpret_cast<f16x8*>(&Al[r * 40 + c]) = h;
            }
            {
                const float* src = &W[(size_t)(n0 + r) * DMODEL + k0 + c];
                float4 v0 = *reinterpret_cast<const float4*>(src);
                float4 v1 = *reinterpret_cast<const float4*>(src + 4);
                f16x8 h = { (f16)v0.x, (f16)v0.y, (f16)v0.z, (f16)v0.w,
                            (f16)v1.x, (f16)v1.y, (f16)v1.z, (f16)v1.w };
                *reinterpret_cast<f16x8*>(&Bl[r * 40 + c]) = h;
            }
        }
        __syncthreads();
        f16x8 a[4], b[4];
        #pragma unroll
        for (int m = 0; m < 4; m++)
            a[m] = *reinterpret_cast<const f16x8*>(&Al[(wr * 64 + m * 16 + (lane & 15)) * 40 + (lane >> 4) * 8]);
        #pragma unroll
        for (int n = 0; n < 4; n++)
            b[n] = *reinterpret_cast<const f16x8*>(&Bl[(wc * 64 + n * 16 + (lane & 15)) * 40 + (lane >> 4) * 8]);
        #pragma unroll
        for (int m = 0; m < 4; m++)
            #pragma unroll
            for (int n = 0; n < 4; n++)
                acc[m][n] = __builtin_amdgcn_mfma_f32_16x16x32_f16(a[m], b[n], acc[m][n], 0, 0, 0);
    }

    const int rowb = m0 + wr * 64, colb = n0 + wc * 64;
    #pragma unroll
    for (int n = 0; n < 4; n++) {
        int cN = colb + n * 16 + (lane & 15);
        float bvv = bias[cN];
        int h = cN >> 6, d = cN & 63;
        #pragma unroll
        for (int m = 0; m < 4; m++) {
            #pragma unroll
            for (int rg = 0; rg < 4; rg++) {
                int r = rowb + m * 16 + (lane >> 4) * 4 + rg;
                int s = r >> 1, bi = r & 1;
                float val = acc[m][n][rg] + bvv;
                if (mode < 2) {
                    float pv = __shfl_xor(val, 1);
                    if (d < 32) {
                        int fi = d >> 1;
                        float cc = rc[s * 16 + fi], ss = rs[s * 16 + fi];
                        val = ((d & 1) == 0) ? val * cc - pv * ss : val * cc + pv * ss;
                    }
                    if (mode == 0) val *= 0.18033688f;
                    ((mode == 0) ? qo : ko)[(((size_t)bi * NHEADS + h) * S_LEN + s) * HD + d] = (f16)val;
                } else {
                    vo[(((size_t)bi * NHEADS + h) * HD + d) * S_LEN + s] = (f16)val;
                }
            }
        }
    }
}

// ---------------- FALLBACK: output projection ----------------
__global__ __launch_bounds__(256) void out_gemm(
    const f16* __restrict__ X, const float* __restrict__ W,
    const float* __restrict__ bias, float* __restrict__ out)
{
    __shared__ f16 Al[128 * 40];
    __shared__ f16 Bl[128 * 40];

    const int t = threadIdx.x;
    const int lane = t & 63, wid = t >> 6;
    const int wr = wid >> 1, wc = wid & 1;
    const int m0 = blockIdx.x * 128, n0 = blockIdx.y * 128;

    f32x4 acc[4][4];
    #pragma unroll
    for (int m = 0; m < 4; m++)
        #pragma unroll
        for (int n = 0; n < 4; n++)
            acc[m][n] = f32x4{0.f, 0.f, 0.f, 0.f};

    for (int k0 = 0; k0 < DMODEL; k0 += 32) {
        __syncthreads();
        #pragma unroll
        for (int i = 0; i < 2; i++) {
            int e = (i * 256 + t) * 8;
            int r = e >> 5, c = e & 31;
            *reinterpret_cast<uint4*>(&Al[r * 40 + c]) =
                *reinterpret_cast<const uint4*>(&X[(size_t)(m0 + r) * DMODEL + k0 + c]);
            {
                const float* src = &W[(size_t)(n0 + r) * DMODEL + k0 + c];
                float4 v0 = *reinterpret_cast<const float4*>(src);
                float4 v1 = *reinterpret_cast<const float4*>(src + 4);
                f16x8 h = { (f16)v0.x, (f16)v0.y, (f16)v0.z, (f16)v0.w,
                            (f16)v1.x, (f16)v1.y, (f16)v1.z, (f16)v1.w };
                *reinterpret_cast<f16x8*>(&Bl[r * 40 + c]) = h;
            }
        }
        __syncthreads();
        f16x8 a[4], b[4];
        #pragma unroll
        for (int m = 0; m < 4; m++)
            a[m] = *reinterpret_cast<const f16x8*>(&Al[(wr * 64 + m * 16 + (lane & 15)) * 40 + (lane >> 4) * 8]);
        #pragma unroll
        for (int n = 0; n < 4; n++)
            b[n] = *reinterpret_cast<const f16x8*>(&Bl[(wc * 64 + n * 16 + (lane & 15)) * 40 + (lane >> 4) * 8]);
        #pragma unroll
        for (int m = 0; m < 4; m++)
            #pragma unroll
            for (int n = 0; n < 4; n++)
                acc[m][n] = __builtin_amdgcn_mfma_f32_16x16x32_f16(a[m], b[n], acc[m][n], 0, 0, 0);
    }

    const int rowb = m0 + wr * 64, colb = n0 + wc * 64;
    #pragma unroll
    for (int n = 0; n < 4; n++) {
        int cN = colb + n * 16 + (lane & 15);
        float bvv = bias[cN];
        #pragma unroll
        for (int m = 0; m < 4; m++) {
            #pragma unroll
            for (int rg = 0; rg < 4; rg++) {
                int r = rowb + m * 16 + (lane >> 4) * 4 + rg;
                out[(size_t)r * DMODEL + cN] = acc[m][n][rg] + bvv;
            }
        }
    }
}

// ---------------- flash attention: gload_lds double-buffered K/V, 1 barrier/iter ----------------
// grid (S/128, B*H); 8 waves x 16 q-rows. K/V linear [64][64] LDS, XOR-swizzled source cols
// (slot' = slot ^ (row&7)); reads apply the same XOR. One __syncthreads per iter drains vmcnt.
__global__ __launch_bounds__(512) void attn_fwd(
    const f16* __restrict__ qb, const f16* __restrict__ kb,
    const f16* __restrict__ vt, f16* __restrict__ ctx)
{
    __shared__ f16 Kl[2][64 * 64];
    __shared__ f16 Vl[2][64 * 64];
    __shared__ f16 Pl[8 * 16 * LD];

    const int t = threadIdx.x, lane = t & 63, wid = t >> 6;
    const int q15 = lane & 15, g = lane >> 4;
    const int sw = q15 & 7;                 // read-side XOR key (row&7 == q15&7 for rows f*16+q15)
    const int bh = blockIdx.y;
    const int q0 = blockIdx.x * 128 + wid * 16;

    // Q B-frag: lane holds Q[q15][g*8..+7] and +32
    const f16* qptr = qb + ((size_t)bh * S_LEN + q0) * HD;
    f16x8 qf0 = *reinterpret_cast<const f16x8*>(&qptr[q15 * HD + g * 8]);
    f16x8 qf1 = *reinterpret_cast<const f16x8*>(&qptr[q15 * HD + g * 8 + 32]);

    f32x4 ctxa[4];
    #pragma unroll
    for (int i = 0; i < 4; i++) ctxa[i] = f32x4{0.f, 0.f, 0.f, 0.f};
    float mrun = -3.0e38f, lrun = 0.f;

    // staging: lane l of wave w writes LDS elems [w*512 + l*8, +8) = row (t>>3), slot (t&7).
    // global source col pre-swizzled so LDS slot s' holds global slot s'^(row&7).
    const int srow = t >> 3;                          // 0..63
    const int sslot = (t & 7) ^ (srow & 7);           // swizzled source slot
    const f16* kg = kb + (size_t)bh * S_LEN * HD + (size_t)srow * HD + sslot * 8;
    const f16* vg = vt + (size_t)bh * HD * S_LEN + (size_t)srow * S_LEN + sslot * 8;
    const int lds_wbase = wid * 512;                  // wave-uniform LDS base (elems)
    f16* pbase = &Pl[wid * (16 * LD)];

    // prologue: tile 0 -> buf0
    gload16(kg, &Kl[0][lds_wbase]);
    gload16(vg, &Vl[0][lds_wbase]);
    __syncthreads();
    int cur = 0;

    for (int kt = 0; kt < S_LEN / 64; kt++) {
        if (kt + 1 < S_LEN / 64) {          // async prefetch next tile into other buffer
            gload16(kg + (size_t)(kt + 1) * 64 * HD, &Kl[cur ^ 1][lds_wbase]);
            gload16(vg + (size_t)(kt + 1) * 64,      &Vl[cur ^ 1][lds_wbase]);
        }
        const f16* Kc = Kl[cur];
        const f16* Vc = Vl[cur];

        // QK^T swapped: sc[f][rg] = score(k = kt*64+16f+4g+rg, q = q0+q15)
        f32x4 sc[4];
        __builtin_amdgcn_s_setprio(1);
        #pragma unroll
        for (int f = 0; f < 4; f++) {
            f16x8 kf0 = *reinterpret_cast<const f16x8*>(&Kc[(f * 16 + q15) * 64 + ((g ^ sw) * 8)]);
            f16x8 kf1 = *reinterpret_cast<const f16x8*>(&Kc[(f * 16 + q15) * 64 + (((g + 4) ^ sw) * 8)]);
            f32x4 z = {0.f, 0.f, 0.f, 0.f};
            z = __builtin_amdgcn_mfma_f32_16x16x32_f16(kf0, qf0, z, 0, 0, 0);
            sc[f] = __builtin_amdgcn_mfma_f32_16x16x32_f16(kf1, qf1, z, 0, 0, 0);
        }
        __builtin_amdgcn_s_setprio(0);

        // online softmax (base-2); lane-local for q = q15
        float pmf[4];
        #pragma unroll
        for (int f = 0; f < 4; f++)
            pmf[f] = fmaxf(fmaxf(sc[f][0], sc[f][1]), fmaxf(sc[f][2], sc[f][3]));
        float pmax = fmaxf(fmaxf(pmf[0], pmf[1]), fmaxf(pmf[2], pmf[3]));
        pmax = fmaxf(pmax, __shfl_xor(pmax, 16));
        pmax = fmaxf(pmax, __shfl_xor(pmax, 32));
        float mnew = fmaxf(mrun, pmax);
        float scale = __builtin_amdgcn_exp2f(mrun - mnew);
        float tsum = 0.f;
        #pragma unroll
        for (int f = 0; f < 4; f++)
            #pragma unroll
            for (int rg = 0; rg < 4; rg++) {
                float p = __builtin_amdgcn_exp2f(sc[f][rg] - mnew);
                sc[f][rg] = p;
                tsum += p;
            }
        tsum += __shfl_xor(tsum, 16);
        tsum += __shfl_xor(tsum, 32);
        lrun = lrun * scale + tsum;
        mrun = mnew;
        #pragma unroll
        for (int n = 0; n < 4; n++) {
            ctxa[n][0] *= scale; ctxa[n][1] *= scale;
            ctxa[n][2] *= scale; ctxa[n][3] *= scale;
        }

        // P -> per-wave LDS (b64 packs)
        #pragma unroll
        for (int f = 0; f < 4; f++) {
            f16x4 pw = { (f16)sc[f][0], (f16)sc[f][1], (f16)sc[f][2], (f16)sc[f][3] };
            *reinterpret_cast<f16x4*>(&pbase[q15 * LD + f * 16 + g * 4]) = pw;
        }
        asm volatile("s_waitcnt lgkmcnt(0)" ::: "memory");
        __builtin_amdgcn_sched_barrier(0);

        // PV swapped: ctx[d][q] += V^T[d][s] * P[q][s]
        __builtin_amdgcn_s_setprio(1);
        #pragma unroll
        for (int c = 0; c < 2; c++) {
            f16x8 pfr = *reinterpret_cast<const f16x8*>(&pbase[q15 * LD + g * 8 + c * 32]);
            #pragma unroll
            for (int n = 0; n < 4; n++) {
                f16x8 vf = *reinterpret_cast<const f16x8*>(&Vc[(n * 16 + q15) * 64 + (((g + c * 4) ^ sw) * 8)]);
                ctxa[n] = __builtin_amdgcn_mfma_f32_16x16x32_f16(vf, pfr, ctxa[n], 0, 0, 0);
            }
        }
        __builtin_amdgcn_s_setprio(0);

        __syncthreads();                    // drains vmcnt (prefetch done) + LDS reads of cur
        cur ^= 1;
    }

    // epilogue: lane-local 1/l, packed b64 stores
    const int bi = bh >> 4, h = bh & 15;
    const int s = q0 + q15;
    float inv = 1.0f / lrun;
    f16* outp = &ctx[((size_t)s * BATCH + bi) * DMODEL + h * HD];
    #pragma unroll
    for (int n = 0; n < 4; n++) {
        f16x4 o = { (f16)(ctxa[n][0] * inv), (f16)(ctxa[n][1] * inv),
                    (f16)(ctxa[n][2] * inv), (f16)(ctxa[n][3] * inv) };
        *reinterpret_cast<f16x4*>(&outp[n * 16 + g * 4]) = o;
    }
}

// ---------------- launch ----------------
extern "C" void kernel_launch(void* const* d_in, const int* in_sizes, int n_in,
                              void* d_out, int out_size, void* d_ws, size_t ws_size,
                              hipStream_t stream)
{
    const float* Q  = (const float*)d_in[0];
    const float* K  = (const float*)d_in[1];
    const float* V  = (const float*)d_in[2];
    const float* Wq = (const float*)d_in[3];
    const float* bq = (const float*)d_in[4];
    const float* Wk = (const float*)d_in[5];
    const float* bk = (const float*)d_in[6];
    const float* Wv = (const float*)d_in[7];
    const float* bv = (const float*)d_in[8];
    const float* Wo = (const float*)d_in[9];
    const float* bo = (const float*)d_in[10];
    float* out = (float*)d_out;

    char* w = (char*)d_ws;
    const size_t MBc = 1024 * 1024;
    const size_t NEED_FAST = 56 * MBc + 256 * 1024;   // 56.25 MiB

    if (ws_size >= NEED_FAST) {
        f16* cvtb = (f16*)w;
        f16* Xqh = cvtb;
        f16* Xkh = cvtb + 4194304;
        f16* Xvh = cvtb + 8388608;
        f16* Wqh = cvtb + 12582912;
        f16* Wkh = cvtb + 13631488;
        f16* Wvh = cvtb + 14680064;
        f16* Woh = cvtb + 15728640;
        float* rc = (float*)(w + 32 * MBc);
        float* rs = rc + 32768;
        f16* qbuf = (f16*)(w + 32 * MBc + 256 * 1024);
        f16* kbuf = qbuf + 4194304;
        f16* vtb  = kbuf + 4194304;
        f16* ctxb = Xqh;

        rope_table<<<(S_LEN * 16) / 256, 256, 0, stream>>>(rc, rs);
        cvt_all<<<dim3(2048, 7), 256, 0, stream>>>(Q, K, V, Wq, Wk, Wv, Wo, cvtb);
        proj_gemm_h<<<dim3(MROWS / 128, DMODEL / 128, 3), 256, 0, stream>>>(
            Xqh, Xkh, Xvh, Wqh, Wkh, Wvh, bq, bk, bv, qbuf, kbuf, vtb, rc, rs);
        attn_fwd<<<dim3(S_LEN / 128, BATCH * NHEADS), 512, 0, stream>>>(qbuf, kbuf, vtb, ctxb);
        out_gemm_h<<<dim3(MROWS / 128, DMODEL / 128), 256, 0, stream>>>(ctxb, Woh, bo, out);
    } else {
        const size_t szT = (size_t)S_LEN * 16 * sizeof(float);
        const size_t szQ = (size_t)MROWS * DMODEL * sizeof(f16);
        float* rc  = (float*)(w);
        float* rs  = (float*)(w + szT);
        f16* qbuf = (f16*)(w + 2 * szT);
        f16* kbuf = (f16*)(w + 2 * szT + szQ);
        f16* vtb  = (f16*)(w + 2 * szT + 2 * szQ);
        f16* ctxb = (f16*)(w + 2 * szT + 3 * szQ);

        rope_table<<<(S_LEN * 16) / 256, 256, 0, stream>>>(rc, rs);
        proj_gemm<<<dim3(MROWS / 128, DMODEL / 128, 3), 256, 0, stream>>>(
            Q, K, V, Wq, Wk, Wv, bq, bk, bv, qbuf, kbuf, vtb, rc, rs);
        attn_fwd<<<dim3(S_LEN / 128, BATCH * NHEADS), 512, 0, stream>>>(qbuf, kbuf, vtb, ctxb);
        out_gemm<<<dim3(MROWS / 128, DMODEL / 128), 256, 0, stream>>>(ctxb, Wo, bo, out);
    }
}

// Round 14
// 150.842 us; speedup vs baseline: 2.7761x; 1.0367x over previous
//
#include <hip/hip_runtime.h>
#include <hip/hip_bf16.h>
#include <hip/hip_fp16.h>

#define S_LEN  2048
#define BATCH  2
#define DMODEL 1024
#define NHEADS 16
#define HD     64
#define MROWS  4096   // S*B
#define LD     72     // attn P LDS stride (padded, per-wave)

using f16 = _Float16;
typedef __attribute__((ext_vector_type(8))) _Float16 f16x8;
typedef __attribute__((ext_vector_type(4))) _Float16 f16x4;
typedef __attribute__((ext_vector_type(4))) float    f32x4;

// async global->LDS, 16B per lane; LDS dest = wave-uniform base + lane*16
__device__ __forceinline__ void gload16(const void* g, void* l)
{
    __builtin_amdgcn_global_load_lds((const __attribute__((address_space(1))) void*)g,
                                     (__attribute__((address_space(3))) void*)l, 16, 0, 0);
}

// ---------------- RoPE cos/sin table: [S][16] ----------------
__global__ __launch_bounds__(256) void rope_table(float* __restrict__ rc, float* __restrict__ rs)
{
    int idx = blockIdx.x * 256 + threadIdx.x;   // S*16 threads
    int s = idx >> 4, i = idx & 15;
    float inv = powf(10000.0f, -(float)(2 * i) / 32.0f);
    float ang = (float)s * inv;
    rc[idx] = cosf(ang);
    rs[idx] = sinf(ang);
}

// ---------------- fp32 -> f16 conversion of all 7 tensors into one ws block ----------------
__global__ __launch_bounds__(256) void cvt_all(
    const float* __restrict__ Q, const float* __restrict__ K, const float* __restrict__ V,
    const float* __restrict__ Wq, const float* __restrict__ Wk, const float* __restrict__ Wv,
    const float* __restrict__ Wo, f16* __restrict__ dst)
{
    const int z = blockIdx.y;
    const float* src; size_t off; int n8;
    switch (z) {
        case 0:  src = Q;  off = 0;        n8 = 524288; break;
        case 1:  src = K;  off = 4194304;  n8 = 524288; break;
        case 2:  src = V;  off = 8388608;  n8 = 524288; break;
        case 3:  src = Wq; off = 12582912; n8 = 131072; break;
        case 4:  src = Wk; off = 13631488; n8 = 131072; break;
        case 5:  src = Wv; off = 14680064; n8 = 131072; break;
        default: src = Wo; off = 15728640; n8 = 131072; break;
    }
    int i = blockIdx.x * 256 + threadIdx.x;
    if (i >= n8) return;
    const float4* s = reinterpret_cast<const float4*>(src) + (size_t)i * 2;
    float4 v0 = s[0], v1 = s[1];
    f16x8 h = { (f16)v0.x, (f16)v0.y, (f16)v0.z, (f16)v0.w,
                (f16)v1.x, (f16)v1.y, (f16)v1.z, (f16)v1.w };
    reinterpret_cast<f16x8*>(dst + off)[i] = h;
}

// ---------------- f16-input projection GEMM, global_load_lds staging ----------------
__global__ __launch_bounds__(256) void proj_gemm_h(
    const f16* __restrict__ Xq, const f16* __restrict__ Xk, const f16* __restrict__ Xv,
    const f16* __restrict__ Wq, const f16* __restrict__ Wk, const f16* __restrict__ Wv,
    const float* __restrict__ bq, const float* __restrict__ bk, const float* __restrict__ bv,
    f16* __restrict__ qo, f16* __restrict__ ko, f16* __restrict__ vo,
    const float* __restrict__ rc, const float* __restrict__ rs)
{
    const int mode = blockIdx.z;            // 0=q 1=k 2=v
    const f16* X     = (mode == 0) ? Xq : (mode == 1) ? Xk : Xv;
    const f16* W     = (mode == 0) ? Wq : (mode == 1) ? Wk : Wv;
    const float* bias = (mode == 0) ? bq : (mode == 1) ? bk : bv;

    __shared__ f16 Al[128 * 32];
    __shared__ f16 Bl[128 * 32];

    const int t = threadIdx.x, lane = t & 63, wid = t >> 6;
    const int q15 = lane & 15, g = lane >> 4;
    const int wr = wid >> 1, wc = wid & 1;
    const int m0 = blockIdx.x * 128, n0 = blockIdx.y * 128;

    const int srow = wid * 16 + (lane >> 2);
    const int scol = (lane & 3) * 8;
    const f16* Xg = X + (size_t)(m0 + srow) * DMODEL + scol;
    const f16* Wg = W + (size_t)(n0 + srow) * DMODEL + scol;
    f16* al0 = &Al[(wid * 16) * 32];
    f16* al1 = &Al[(wid * 16 + 64) * 32];
    f16* bl0 = &Bl[(wid * 16) * 32];
    f16* bl1 = &Bl[(wid * 16 + 64) * 32];

    f32x4 acc[4][4];
    #pragma unroll
    for (int m = 0; m < 4; m++)
        #pragma unroll
        for (int n = 0; n < 4; n++)
            acc[m][n] = f32x4{0.f, 0.f, 0.f, 0.f};

    for (int k0 = 0; k0 < DMODEL; k0 += 32) {
        __syncthreads();
        gload16(Xg + k0, al0);
        gload16(Xg + (size_t)64 * DMODEL + k0, al1);
        gload16(Wg + k0, bl0);
        gload16(Wg + (size_t)64 * DMODEL + k0, bl1);
        __syncthreads();

        f16x8 a[4], b[4];
        #pragma unroll
        for (int m = 0; m < 4; m++)
            a[m] = *reinterpret_cast<const f16x8*>(&Al[(wr * 64 + m * 16 + q15) * 32 + g * 8]);
        #pragma unroll
        for (int n = 0; n < 4; n++)
            b[n] = *reinterpret_cast<const f16x8*>(&Bl[(wc * 64 + n * 16 + q15) * 32 + g * 8]);
        #pragma unroll
        for (int m = 0; m < 4; m++)
            #pragma unroll
            for (int n = 0; n < 4; n++)
                acc[m][n] = __builtin_amdgcn_mfma_f32_16x16x32_f16(a[m], b[n], acc[m][n], 0, 0, 0);
    }

    const int rowb = m0 + wr * 64, colb = n0 + wc * 64;
    #pragma unroll
    for (int n = 0; n < 4; n++) {
        int cN = colb + n * 16 + q15;
        float bvv = bias[cN];
        int h = cN >> 6, d = cN & 63;
        #pragma unroll
        for (int m = 0; m < 4; m++) {
            #pragma unroll
            for (int rg = 0; rg < 4; rg++) {
                int r = rowb + m * 16 + g * 4 + rg;
                int s = r >> 1, bi = r & 1;
                float val = acc[m][n][rg] + bvv;
                if (mode < 2) {
                    float pv = __shfl_xor(val, 1);
                    if (d < 32) {
                        int fi = d >> 1;
                        float cc = rc[s * 16 + fi], ss = rs[s * 16 + fi];
                        val = ((d & 1) == 0) ? val * cc - pv * ss : val * cc + pv * ss;
                    }
                    if (mode == 0) val *= 0.18033688f;      // (1/8)*log2(e)
                    ((mode == 0) ? qo : ko)[(((size_t)bi * NHEADS + h) * S_LEN + s) * HD + d] = (f16)val;
                } else {
                    vo[(((size_t)bi * NHEADS + h) * HD + d) * S_LEN + s] = (f16)val;
                }
            }
        }
    }
}

// ---------------- f16-input output GEMM, global_load_lds staging ----------------
__global__ __launch_bounds__(256) void out_gemm_h(
    const f16* __restrict__ X, const f16* __restrict__ W,
    const float* __restrict__ bias, float* __restrict__ out)
{
    __shared__ f16 Al[128 * 32];
    __shared__ f16 Bl[128 * 32];

    const int t = threadIdx.x, lane = t & 63, wid = t >> 6;
    const int q15 = lane & 15, g = lane >> 4;
    const int wr = wid >> 1, wc = wid & 1;
    const int m0 = blockIdx.x * 128, n0 = blockIdx.y * 128;

    const int srow = wid * 16 + (lane >> 2);
    const int scol = (lane & 3) * 8;
    const f16* Xg = X + (size_t)(m0 + srow) * DMODEL + scol;
    const f16* Wg = W + (size_t)(n0 + srow) * DMODEL + scol;
    f16* al0 = &Al[(wid * 16) * 32];
    f16* al1 = &Al[(wid * 16 + 64) * 32];
    f16* bl0 = &Bl[(wid * 16) * 32];
    f16* bl1 = &Bl[(wid * 16 + 64) * 32];

    f32x4 acc[4][4];
    #pragma unroll
    for (int m = 0; m < 4; m++)
        #pragma unroll
        for (int n = 0; n < 4; n++)
            acc[m][n] = f32x4{0.f, 0.f, 0.f, 0.f};

    for (int k0 = 0; k0 < DMODEL; k0 += 32) {
        __syncthreads();
        gload16(Xg + k0, al0);
        gload16(Xg + (size_t)64 * DMODEL + k0, al1);
        gload16(Wg + k0, bl0);
        gload16(Wg + (size_t)64 * DMODEL + k0, bl1);
        __syncthreads();

        f16x8 a[4], b[4];
        #pragma unroll
        for (int m = 0; m < 4; m++)
            a[m] = *reinterpret_cast<const f16x8*>(&Al[(wr * 64 + m * 16 + q15) * 32 + g * 8]);
        #pragma unroll
        for (int n = 0; n < 4; n++)
            b[n] = *reinterpret_cast<const f16x8*>(&Bl[(wc * 64 + n * 16 + q15) * 32 + g * 8]);
        #pragma unroll
        for (int m = 0; m < 4; m++)
            #pragma unroll
            for (int n = 0; n < 4; n++)
                acc[m][n] = __builtin_amdgcn_mfma_f32_16x16x32_f16(a[m], b[n], acc[m][n], 0, 0, 0);
    }

    const int rowb = m0 + wr * 64, colb = n0 + wc * 64;
    #pragma unroll
    for (int n = 0; n < 4; n++) {
        int cN = colb + n * 16 + q15;
        float bvv = bias[cN];
        #pragma unroll
        for (int m = 0; m < 4; m++) {
            #pragma unroll
            for (int rg = 0; rg < 4; rg++) {
                int r = rowb + m * 16 + g * 4 + rg;
                out[(size_t)r * DMODEL + cN] = acc[m][n][rg] + bvv;
            }
        }
    }
}

// ---------------- FALLBACK: fp32-input projection GEMM ----------------
__global__ __launch_bounds__(256) void proj_gemm(
    const float* __restrict__ Xq, const float* __restrict__ Xk, const float* __restrict__ Xv,
    const float* __restrict__ Wq, const float* __restrict__ Wk, const float* __restrict__ Wv,
    const float* __restrict__ bq, const float* __restrict__ bk, const float* __restrict__ bv,
    f16* __restrict__ qo, f16* __restrict__ ko, f16* __restrict__ vo,
    const float* __restrict__ rc, const float* __restrict__ rs)
{
    const int mode = blockIdx.z;
    const float* X    = (mode == 0) ? Xq : (mode == 1) ? Xk : Xv;
    const float* W    = (mode == 0) ? Wq : (mode == 1) ? Wk : Wv;
    const float* bias = (mode == 0) ? bq : (mode == 1) ? bk : bv;

    __shared__ f16 Al[128 * 40];
    __shared__ f16 Bl[128 * 40];

    const int t = threadIdx.x;
    const int lane = t & 63, wid = t >> 6;
    const int wr = wid >> 1, wc = wid & 1;
    const int m0 = blockIdx.x * 128, n0 = blockIdx.y * 128;

    f32x4 acc[4][4];
    #pragma unroll
    for (int m = 0; m < 4; m++)
        #pragma unroll
        for (int n = 0; n < 4; n++)
            acc[m][n] = f32x4{0.f, 0.f, 0.f, 0.f};

    for (int k0 = 0; k0 < DMODEL; k0 += 32) {
        __syncthreads();
        #pragma unroll
        for (int i = 0; i < 2; i++) {
            int e = (i * 256 + t) * 8;
            int r = e >> 5, c = e & 31;
            {
                const float* src = &X[(size_t)(m0 + r) * DMODEL + k0 + c];
                float4 v0 = *reinterpret_cast<const float4*>(src);
                float4 v1 = *reinterpret_cast<const float4*>(src + 4);
                f16x8 h = { (f16)v0.x, (f16)v0.y, (f16)v0.z, (f16)v0.w,
                            (f16)v1.x, (f16)v1.y, (f16)v1.z, (f16)v1.w };
                *reinterpret_cast<f16x8*>(&Al[r * 40 + c]) = h;
            }
            {
                const float* src = &W[(size_t)(n0 + r) * DMODEL + k0 + c];
                float4 v0 = *reinterpret_cast<const float4*>(src);
                float4 v1 = *reinterpret_cast<const float4*>(src + 4);
                f16x8 h = { (f16)v0.x, (f16)v0.y, (f16)v0.z, (f16)v0.w,
                            (f16)v1.x, (f16)v1.y, (f16)v1.z, (f16)v1.w };
                *reinterpret_cast<f16x8*>(&Bl[r * 40 + c]) = h;
            }
        }
        __syncthreads();
        f16x8 a[4], b[4];
        #pragma unroll
        for (int m = 0; m < 4; m++)
            a[m] = *reinterpret_cast<const f16x8*>(&Al[(wr * 64 + m * 16 + (lane & 15)) * 40 + (lane >> 4) * 8]);
        #pragma unroll
        for (int n = 0; n < 4; n++)
            b[n] = *reinterpret_cast<const f16x8*>(&Bl[(wc * 64 + n * 16 + (lane & 15)) * 40 + (lane >> 4) * 8]);
        #pragma unroll
        for (int m = 0; m < 4; m++)
            #pragma unroll
            for (int n = 0; n < 4; n++)
                acc[m][n] = __builtin_amdgcn_mfma_f32_16x16x32_f16(a[m], b[n], acc[m][n], 0, 0, 0);
    }

    const int rowb = m0 + wr * 64, colb = n0 + wc * 64;
    #pragma unroll
    for (int n = 0; n < 4; n++) {
        int cN = colb + n * 16 + (lane & 15);
        float bvv = bias[cN];
        int h = cN >> 6, d = cN & 63;
        #pragma unroll
        for (int m = 0; m < 4; m++) {
            #pragma unroll
            for (int rg = 0; rg < 4; rg++) {
                int r = rowb + m * 16 + (lane >> 4) * 4 + rg;
                int s = r >> 1, bi = r & 1;
                float val = acc[m][n][rg] + bvv;
                if (mode < 2) {
                    float pv = __shfl_xor(val, 1);
                    if (d < 32) {
                        int fi = d >> 1;
                        float cc = rc[s * 16 + fi], ss = rs[s * 16 + fi];
                        val = ((d & 1) == 0) ? val * cc - pv * ss : val * cc + pv * ss;
                    }
                    if (mode == 0) val *= 0.18033688f;
                    ((mode == 0) ? qo : ko)[(((size_t)bi * NHEADS + h) * S_LEN + s) * HD + d] = (f16)val;
                } else {
                    vo[(((size_t)bi * NHEADS + h) * HD + d) * S_LEN + s] = (f16)val;
                }
            }
        }
    }
}

// ---------------- FALLBACK: output projection ----------------
__global__ __launch_bounds__(256) void out_gemm(
    const f16* __restrict__ X, const float* __restrict__ W,
    const float* __restrict__ bias, float* __restrict__ out)
{
    __shared__ f16 Al[128 * 40];
    __shared__ f16 Bl[128 * 40];

    const int t = threadIdx.x;
    const int lane = t & 63, wid = t >> 6;
    const int wr = wid >> 1, wc = wid & 1;
    const int m0 = blockIdx.x * 128, n0 = blockIdx.y * 128;

    f32x4 acc[4][4];
    #pragma unroll
    for (int m = 0; m < 4; m++)
        #pragma unroll
        for (int n = 0; n < 4; n++)
            acc[m][n] = f32x4{0.f, 0.f, 0.f, 0.f};

    for (int k0 = 0; k0 < DMODEL; k0 += 32) {
        __syncthreads();
        #pragma unroll
        for (int i = 0; i < 2; i++) {
            int e = (i * 256 + t) * 8;
            int r = e >> 5, c = e & 31;
            *reinterpret_cast<uint4*>(&Al[r * 40 + c]) =
                *reinterpret_cast<const uint4*>(&X[(size_t)(m0 + r) * DMODEL + k0 + c]);
            {
                const float* src = &W[(size_t)(n0 + r) * DMODEL + k0 + c];
                float4 v0 = *reinterpret_cast<const float4*>(src);
                float4 v1 = *reinterpret_cast<const float4*>(src + 4);
                f16x8 h = { (f16)v0.x, (f16)v0.y, (f16)v0.z, (f16)v0.w,
                            (f16)v1.x, (f16)v1.y, (f16)v1.z, (f16)v1.w };
                *reinterpret_cast<f16x8*>(&Bl[r * 40 + c]) = h;
            }
        }
        __syncthreads();
        f16x8 a[4], b[4];
        #pragma unroll
        for (int m = 0; m < 4; m++)
            a[m] = *reinterpret_cast<const f16x8*>(&Al[(wr * 64 + m * 16 + (lane & 15)) * 40 + (lane >> 4) * 8]);
        #pragma unroll
        for (int n = 0; n < 4; n++)
            b[n] = *reinterpret_cast<const f16x8*>(&Bl[(wc * 64 + n * 16 + (lane & 15)) * 40 + (lane >> 4) * 8]);
        #pragma unroll
        for (int m = 0; m < 4; m++)
            #pragma unroll
            for (int n = 0; n < 4; n++)
                acc[m][n] = __builtin_amdgcn_mfma_f32_16x16x32_f16(a[m], b[n], acc[m][n], 0, 0, 0);
    }

    const int rowb = m0 + wr * 64, colb = n0 + wc * 64;
    #pragma unroll
    for (int n = 0; n < 4; n++) {
        int cN = colb + n * 16 + (lane & 15);
        float bvv = bias[cN];
        #pragma unroll
        for (int m = 0; m < 4; m++) {
            #pragma unroll
            for (int rg = 0; rg < 4; rg++) {
                int r = rowb + m * 16 + (lane >> 4) * 4 + rg;
                out[(size_t)r * DMODEL + cN] = acc[m][n][rg] + bvv;
            }
        }
    }
}

// ---------------- flash attention: gload_lds dbuf K/V + defer-max softmax ----------------
// grid (S/128, B*H); 8 waves x 16 q-rows. Defer-max (THR=8): skip rescale when max growth
// small; lrun kept per-lane partial, cross-lane reduced once in epilogue.
__global__ __launch_bounds__(512) void attn_fwd(
    const f16* __restrict__ qb, const f16* __restrict__ kb,
    const f16* __restrict__ vt, f16* __restrict__ ctx)
{
    __shared__ f16 Kl[2][64 * 64];
    __shared__ f16 Vl[2][64 * 64];
    __shared__ f16 Pl[8 * 16 * LD];

    const int t = threadIdx.x, lane = t & 63, wid = t >> 6;
    const int q15 = lane & 15, g = lane >> 4;
    const int sw = q15 & 7;                 // read-side XOR key
    const int bh = blockIdx.y;
    const int q0 = blockIdx.x * 128 + wid * 16;

    const f16* qptr = qb + ((size_t)bh * S_LEN + q0) * HD;
    f16x8 qf0 = *reinterpret_cast<const f16x8*>(&qptr[q15 * HD + g * 8]);
    f16x8 qf1 = *reinterpret_cast<const f16x8*>(&qptr[q15 * HD + g * 8 + 32]);

    f32x4 ctxa[4];
    #pragma unroll
    for (int i = 0; i < 4; i++) ctxa[i] = f32x4{0.f, 0.f, 0.f, 0.f};
    float mrun = -3.0e38f, lrun = 0.f;      // lrun: per-lane partial sum

    const int srow = t >> 3;
    const int sslot = (t & 7) ^ (srow & 7);
    const f16* kg = kb + (size_t)bh * S_LEN * HD + (size_t)srow * HD + sslot * 8;
    const f16* vg = vt + (size_t)bh * HD * S_LEN + (size_t)srow * S_LEN + sslot * 8;
    const int lds_wbase = wid * 512;
    f16* pbase = &Pl[wid * (16 * LD)];

    gload16(kg, &Kl[0][lds_wbase]);
    gload16(vg, &Vl[0][lds_wbase]);
    __syncthreads();
    int cur = 0;

    for (int kt = 0; kt < S_LEN / 64; kt++) {
        if (kt + 1 < S_LEN / 64) {
            gload16(kg + (size_t)(kt + 1) * 64 * HD, &Kl[cur ^ 1][lds_wbase]);
            gload16(vg + (size_t)(kt + 1) * 64,      &Vl[cur ^ 1][lds_wbase]);
        }
        const f16* Kc = Kl[cur];
        const f16* Vc = Vl[cur];

        // QK^T swapped: sc[f][rg] = score(k = kt*64+16f+4g+rg, q = q0+q15)
        f32x4 sc[4];
        __builtin_amdgcn_s_setprio(1);
        #pragma unroll
        for (int f = 0; f < 4; f++) {
            f16x8 kf0 = *reinterpret_cast<const f16x8*>(&Kc[(f * 16 + q15) * 64 + ((g ^ sw) * 8)]);
            f16x8 kf1 = *reinterpret_cast<const f16x8*>(&Kc[(f * 16 + q15) * 64 + (((g + 4) ^ sw) * 8)]);
            f32x4 z = {0.f, 0.f, 0.f, 0.f};
            z = __builtin_amdgcn_mfma_f32_16x16x32_f16(kf0, qf0, z, 0, 0, 0);
            sc[f] = __builtin_amdgcn_mfma_f32_16x16x32_f16(kf1, qf1, z, 0, 0, 0);
        }
        __builtin_amdgcn_s_setprio(0);

        // defer-max online softmax (base-2), THR=8
        float pmf[4];
        #pragma unroll
        for (int f = 0; f < 4; f++)
            pmf[f] = fmaxf(fmaxf(sc[f][0], sc[f][1]), fmaxf(sc[f][2], sc[f][3]));
        float pm = fmaxf(fmaxf(pmf[0], pmf[1]), fmaxf(pmf[2], pmf[3]));
        if (!__all(pm - mrun <= 8.0f)) {    // wave-uniform slow path
            float pmax = fmaxf(pm, __shfl_xor(pm, 16));
            pmax = fmaxf(pmax, __shfl_xor(pmax, 32));
            float mnew = fmaxf(mrun, pmax);
            float scale = __builtin_amdgcn_exp2f(mrun - mnew);
            lrun *= scale;
            #pragma unroll
            for (int n = 0; n < 4; n++) {
                ctxa[n][0] *= scale; ctxa[n][1] *= scale;
                ctxa[n][2] *= scale; ctxa[n][3] *= scale;
            }
            mrun = mnew;
        }
        float tsum = 0.f;
        #pragma unroll
        for (int f = 0; f < 4; f++)
            #pragma unroll
            for (int rg = 0; rg < 4; rg++) {
                float p = __builtin_amdgcn_exp2f(sc[f][rg] - mrun);   // bounded by 2^8
                sc[f][rg] = p;
                tsum += p;
            }
        lrun += tsum;                        // per-lane partial; reduced in epilogue

        // P -> per-wave LDS (b64 packs)
        #pragma unroll
        for (int f = 0; f < 4; f++) {
            f16x4 pw = { (f16)sc[f][0], (f16)sc[f][1], (f16)sc[f][2], (f16)sc[f][3] };
            *reinterpret_cast<f16x4*>(&pbase[q15 * LD + f * 16 + g * 4]) = pw;
        }
        asm volatile("s_waitcnt lgkmcnt(0)" ::: "memory");
        __builtin_amdgcn_sched_barrier(0);

        // PV swapped: ctx[d][q] += V^T[d][s] * P[q][s]
        __builtin_amdgcn_s_setprio(1);
        #pragma unroll
        for (int c = 0; c < 2; c++) {
            f16x8 pfr = *reinterpret_cast<const f16x8*>(&pbase[q15 * LD + g * 8 + c * 32]);
            #pragma unroll
            for (int n = 0; n < 4; n++) {
                f16x8 vf = *reinterpret_cast<const f16x8*>(&Vc[(n * 16 + q15) * 64 + (((g + c * 4) ^ sw) * 8)]);
                ctxa[n] = __builtin_amdgcn_mfma_f32_16x16x32_f16(vf, pfr, ctxa[n], 0, 0, 0);
            }
        }
        __builtin_amdgcn_s_setprio(0);

        __syncthreads();
        cur ^= 1;
    }

    // epilogue: reduce lrun across g-lanes, then lane-local 1/l, packed b64 stores
    lrun += __shfl_xor(lrun, 16);
    lrun += __shfl_xor(lrun, 32);
    const int bi = bh >> 4, h = bh & 15;
    const int s = q0 + q15;
    float inv = 1.0f / lrun;
    f16* outp = &ctx[((size_t)s * BATCH + bi) * DMODEL + h * HD];
    #pragma unroll
    for (int n = 0; n < 4; n++) {
        f16x4 o = { (f16)(ctxa[n][0] * inv), (f16)(ctxa[n][1] * inv),
                    (f16)(ctxa[n][2] * inv), (f16)(ctxa[n][3] * inv) };
        *reinterpret_cast<f16x4*>(&outp[n * 16 + g * 4]) = o;
    }
}

// ---------------- launch ----------------
extern "C" void kernel_launch(void* const* d_in, const int* in_sizes, int n_in,
                              void* d_out, int out_size, void* d_ws, size_t ws_size,
                              hipStream_t stream)
{
    const float* Q  = (const float*)d_in[0];
    const float* K  = (const float*)d_in[1];
    const float* V  = (const float*)d_in[2];
    const float* Wq = (const float*)d_in[3];
    const float* bq = (const float*)d_in[4];
    const float* Wk = (const float*)d_in[5];
    const float* bk = (const float*)d_in[6];
    const float* Wv = (const float*)d_in[7];
    const float* bv = (const float*)d_in[8];
    const float* Wo = (const float*)d_in[9];
    const float* bo = (const float*)d_in[10];
    float* out = (float*)d_out;

    char* w = (char*)d_ws;
    const size_t MBc = 1024 * 1024;
    const size_t NEED_FAST = 56 * MBc + 256 * 1024;   // 56.25 MiB

    if (ws_size >= NEED_FAST) {
        f16* cvtb = (f16*)w;
        f16* Xqh = cvtb;
        f16* Xkh = cvtb + 4194304;
        f16* Xvh = cvtb + 8388608;
        f16* Wqh = cvtb + 12582912;
        f16* Wkh = cvtb + 13631488;
        f16* Wvh = cvtb + 14680064;
        f16* Woh = cvtb + 15728640;
        float* rc = (float*)(w + 32 * MBc);
        float* rs = rc + 32768;
        f16* qbuf = (f16*)(w + 32 * MBc + 256 * 1024);
        f16* kbuf = qbuf + 4194304;
        f16* vtb  = kbuf + 4194304;
        f16* ctxb = Xqh;

        rope_table<<<(S_LEN * 16) / 256, 256, 0, stream>>>(rc, rs);
        cvt_all<<<dim3(2048, 7), 256, 0, stream>>>(Q, K, V, Wq, Wk, Wv, Wo, cvtb);
        proj_gemm_h<<<dim3(MROWS / 128, DMODEL / 128, 3), 256, 0, stream>>>(
            Xqh, Xkh, Xvh, Wqh, Wkh, Wvh, bq, bk, bv, qbuf, kbuf, vtb, rc, rs);
        attn_fwd<<<dim3(S_LEN / 128, BATCH * NHEADS), 512, 0, stream>>>(qbuf, kbuf, vtb, ctxb);
        out_gemm_h<<<dim3(MROWS / 128, DMODEL / 128), 256, 0, stream>>>(ctxb, Woh, bo, out);
    } else {
        const size_t szT = (size_t)S_LEN * 16 * sizeof(float);
        const size_t szQ = (size_t)MROWS * DMODEL * sizeof(f16);
        float* rc  = (float*)(w);
        float* rs  = (float*)(w + szT);
        f16* qbuf = (f16*)(w + 2 * szT);
        f16* kbuf = (f16*)(w + 2 * szT + szQ);
        f16* vtb  = (f16*)(w + 2 * szT + 2 * szQ);
        f16* ctxb = (f16*)(w + 2 * szT + 3 * szQ);

        rope_table<<<(S_LEN * 16) / 256, 256, 0, stream>>>(rc, rs);
        proj_gemm<<<dim3(MROWS / 128, DMODEL / 128, 3), 256, 0, stream>>>(
            Q, K, V, Wq, Wk, Wv, bq, bk, bv, qbuf, kbuf, vtb, rc, rs);
        attn_fwd<<<dim3(S_LEN / 128, BATCH * NHEADS), 512, 0, stream>>>(qbuf, kbuf, vtb, ctxb);
        out_gemm<<<dim3(MROWS / 128, DMODEL / 128), 256, 0, stream>>>(ctxb, Wo, bo, out);
    }
}

// Round 17
// 150.542 us; speedup vs baseline: 2.7816x; 1.0020x over previous
//
#include <hip/hip_runtime.h>
#include <hip/hip_bf16.h>
#include <hip/hip_fp16.h>

#define S_LEN  2048
#define BATCH  2
#define DMODEL 1024
#define NHEADS 16
#define HD     64
#define MROWS  4096   // S*B
#define LD     72     // attn P LDS stride (padded, per-wave)
#define NT     (S_LEN / 64)

using f16 = _Float16;
typedef __attribute__((ext_vector_type(8))) _Float16 f16x8;
typedef __attribute__((ext_vector_type(4))) _Float16 f16x4;
typedef __attribute__((ext_vector_type(4))) float    f32x4;

// async global->LDS, 16B per lane; LDS dest = wave-uniform base + lane*16
__device__ __forceinline__ void gload16(const void* g, void* l)
{
    __builtin_amdgcn_global_load_lds((const __attribute__((address_space(1))) void*)g,
                                     (__attribute__((address_space(3))) void*)l, 16, 0, 0);
}

// ---------------- RoPE cos/sin table: [S][16] ----------------
__global__ __launch_bounds__(256) void rope_table(float* __restrict__ rc, float* __restrict__ rs)
{
    int idx = blockIdx.x * 256 + threadIdx.x;   // S*16 threads
    int s = idx >> 4, i = idx & 15;
    float inv = powf(10000.0f, -(float)(2 * i) / 32.0f);
    float ang = (float)s * inv;
    rc[idx] = cosf(ang);
    rs[idx] = sinf(ang);
}

// ---------------- fp32 -> f16 conversion of all 7 tensors into one ws block ----------------
__global__ __launch_bounds__(256) void cvt_all(
    const float* __restrict__ Q, const float* __restrict__ K, const float* __restrict__ V,
    const float* __restrict__ Wq, const float* __restrict__ Wk, const float* __restrict__ Wv,
    const float* __restrict__ Wo, f16* __restrict__ dst)
{
    const int z = blockIdx.y;
    const float* src; size_t off; int n8;
    switch (z) {
        case 0:  src = Q;  off = 0;        n8 = 524288; break;
        case 1:  src = K;  off = 4194304;  n8 = 524288; break;
        case 2:  src = V;  off = 8388608;  n8 = 524288; break;
        case 3:  src = Wq; off = 12582912; n8 = 131072; break;
        case 4:  src = Wk; off = 13631488; n8 = 131072; break;
        case 5:  src = Wv; off = 14680064; n8 = 131072; break;
        default: src = Wo; off = 15728640; n8 = 131072; break;
    }
    int i = blockIdx.x * 256 + threadIdx.x;
    if (i >= n8) return;
    const float4* s = reinterpret_cast<const float4*>(src) + (size_t)i * 2;
    float4 v0 = s[0], v1 = s[1];
    f16x8 h = { (f16)v0.x, (f16)v0.y, (f16)v0.z, (f16)v0.w,
                (f16)v1.x, (f16)v1.y, (f16)v1.z, (f16)v1.w };
    reinterpret_cast<f16x8*>(dst + off)[i] = h;
}

// ---------------- f16-input projection GEMM, global_load_lds staging ----------------
__global__ __launch_bounds__(256) void proj_gemm_h(
    const f16* __restrict__ Xq, const f16* __restrict__ Xk, const f16* __restrict__ Xv,
    const f16* __restrict__ Wq, const f16* __restrict__ Wk, const f16* __restrict__ Wv,
    const float* __restrict__ bq, const float* __restrict__ bk, const float* __restrict__ bv,
    f16* __restrict__ qo, f16* __restrict__ ko, f16* __restrict__ vo,
    const float* __restrict__ rc, const float* __restrict__ rs)
{
    const int mode = blockIdx.z;            // 0=q 1=k 2=v
    const f16* X     = (mode == 0) ? Xq : (mode == 1) ? Xk : Xv;
    const f16* W     = (mode == 0) ? Wq : (mode == 1) ? Wk : Wv;
    const float* bias = (mode == 0) ? bq : (mode == 1) ? bk : bv;

    __shared__ f16 Al[128 * 32];
    __shared__ f16 Bl[128 * 32];

    const int t = threadIdx.x, lane = t & 63, wid = t >> 6;
    const int q15 = lane & 15, g = lane >> 4;
    const int wr = wid >> 1, wc = wid & 1;
    const int m0 = blockIdx.x * 128, n0 = blockIdx.y * 128;

    const int srow = wid * 16 + (lane >> 2);
    const int scol = (lane & 3) * 8;
    const f16* Xg = X + (size_t)(m0 + srow) * DMODEL + scol;
    const f16* Wg = W + (size_t)(n0 + srow) * DMODEL + scol;
    f16* al0 = &Al[(wid * 16) * 32];
    f16* al1 = &Al[(wid * 16 + 64) * 32];
    f16* bl0 = &Bl[(wid * 16) * 32];
    f16* bl1 = &Bl[(wid * 16 + 64) * 32];

    f32x4 acc[4][4];
    #pragma unroll
    for (int m = 0; m < 4; m++)
        #pragma unroll
        for (int n = 0; n < 4; n++)
            acc[m][n] = f32x4{0.f, 0.f, 0.f, 0.f};

    for (int k0 = 0; k0 < DMODEL; k0 += 32) {
        __syncthreads();
        gload16(Xg + k0, al0);
        gload16(Xg + (size_t)64 * DMODEL + k0, al1);
        gload16(Wg + k0, bl0);
        gload16(Wg + (size_t)64 * DMODEL + k0, bl1);
        __syncthreads();

        f16x8 a[4], b[4];
        #pragma unroll
        for (int m = 0; m < 4; m++)
            a[m] = *reinterpret_cast<const f16x8*>(&Al[(wr * 64 + m * 16 + q15) * 32 + g * 8]);
        #pragma unroll
        for (int n = 0; n < 4; n++)
            b[n] = *reinterpret_cast<const f16x8*>(&Bl[(wc * 64 + n * 16 + q15) * 32 + g * 8]);
        #pragma unroll
        for (int m = 0; m < 4; m++)
            #pragma unroll
            for (int n = 0; n < 4; n++)
                acc[m][n] = __builtin_amdgcn_mfma_f32_16x16x32_f16(a[m], b[n], acc[m][n], 0, 0, 0);
    }

    const int rowb = m0 + wr * 64, colb = n0 + wc * 64;
    #pragma unroll
    for (int n = 0; n < 4; n++) {
        int cN = colb + n * 16 + q15;
        float bvv = bias[cN];
        int h = cN >> 6, d = cN & 63;
        #pragma unroll
        for (int m = 0; m < 4; m++) {
            #pragma unroll
            for (int rg = 0; rg < 4; rg++) {
                int r = rowb + m * 16 + g * 4 + rg;
                int s = r >> 1, bi = r & 1;
                float val = acc[m][n][rg] + bvv;
                if (mode < 2) {
                    float pv = __shfl_xor(val, 1);
                    if (d < 32) {
                        int fi = d >> 1;
                        float cc = rc[s * 16 + fi], ss = rs[s * 16 + fi];
                        val = ((d & 1) == 0) ? val * cc - pv * ss : val * cc + pv * ss;
                    }
                    if (mode == 0) val *= 0.18033688f;      // (1/8)*log2(e)
                    ((mode == 0) ? qo : ko)[(((size_t)bi * NHEADS + h) * S_LEN + s) * HD + d] = (f16)val;
                } else {
                    vo[(((size_t)bi * NHEADS + h) * HD + d) * S_LEN + s] = (f16)val;
                }
            }
        }
    }
}

// ---------------- f16-input output GEMM, global_load_lds staging ----------------
__global__ __launch_bounds__(256) void out_gemm_h(
    const f16* __restrict__ X, const f16* __restrict__ W,
    const float* __restrict__ bias, float* __restrict__ out)
{
    __shared__ f16 Al[128 * 32];
    __shared__ f16 Bl[128 * 32];

    const int t = threadIdx.x, lane = t & 63, wid = t >> 6;
    const int q15 = lane & 15, g = lane >> 4;
    const int wr = wid >> 1, wc = wid & 1;
    const int m0 = blockIdx.x * 128, n0 = blockIdx.y * 128;

    const int srow = wid * 16 + (lane >> 2);
    const int scol = (lane & 3) * 8;
    const f16* Xg = X + (size_t)(m0 + srow) * DMODEL + scol;
    const f16* Wg = W + (size_t)(n0 + srow) * DMODEL + scol;
    f16* al0 = &Al[(wid * 16) * 32];
    f16* al1 = &Al[(wid * 16 + 64) * 32];
    f16* bl0 = &Bl[(wid * 16) * 32];
    f16* bl1 = &Bl[(wid * 16 + 64) * 32];

    f32x4 acc[4][4];
    #pragma unroll
    for (int m = 0; m < 4; m++)
        #pragma unroll
        for (int n = 0; n < 4; n++)
            acc[m][n] = f32x4{0.f, 0.f, 0.f, 0.f};

    for (int k0 = 0; k0 < DMODEL; k0 += 32) {
        __syncthreads();
        gload16(Xg + k0, al0);
        gload16(Xg + (size_t)64 * DMODEL + k0, al1);
        gload16(Wg + k0, bl0);
        gload16(Wg + (size_t)64 * DMODEL + k0, bl1);
        __syncthreads();

        f16x8 a[4], b[4];
        #pragma unroll
        for (int m = 0; m < 4; m++)
            a[m] = *reinterpret_cast<const f16x8*>(&Al[(wr * 64 + m * 16 + q15) * 32 + g * 8]);
        #pragma unroll
        for (int n = 0; n < 4; n++)
            b[n] = *reinterpret_cast<const f16x8*>(&Bl[(wc * 64 + n * 16 + q15) * 32 + g * 8]);
        #pragma unroll
        for (int m = 0; m < 4; m++)
            #pragma unroll
            for (int n = 0; n < 4; n++)
                acc[m][n] = __builtin_amdgcn_mfma_f32_16x16x32_f16(a[m], b[n], acc[m][n], 0, 0, 0);
    }

    const int rowb = m0 + wr * 64, colb = n0 + wc * 64;
    #pragma unroll
    for (int n = 0; n < 4; n++) {
        int cN = colb + n * 16 + q15;
        float bvv = bias[cN];
        #pragma unroll
        for (int m = 0; m < 4; m++) {
            #pragma unroll
            for (int rg = 0; rg < 4; rg++) {
                int r = rowb + m * 16 + g * 4 + rg;
                out[(size_t)r * DMODEL + cN] = acc[m][n][rg] + bvv;
            }
        }
    }
}

// ---------------- FALLBACK: fp32-input projection GEMM ----------------
__global__ __launch_bounds__(256) void proj_gemm(
    const float* __restrict__ Xq, const float* __restrict__ Xk, const float* __restrict__ Xv,
    const float* __restrict__ Wq, const float* __restrict__ Wk, const float* __restrict__ Wv,
    const float* __restrict__ bq, const float* __restrict__ bk, const float* __restrict__ bv,
    f16* __restrict__ qo, f16* __restrict__ ko, f16* __restrict__ vo,
    const float* __restrict__ rc, const float* __restrict__ rs)
{
    const int mode = blockIdx.z;
    const float* X    = (mode == 0) ? Xq : (mode == 1) ? Xk : Xv;
    const float* W    = (mode == 0) ? Wq : (mode == 1) ? Wk : Wv;
    const float* bias = (mode == 0) ? bq : (mode == 1) ? bk : bv;

    __shared__ f16 Al[128 * 40];
    __shared__ f16 Bl[128 * 40];

    const int t = threadIdx.x;
    const int lane = t & 63, wid = t >> 6;
    const int wr = wid >> 1, wc = wid & 1;
    const int m0 = blockIdx.x * 128, n0 = blockIdx.y * 128;

    f32x4 acc[4][4];
    #pragma unroll
    for (int m = 0; m < 4; m++)
        #pragma unroll
        for (int n = 0; n < 4; n++)
            acc[m][n] = f32x4{0.f, 0.f, 0.f, 0.f};

    for (int k0 = 0; k0 < DMODEL; k0 += 32) {
        __syncthreads();
        #pragma unroll
        for (int i = 0; i < 2; i++) {
            int e = (i * 256 + t) * 8;
            int r = e >> 5, c = e & 31;
            {
                const float* src = &X[(size_t)(m0 + r) * DMODEL + k0 + c];
                float4 v0 = *reinterpret_cast<const float4*>(src);
                float4 v1 = *reinterpret_cast<const float4*>(src + 4);
                f16x8 h = { (f16)v0.x, (f16)v0.y, (f16)v0.z, (f16)v0.w,
                            (f16)v1.x, (f16)v1.y, (f16)v1.z, (f16)v1.w };
                *reinterpret_cast<f16x8*>(&Al[r * 40 + c]) = h;
            }
            {
                const float* src = &W[(size_t)(n0 + r) * DMODEL + k0 + c];
                float4 v0 = *reinterpret_cast<const float4*>(src);
                float4 v1 = *reinterpret_cast<const float4*>(src + 4);
                f16x8 h = { (f16)v0.x, (f16)v0.y, (f16)v0.z, (f16)v0.w,
                            (f16)v1.x, (f16)v1.y, (f16)v1.z, (f16)v1.w };
                *reinterpret_cast<f16x8*>(&Bl[r * 40 + c]) = h;
            }
        }
        __syncthreads();
        f16x8 a[4], b[4];
        #pragma unroll
        for (int m = 0; m < 4; m++)
            a[m] = *reinterpret_cast<const f16x8*>(&Al[(wr * 64 + m * 16 + (lane & 15)) * 40 + (lane >> 4) * 8]);
        #pragma unroll
        for (int n = 0; n < 4; n++)
            b[n] = *reinterpret_cast<const f16x8*>(&Bl[(wc * 64 + n * 16 + (lane & 15)) * 40 + (lane >> 4) * 8]);
        #pragma unroll
        for (int m = 0; m < 4; m++)
            #pragma unroll
            for (int n = 0; n < 4; n++)
                acc[m][n] = __builtin_amdgcn_mfma_f32_16x16x32_f16(a[m], b[n], acc[m][n], 0, 0, 0);
    }

    const int rowb = m0 + wr * 64, colb = n0 + wc * 64;
    #pragma unroll
    for (int n = 0; n < 4; n++) {
        int cN = colb + n * 16 + (lane & 15);
        float bvv = bias[cN];
        int h = cN >> 6, d = cN & 63;
        #pragma unroll
        for (int m = 0; m < 4; m++) {
            #pragma unroll
            for (int rg = 0; rg < 4; rg++) {
                int r = rowb + m * 16 + (lane >> 4) * 4 + rg;
                int s = r >> 1, bi = r & 1;
                float val = acc[m][n][rg] + bvv;
                if (mode < 2) {
                    float pv = __shfl_xor(val, 1);
                    if (d < 32) {
                        int fi = d >> 1;
                        float cc = rc[s * 16 + fi], ss = rs[s * 16 + fi];
                        val = ((d & 1) == 0) ? val * cc - pv * ss : val * cc + pv * ss;
                    }
                    if (mode == 0) val *= 0.18033688f;
                    ((mode == 0) ? qo : ko)[(((size_t)bi * NHEADS + h) * S_LEN + s) * HD + d] = (f16)val;
                } else {
                    vo[(((size_t)bi * NHEADS + h) * HD + d) * S_LEN + s] = (f16)val;
                }
            }
        }
    }
}

// ---------------- FALLBACK: output projection ----------------
__global__ __launch_bounds__(256) void out_gemm(
    const f16* __restrict__ X, const float* __restrict__ W,
    const float* __restrict__ bias, float* __restrict__ out)
{
    __shared__ f16 Al[128 * 40];
    __shared__ f16 Bl[128 * 40];

    const int t = threadIdx.x;
    const int lane = t & 63, wid = t >> 6;
    const int wr = wid >> 1, wc = wid & 1;
    const int m0 = blockIdx.x * 128, n0 = blockIdx.y * 128;

    f32x4 acc[4][4];
    #pragma unroll
    for (int m = 0; m < 4; m++)
        #pragma unroll
        for (int n = 0; n < 4; n++)
            acc[m][n] = f32x4{0.f, 0.f, 0.f, 0.f};

    for (int k0 = 0; k0 < DMODEL; k0 += 32) {
        __syncthreads();
        #pragma unroll
        for (int i = 0; i < 2; i++) {
            int e = (i * 256 + t) * 8;
            int r = e >> 5, c = e & 31;
            *reinterpret_cast<uint4*>(&Al[r * 40 + c]) =
                *reinterpret_cast<const uint4*>(&X[(size_t)(m0 + r) * DMODEL + k0 + c]);
            {
                const float* src = &W[(size_t)(n0 + r) * DMODEL + k0 + c];
                float4 v0 = *reinterpret_cast<const float4*>(src);
                float4 v1 = *reinterpret_cast<const float4*>(src + 4);
                f16x8 h = { (f16)v0.x, (f16)v0.y, (f16)v0.z, (f16)v0.w,
                            (f16)v1.x, (f16)v1.y, (f16)v1.z, (f16)v1.w };
                *reinterpret_cast<f16x8*>(&Bl[r * 40 + c]) = h;
            }
        }
        __syncthreads();
        f16x8 a[4], b[4];
        #pragma unroll
        for (int m = 0; m < 4; m++)
            a[m] = *reinterpret_cast<const f16x8*>(&Al[(wr * 64 + m * 16 + (lane & 15)) * 40 + (lane >> 4) * 8]);
        #pragma unroll
        for (int n = 0; n < 4; n++)
            b[n] = *reinterpret_cast<const f16x8*>(&Bl[(wc * 64 + n * 16 + (lane & 15)) * 40 + (lane >> 4) * 8]);
        #pragma unroll
        for (int m = 0; m < 4; m++)
            #pragma unroll
            for (int n = 0; n < 4; n++)
                acc[m][n] = __builtin_amdgcn_mfma_f32_16x16x32_f16(a[m], b[n], acc[m][n], 0, 0, 0);
    }

    const int rowb = m0 + wr * 64, colb = n0 + wc * 64;
    #pragma unroll
    for (int n = 0; n < 4; n++) {
        int cN = colb + n * 16 + (lane & 15);
        float bvv = bias[cN];
        #pragma unroll
        for (int m = 0; m < 4; m++) {
            #pragma unroll
            for (int rg = 0; rg < 4; rg++) {
                int r = rowb + m * 16 + (lane >> 4) * 4 + rg;
                out[(size_t)r * DMODEL + cN] = acc[m][n][rg] + bvv;
            }
        }
    }
}

// ---------------- flash attention: deferred-PV pipeline (T15) ----------------
// grid (S/128, B*H); 8 waves x 16 q-rows. Per iter: prefetch(kt+1) -> {QK(kt) + PV(kt-1)}
// MFMA cluster -> softmax(kt) (defer-max) -> write P[kt] -> barrier.
// P 2-buf, V 3-buf, K 2-buf. No manual lgkmcnt: PV reads P written a full iter ago.
__global__ __launch_bounds__(512) void attn_fwd(
    const f16* __restrict__ qb, const f16* __restrict__ kb,
    const f16* __restrict__ vt, f16* __restrict__ ctx)
{
    __shared__ f16 Kl[2][64 * 64];
    __shared__ f16 Vl[3][64 * 64];
    __shared__ f16 Pl[2][8 * 16 * LD];

    const int t = threadIdx.x, lane = t & 63, wid = t >> 6;
    const int q15 = lane & 15, g = lane >> 4;
    const int sw = q15 & 7;                 // read-side XOR key
    const int bh = blockIdx.y;
    const int q0 = blockIdx.x * 128 + wid * 16;

    const f16* qptr = qb + ((size_t)bh * S_LEN + q0) * HD;
    f16x8 qf0 = *reinterpret_cast<const f16x8*>(&qptr[q15 * HD + g * 8]);
    f16x8 qf1 = *reinterpret_cast<const f16x8*>(&qptr[q15 * HD + g * 8 + 32]);

    f32x4 ctxa[4];
    #pragma unroll
    for (int i = 0; i < 4; i++) ctxa[i] = f32x4{0.f, 0.f, 0.f, 0.f};
    float mrun = -3.0e38f, lrun = 0.f;

    const int srow = t >> 3;
    const int sslot = (t & 7) ^ (srow & 7);
    const f16* kg = kb + (size_t)bh * S_LEN * HD + (size_t)srow * HD + sslot * 8;
    const f16* vg = vt + (size_t)bh * HD * S_LEN + (size_t)srow * S_LEN + sslot * 8;
    const int lds_wbase = wid * 512;
    const int poff = wid * (16 * LD);

    // prologue: tile 0 -> K buf0 / V buf0
    gload16(kg, &Kl[0][lds_wbase]);
    gload16(vg, &Vl[0][lds_wbase]);
    __syncthreads();

    int kbuf = 0;
    int vprev = 2, vcur = 0, vnext = 1;     // V tile (kt-1, kt, kt+1) buffer indices

    for (int kt = 0; kt < NT; kt++) {
        if (kt + 1 < NT) {                  // async prefetch next tile
            gload16(kg + (size_t)(kt + 1) * 64 * HD, &Kl[kbuf ^ 1][lds_wbase]);
            gload16(vg + (size_t)(kt + 1) * 64,      &Vl[vnext][lds_wbase]);
        }
        const f16* Kc = Kl[kbuf];

        // ---- MFMA cluster: QK(kt) then PV(kt-1) ----
        f32x4 sc[4];
        __builtin_amdgcn_s_setprio(1);
        #pragma unroll
        for (int f = 0; f < 4; f++) {
            f16x8 kf0 = *reinterpret_cast<const f16x8*>(&Kc[(f * 16 + q15) * 64 + ((g ^ sw) * 8)]);
            f16x8 kf1 = *reinterpret_cast<const f16x8*>(&Kc[(f * 16 + q15) * 64 + (((g + 4) ^ sw) * 8)]);
            f32x4 z = {0.f, 0.f, 0.f, 0.f};
            z = __builtin_amdgcn_mfma_f32_16x16x32_f16(kf0, qf0, z, 0, 0, 0);
            sc[f] = __builtin_amdgcn_mfma_f32_16x16x32_f16(kf1, qf1, z, 0, 0, 0);
        }
        if (kt > 0) {                       // PV of previous tile; P landed last iteration
            const f16* Vp = Vl[vprev];
            const f16* pr = &Pl[(kt & 1) ^ 1][poff];
            #pragma unroll
            for (int c = 0; c < 2; c++) {
                f16x8 pfr = *reinterpret_cast<const f16x8*>(&pr[q15 * LD + g * 8 + c * 32]);
                #pragma unroll
                for (int n = 0; n < 4; n++) {
                    f16x8 vf = *reinterpret_cast<const f16x8*>(&Vp[(n * 16 + q15) * 64 + (((g + c * 4) ^ sw) * 8)]);
                    ctxa[n] = __builtin_amdgcn_mfma_f32_16x16x32_f16(vf, pfr, ctxa[n], 0, 0, 0);
                }
            }
        }
        __builtin_amdgcn_s_setprio(0);

        // ---- defer-max online softmax (base-2), THR=8 ----
        float pmf[4];
        #pragma unroll
        for (int f = 0; f < 4; f++)
            pmf[f] = fmaxf(fmaxf(sc[f][0], sc[f][1]), fmaxf(sc[f][2], sc[f][3]));
        float pm = fmaxf(fmaxf(pmf[0], pmf[1]), fmaxf(pmf[2], pmf[3]));
        if (!__all(pm - mrun <= 8.0f)) {    // wave-uniform slow path (ctxa holds thru kt-1)
            float pmax = fmaxf(pm, __shfl_xor(pm, 16));
            pmax = fmaxf(pmax, __shfl_xor(pmax, 32));
            float mnew = fmaxf(mrun, pmax);
            float scale = __builtin_amdgcn_exp2f(mrun - mnew);
            lrun *= scale;
            #pragma unroll
            for (int n = 0; n < 4; n++) {
                ctxa[n][0] *= scale; ctxa[n][1] *= scale;
                ctxa[n][2] *= scale; ctxa[n][3] *= scale;
            }
            mrun = mnew;
        }
        float tsum = 0.f;
        #pragma unroll
        for (int f = 0; f < 4; f++)
            #pragma unroll
            for (int rg = 0; rg < 4; rg++) {
                float p = __builtin_amdgcn_exp2f(sc[f][rg] - mrun);
                sc[f][rg] = p;
                tsum += p;
            }
        lrun += tsum;

        // ---- write P[kt] (consumed next iteration) ----
        f16* pw = &Pl[kt & 1][poff];
        #pragma unroll
        for (int f = 0; f < 4; f++) {
            f16x4 pwv = { (f16)sc[f][0], (f16)sc[f][1], (f16)sc[f][2], (f16)sc[f][3] };
            *reinterpret_cast<f16x4*>(&pw[q15 * LD + f * 16 + g * 4]) = pwv;
        }

        __syncthreads();                    // drains vmcnt (prefetch) + K/V LDS reads
        kbuf ^= 1;
        int tmp = vprev; vprev = vcur; vcur = vnext; vnext = tmp;
    }

    // epilogue: PV(NT-1)
    {
        const f16* Vp = Vl[vprev];
        const f16* pr = &Pl[(NT - 1) & 1][poff];
        #pragma unroll
        for (int c = 0; c < 2; c++) {
            f16x8 pfr = *reinterpret_cast<const f16x8*>(&pr[q15 * LD + g * 8 + c * 32]);
            #pragma unroll
            for (int n = 0; n < 4; n++) {
                f16x8 vf = *reinterpret_cast<const f16x8*>(&Vp[(n * 16 + q15) * 64 + (((g + c * 4) ^ sw) * 8)]);
                ctxa[n] = __builtin_amdgcn_mfma_f32_16x16x32_f16(vf, pfr, ctxa[n], 0, 0, 0);
            }
        }
    }

    // reduce lrun across g-lanes, then lane-local 1/l, packed b64 stores
    lrun += __shfl_xor(lrun, 16);
    lrun += __shfl_xor(lrun, 32);
    const int bi = bh >> 4, h = bh & 15;
    const int s = q0 + q15;
    float inv = 1.0f / lrun;
    f16* outp = &ctx[((size_t)s * BATCH + bi) * DMODEL + h * HD];
    #pragma unroll
    for (int n = 0; n < 4; n++) {
        f16x4 o = { (f16)(ctxa[n][0] * inv), (f16)(ctxa[n][1] * inv),
                    (f16)(ctxa[n][2] * inv), (f16)(ctxa[n][3] * inv) };
        *reinterpret_cast<f16x4*>(&outp[n * 16 + g * 4]) = o;
    }
}

// ---------------- launch ----------------
extern "C" void kernel_launch(void* const* d_in, const int* in_sizes, int n_in,
                              void* d_out, int out_size, void* d_ws, size_t ws_size,
                              hipStream_t stream)
{
    const float* Q  = (const float*)d_in[0];
    const float* K  = (const float*)d_in[1];
    const float* V  = (const float*)d_in[2];
    const float* Wq = (const float*)d_in[3];
    const float* bq = (const float*)d_in[4];
    const float* Wk = (const float*)d_in[5];
    const float* bk = (const float*)d_in[6];
    const float* Wv = (const float*)d_in[7];
    const float* bv = (const float*)d_in[8];
    const float* Wo = (const float*)d_in[9];
    const float* bo = (const float*)d_in[10];
    float* out = (float*)d_out;

    char* w = (char*)d_ws;
    const size_t MBc = 1024 * 1024;
    const size_t NEED_FAST = 56 * MBc + 256 * 1024;   // 56.25 MiB

    if (ws_size >= NEED_FAST) {
        f16* cvtb = (f16*)w;
        f16* Xqh = cvtb;
        f16* Xkh = cvtb + 4194304;
        f16* Xvh = cvtb + 8388608;
        f16* Wqh = cvtb + 12582912;
        f16* Wkh = cvtb + 13631488;
        f16* Wvh = cvtb + 14680064;
        f16* Woh = cvtb + 15728640;
        float* rc = (float*)(w + 32 * MBc);
        float* rs = rc + 32768;
        f16* qbuf = (f16*)(w + 32 * MBc + 256 * 1024);
        f16* kbuf = qbuf + 4194304;
        f16* vtb  = kbuf + 4194304;
        f16* ctxb = Xqh;

        rope_table<<<(S_LEN * 16) / 256, 256, 0, stream>>>(rc, rs);
        cvt_all<<<dim3(2048, 7), 256, 0, stream>>>(Q, K, V, Wq, Wk, Wv, Wo, cvtb);
        proj_gemm_h<<<dim3(MROWS / 128, DMODEL / 128, 3), 256, 0, stream>>>(
            Xqh, Xkh, Xvh, Wqh, Wkh, Wvh, bq, bk, bv, qbuf, kbuf, vtb, rc, rs);
        attn_fwd<<<dim3(S_LEN / 128, BATCH * NHEADS), 512, 0, stream>>>(qbuf, kbuf, vtb, ctxb);
        out_gemm_h<<<dim3(MROWS / 128, DMODEL / 128), 256, 0, stream>>>(ctxb, Woh, bo, out);
    } else {
        const size_t szT = (size_t)S_LEN * 16 * sizeof(float);
        const size_t szQ = (size_t)MROWS * DMODEL * sizeof(f16);
        float* rc  = (float*)(w);
        float* rs  = (float*)(w + szT);
        f16* qbuf = (f16*)(w + 2 * szT);
        f16* kbuf = (f16*)(w + 2 * szT + szQ);
        f16* vtb  = (f16*)(w + 2 * szT + 2 * szQ);
        f16* ctxb = (f16*)(w + 2 * szT + 3 * szQ);

        rope_table<<<(S_LEN * 16) / 256, 256, 0, stream>>>(rc, rs);
        proj_gemm<<<dim3(MROWS / 128, DMODEL / 128, 3), 256, 0, stream>>>(
            Q, K, V, Wq, Wk, Wv, bq, bk, bv, qbuf, kbuf, vtb, rc, rs);
        attn_fwd<<<dim3(S_LEN / 128, BATCH * NHEADS), 512, 0, stream>>>(qbuf, kbuf, vtb, ctxb);
        out_gemm<<<dim3(MROWS / 128, DMODEL / 128), 256, 0, stream>>>(ctxb, Wo, bo, out);
    }
}

// Round 19
// 146.166 us; speedup vs baseline: 2.8649x; 1.0299x over previous
//
#include <hip/hip_runtime.h>
#include <hip/hip_bf16.h>
#include <hip/hip_fp16.h>

#define S_LEN  2048
#define BATCH  2
#define DMODEL 1024
#define NHEADS 16
#define HD     64
#define MROWS  4096   // S*B
#define LD     72     // attn P LDS stride (padded, per-wave)
#define NT     (S_LEN / 64)

using f16 = _Float16;
typedef __attribute__((ext_vector_type(8))) _Float16 f16x8;
typedef __attribute__((ext_vector_type(4))) _Float16 f16x4;
typedef __attribute__((ext_vector_type(4))) float    f32x4;

// async global->LDS, 16B per lane; LDS dest = wave-uniform base + lane*16
__device__ __forceinline__ void gload16(const void* g, void* l)
{
    __builtin_amdgcn_global_load_lds((const __attribute__((address_space(1))) void*)g,
                                     (__attribute__((address_space(3))) void*)l, 16, 0, 0);
}

// ---------------- RoPE cos/sin table: [S][16] ----------------
__global__ __launch_bounds__(256) void rope_table(float* __restrict__ rc, float* __restrict__ rs)
{
    int idx = blockIdx.x * 256 + threadIdx.x;   // S*16 threads
    int s = idx >> 4, i = idx & 15;
    float inv = powf(10000.0f, -(float)(2 * i) / 32.0f);
    float ang = (float)s * inv;
    rc[idx] = cosf(ang);
    rs[idx] = sinf(ang);
}

// ---------------- fp32 -> f16 conversion: WEIGHTS ONLY (8 MiB out) ----------------
// dst segments (f16 elems): Wq 0, Wk 1048576, Wv 2097152, Wo 3145728
__global__ __launch_bounds__(256) void cvt_w(
    const float* __restrict__ Wq, const float* __restrict__ Wk,
    const float* __restrict__ Wv, const float* __restrict__ Wo, f16* __restrict__ dst)
{
    const int z = blockIdx.y;
    const float* src = (z == 0) ? Wq : (z == 1) ? Wk : (z == 2) ? Wv : Wo;
    const size_t off = (size_t)z * 1048576;
    int i = blockIdx.x * 256 + threadIdx.x;     // 512 blocks * 256 = 131072 octets exact
    const float4* s = reinterpret_cast<const float4*>(src) + (size_t)i * 2;
    float4 v0 = s[0], v1 = s[1];
    f16x8 h = { (f16)v0.x, (f16)v0.y, (f16)v0.z, (f16)v0.w,
                (f16)v1.x, (f16)v1.y, (f16)v1.z, (f16)v1.w };
    reinterpret_cast<f16x8*>(dst + off)[i] = h;
}

// ---------------- projection GEMM: fp32 X via gload_lds + cvt-on-read; f16 W ----------------
// A LDS: fp32 [128][32], slot-XOR swizzle (slot' = slot ^ (row&7), slot = 4-fp32 group).
// Pre-swizzled global source; fragment read applies same XOR then converts to f16.
// q scaled by (1/8)*log2(e); q,k stored (B,H,S,hd); v stored transposed (B,H,hd,S)
__global__ __launch_bounds__(256) void proj_gemm_h(
    const float* __restrict__ Xq, const float* __restrict__ Xk, const float* __restrict__ Xv,
    const f16* __restrict__ Wq, const f16* __restrict__ Wk, const f16* __restrict__ Wv,
    const float* __restrict__ bq, const float* __restrict__ bk, const float* __restrict__ bv,
    f16* __restrict__ qo, f16* __restrict__ ko, f16* __restrict__ vo,
    const float* __restrict__ rc, const float* __restrict__ rs)
{
    const int mode = blockIdx.z;            // 0=q 1=k 2=v
    const float* X   = (mode == 0) ? Xq : (mode == 1) ? Xk : Xv;
    const f16* W     = (mode == 0) ? Wq : (mode == 1) ? Wk : Wv;
    const float* bias = (mode == 0) ? bq : (mode == 1) ? bk : bv;

    __shared__ __align__(16) float Afp[128 * 32];   // 16 KiB
    __shared__ __align__(16) f16   Bl[128 * 32];    // 8 KiB

    const int t = threadIdx.x, lane = t & 63, wid = t >> 6;
    const int q15 = lane & 15, g = lane >> 4;
    const int wr = wid >> 1, wc = wid & 1;
    const int m0 = blockIdx.x * 128, n0 = blockIdx.y * 128;

    // A staging: 4 insts/wave, each covers 8 rows (8 fp32-slots of 4); source pre-swizzled
    const int srowA = wid * 32 + (lane >> 3);            // +8 per inst
    const int sslotA = (lane & 7) ^ (lane >> 3);         // row&7 == lane>>3
    const float* XgA = X + (size_t)(m0 + srowA) * DMODEL + sslotA * 4;
    float* aB0 = &Afp[(wid * 32 + 0) * 32];
    float* aB1 = &Afp[(wid * 32 + 8) * 32];
    float* aB2 = &Afp[(wid * 32 + 16) * 32];
    float* aB3 = &Afp[(wid * 32 + 24) * 32];

    // B staging: f16, 2 insts/wave (m97 pattern)
    const int srowB = wid * 16 + (lane >> 2);
    const int scolB = (lane & 3) * 8;
    const f16* Wg = W + (size_t)(n0 + srowB) * DMODEL + scolB;
    f16* bl0 = &Bl[(wid * 16) * 32];
    f16* bl1 = &Bl[(wid * 16 + 64) * 32];

    f32x4 acc[4][4];
    #pragma unroll
    for (int m = 0; m < 4; m++)
        #pragma unroll
        for (int n = 0; n < 4; n++)
            acc[m][n] = f32x4{0.f, 0.f, 0.f, 0.f};

    for (int k0 = 0; k0 < DMODEL; k0 += 32) {
        __syncthreads();
        gload16(XgA + k0, aB0);
        gload16(XgA + (size_t)8 * DMODEL + k0, aB1);
        gload16(XgA + (size_t)16 * DMODEL + k0, aB2);
        gload16(XgA + (size_t)24 * DMODEL + k0, aB3);
        gload16(Wg + k0, bl0);
        gload16(Wg + (size_t)64 * DMODEL + k0, bl1);
        __syncthreads();

        f16x8 a[4], b[4];
        const int p = q15 & 7;
        #pragma unroll
        for (int m = 0; m < 4; m++) {
            const float* ap = &Afp[(wr * 64 + m * 16 + q15) * 32];
            float4 v0 = *reinterpret_cast<const float4*>(&ap[((2 * g) ^ p) * 4]);
            float4 v1 = *reinterpret_cast<const float4*>(&ap[((2 * g + 1) ^ p) * 4]);
            a[m] = f16x8{ (f16)v0.x, (f16)v0.y, (f16)v0.z, (f16)v0.w,
                          (f16)v1.x, (f16)v1.y, (f16)v1.z, (f16)v1.w };
        }
        #pragma unroll
        for (int n = 0; n < 4; n++)
            b[n] = *reinterpret_cast<const f16x8*>(&Bl[(wc * 64 + n * 16 + q15) * 32 + g * 8]);
        #pragma unroll
        for (int m = 0; m < 4; m++)
            #pragma unroll
            for (int n = 0; n < 4; n++)
                acc[m][n] = __builtin_amdgcn_mfma_f32_16x16x32_f16(a[m], b[n], acc[m][n], 0, 0, 0);
    }

    const int rowb = m0 + wr * 64, colb = n0 + wc * 64;
    #pragma unroll
    for (int n = 0; n < 4; n++) {
        int cN = colb + n * 16 + q15;
        float bvv = bias[cN];
        int h = cN >> 6, d = cN & 63;
        #pragma unroll
        for (int m = 0; m < 4; m++) {
            #pragma unroll
            for (int rg = 0; rg < 4; rg++) {
                int r = rowb + m * 16 + g * 4 + rg;
                int s = r >> 1, bi = r & 1;
                float val = acc[m][n][rg] + bvv;
                if (mode < 2) {
                    float pv = __shfl_xor(val, 1);
                    if (d < 32) {
                        int fi = d >> 1;
                        float cc = rc[s * 16 + fi], ss = rs[s * 16 + fi];
                        val = ((d & 1) == 0) ? val * cc - pv * ss : val * cc + pv * ss;
                    }
                    if (mode == 0) val *= 0.18033688f;      // (1/8)*log2(e)
                    ((mode == 0) ? qo : ko)[(((size_t)bi * NHEADS + h) * S_LEN + s) * HD + d] = (f16)val;
                } else {
                    vo[(((size_t)bi * NHEADS + h) * HD + d) * S_LEN + s] = (f16)val;
                }
            }
        }
    }
}

// ---------------- f16-input output GEMM, global_load_lds staging ----------------
__global__ __launch_bounds__(256) void out_gemm_h(
    const f16* __restrict__ X, const f16* __restrict__ W,
    const float* __restrict__ bias, float* __restrict__ out)
{
    __shared__ __align__(16) f16 Al[128 * 32];
    __shared__ __align__(16) f16 Bl[128 * 32];

    const int t = threadIdx.x, lane = t & 63, wid = t >> 6;
    const int q15 = lane & 15, g = lane >> 4;
    const int wr = wid >> 1, wc = wid & 1;
    const int m0 = blockIdx.x * 128, n0 = blockIdx.y * 128;

    const int srow = wid * 16 + (lane >> 2);
    const int scol = (lane & 3) * 8;
    const f16* Xg = X + (size_t)(m0 + srow) * DMODEL + scol;
    const f16* Wg = W + (size_t)(n0 + srow) * DMODEL + scol;
    f16* al0 = &Al[(wid * 16) * 32];
    f16* al1 = &Al[(wid * 16 + 64) * 32];
    f16* bl0 = &Bl[(wid * 16) * 32];
    f16* bl1 = &Bl[(wid * 16 + 64) * 32];

    f32x4 acc[4][4];
    #pragma unroll
    for (int m = 0; m < 4; m++)
        #pragma unroll
        for (int n = 0; n < 4; n++)
            acc[m][n] = f32x4{0.f, 0.f, 0.f, 0.f};

    for (int k0 = 0; k0 < DMODEL; k0 += 32) {
        __syncthreads();
        gload16(Xg + k0, al0);
        gload16(Xg + (size_t)64 * DMODEL + k0, al1);
        gload16(Wg + k0, bl0);
        gload16(Wg + (size_t)64 * DMODEL + k0, bl1);
        __syncthreads();

        f16x8 a[4], b[4];
        #pragma unroll
        for (int m = 0; m < 4; m++)
            a[m] = *reinterpret_cast<const f16x8*>(&Al[(wr * 64 + m * 16 + q15) * 32 + g * 8]);
        #pragma unroll
        for (int n = 0; n < 4; n++)
            b[n] = *reinterpret_cast<const f16x8*>(&Bl[(wc * 64 + n * 16 + q15) * 32 + g * 8]);
        #pragma unroll
        for (int m = 0; m < 4; m++)
            #pragma unroll
            for (int n = 0; n < 4; n++)
                acc[m][n] = __builtin_amdgcn_mfma_f32_16x16x32_f16(a[m], b[n], acc[m][n], 0, 0, 0);
    }

    const int rowb = m0 + wr * 64, colb = n0 + wc * 64;
    #pragma unroll
    for (int n = 0; n < 4; n++) {
        int cN = colb + n * 16 + q15;
        float bvv = bias[cN];
        #pragma unroll
        for (int m = 0; m < 4; m++) {
            #pragma unroll
            for (int rg = 0; rg < 4; rg++) {
                int r = rowb + m * 16 + g * 4 + rg;
                out[(size_t)r * DMODEL + cN] = acc[m][n][rg] + bvv;
            }
        }
    }
}

// ---------------- FALLBACK: fp32-input projection GEMM (reg-staged) ----------------
__global__ __launch_bounds__(256) void proj_gemm(
    const float* __restrict__ Xq, const float* __restrict__ Xk, const float* __restrict__ Xv,
    const float* __restrict__ Wq, const float* __restrict__ Wk, const float* __restrict__ Wv,
    const float* __restrict__ bq, const float* __restrict__ bk, const float* __restrict__ bv,
    f16* __restrict__ qo, f16* __restrict__ ko, f16* __restrict__ vo,
    const float* __restrict__ rc, const float* __restrict__ rs)
{
    const int mode = blockIdx.z;
    const float* X    = (mode == 0) ? Xq : (mode == 1) ? Xk : Xv;
    const float* W    = (mode == 0) ? Wq : (mode == 1) ? Wk : Wv;
    const float* bias = (mode == 0) ? bq : (mode == 1) ? bk : bv;

    __shared__ f16 Al[128 * 40];
    __shared__ f16 Bl[128 * 40];

    const int t = threadIdx.x;
    const int lane = t & 63, wid = t >> 6;
    const int wr = wid >> 1, wc = wid & 1;
    const int m0 = blockIdx.x * 128, n0 = blockIdx.y * 128;

    f32x4 acc[4][4];
    #pragma unroll
    for (int m = 0; m < 4; m++)
        #pragma unroll
        for (int n = 0; n < 4; n++)
            acc[m][n] = f32x4{0.f, 0.f, 0.f, 0.f};

    for (int k0 = 0; k0 < DMODEL; k0 += 32) {
        __syncthreads();
        #pragma unroll
        for (int i = 0; i < 2; i++) {
            int e = (i * 256 + t) * 8;
            int r = e >> 5, c = e & 31;
            {
                const float* src = &X[(size_t)(m0 + r) * DMODEL + k0 + c];
                float4 v0 = *reinterpret_cast<const float4*>(src);
                float4 v1 = *reinterpret_cast<const float4*>(src + 4);
                f16x8 h = { (f16)v0.x, (f16)v0.y, (f16)v0.z, (f16)v0.w,
                            (f16)v1.x, (f16)v1.y, (f16)v1.z, (f16)v1.w };
                *reinterpret_cast<f16x8*>(&Al[r * 40 + c]) = h;
            }
            {
                const float* src = &W[(size_t)(n0 + r) * DMODEL + k0 + c];
                float4 v0 = *reinterpret_cast<const float4*>(src);
                float4 v1 = *reinterpret_cast<const float4*>(src + 4);
                f16x8 h = { (f16)v0.x, (f16)v0.y, (f16)v0.z, (f16)v0.w,
                            (f16)v1.x, (f16)v1.y, (f16)v1.z, (f16)v1.w };
                *reinterpret_cast<f16x8*>(&Bl[r * 40 + c]) = h;
            }
        }
        __syncthreads();
        f16x8 a[4], b[4];
        #pragma unroll
        for (int m = 0; m < 4; m++)
            a[m] = *reinterpret_cast<const f16x8*>(&Al[(wr * 64 + m * 16 + (lane & 15)) * 40 + (lane >> 4) * 8]);
        #pragma unroll
        for (int n = 0; n < 4; n++)
            b[n] = *reinterpret_cast<const f16x8*>(&Bl[(wc * 64 + n * 16 + (lane & 15)) * 40 + (lane >> 4) * 8]);
        #pragma unroll
        for (int m = 0; m < 4; m++)
            #pragma unroll
            for (int n = 0; n < 4; n++)
                acc[m][n] = __builtin_amdgcn_mfma_f32_16x16x32_f16(a[m], b[n], acc[m][n], 0, 0, 0);
    }

    const int rowb = m0 + wr * 64, colb = n0 + wc * 64;
    #pragma unroll
    for (int n = 0; n < 4; n++) {
        int cN = colb + n * 16 + (lane & 15);
        float bvv = bias[cN];
        int h = cN >> 6, d = cN & 63;
        #pragma unroll
        for (int m = 0; m < 4; m++) {
            #pragma unroll
            for (int rg = 0; rg < 4; rg++) {
                int r = rowb + m * 16 + (lane >> 4) * 4 + rg;
                int s = r >> 1, bi = r & 1;
                float val = acc[m][n][rg] + bvv;
                if (mode < 2) {
                    float pv = __shfl_xor(val, 1);
                    if (d < 32) {
                        int fi = d >> 1;
                        float cc = rc[s * 16 + fi], ss = rs[s * 16 + fi];
                        val = ((d & 1) == 0) ? val * cc - pv * ss : val * cc + pv * ss;
                    }
                    if (mode == 0) val *= 0.18033688f;
                    ((mode == 0) ? qo : ko)[(((size_t)bi * NHEADS + h) * S_LEN + s) * HD + d] = (f16)val;
                } else {
                    vo[(((size_t)bi * NHEADS + h) * HD + d) * S_LEN + s] = (f16)val;
                }
            }
        }
    }
}

// ---------------- FALLBACK: output projection ----------------
__global__ __launch_bounds__(256) void out_gemm(
    const f16* __restrict__ X, const float* __restrict__ W,
    const float* __restrict__ bias, float* __restrict__ out)
{
    __shared__ f16 Al[128 * 40];
    __shared__ f16 Bl[128 * 40];

    const int t = threadIdx.x;
    const int lane = t & 63, wid = t >> 6;
    const int wr = wid >> 1, wc = wid & 1;
    const int m0 = blockIdx.x * 128, n0 = blockIdx.y * 128;

    f32x4 acc[4][4];
    #pragma unroll
    for (int m = 0; m < 4; m++)
        #pragma unroll
        for (int n = 0; n < 4; n++)
            acc[m][n] = f32x4{0.f, 0.f, 0.f, 0.f};

    for (int k0 = 0; k0 < DMODEL; k0 += 32) {
        __syncthreads();
        #pragma unroll
        for (int i = 0; i < 2; i++) {
            int e = (i * 256 + t) * 8;
            int r = e >> 5, c = e & 31;
            *reinterpret_cast<uint4*>(&Al[r * 40 + c]) =
                *reinterpret_cast<const uint4*>(&X[(size_t)(m0 + r) * DMODEL + k0 + c]);
            {
                const float* src = &W[(size_t)(n0 + r) * DMODEL + k0 + c];
                float4 v0 = *reinterpret_cast<const float4*>(src);
                float4 v1 = *reinterpret_cast<const float4*>(src + 4);
                f16x8 h = { (f16)v0.x, (f16)v0.y, (f16)v0.z, (f16)v0.w,
                            (f16)v1.x, (f16)v1.y, (f16)v1.z, (f16)v1.w };
                *reinterpret_cast<f16x8*>(&Bl[r * 40 + c]) = h;
            }
        }
        __syncthreads();
        f16x8 a[4], b[4];
        #pragma unroll
        for (int m = 0; m < 4; m++)
            a[m] = *reinterpret_cast<const f16x8*>(&Al[(wr * 64 + m * 16 + (lane & 15)) * 40 + (lane >> 4) * 8]);
        #pragma unroll
        for (int n = 0; n < 4; n++)
            b[n] = *reinterpret_cast<const f16x8*>(&Bl[(wc * 64 + n * 16 + (lane & 15)) * 40 + (lane >> 4) * 8]);
        #pragma unroll
        for (int m = 0; m < 4; m++)
            #pragma unroll
            for (int n = 0; n < 4; n++)
                acc[m][n] = __builtin_amdgcn_mfma_f32_16x16x32_f16(a[m], b[n], acc[m][n], 0, 0, 0);
    }

    const int rowb = m0 + wr * 64, colb = n0 + wc * 64;
    #pragma unroll
    for (int n = 0; n < 4; n++) {
        int cN = colb + n * 16 + (lane & 15);
        float bvv = bias[cN];
        #pragma unroll
        for (int m = 0; m < 4; m++) {
            #pragma unroll
            for (int rg = 0; rg < 4; rg++) {
                int r = rowb + m * 16 + (lane >> 4) * 4 + rg;
                out[(size_t)r * DMODEL + cN] = acc[m][n][rg] + bvv;
            }
        }
    }
}

// ---------------- flash attention: deferred-PV pipeline (unchanged from r17) ----------------
__global__ __launch_bounds__(512) void attn_fwd(
    const f16* __restrict__ qb, const f16* __restrict__ kb,
    const f16* __restrict__ vt, f16* __restrict__ ctx)
{
    __shared__ f16 Kl[2][64 * 64];
    __shared__ f16 Vl[3][64 * 64];
    __shared__ f16 Pl[2][8 * 16 * LD];

    const int t = threadIdx.x, lane = t & 63, wid = t >> 6;
    const int q15 = lane & 15, g = lane >> 4;
    const int sw = q15 & 7;                 // read-side XOR key
    const int bh = blockIdx.y;
    const int q0 = blockIdx.x * 128 + wid * 16;

    const f16* qptr = qb + ((size_t)bh * S_LEN + q0) * HD;
    f16x8 qf0 = *reinterpret_cast<const f16x8*>(&qptr[q15 * HD + g * 8]);
    f16x8 qf1 = *reinterpret_cast<const f16x8*>(&qptr[q15 * HD + g * 8 + 32]);

    f32x4 ctxa[4];
    #pragma unroll
    for (int i = 0; i < 4; i++) ctxa[i] = f32x4{0.f, 0.f, 0.f, 0.f};
    float mrun = -3.0e38f, lrun = 0.f;

    const int srow = t >> 3;
    const int sslot = (t & 7) ^ (srow & 7);
    const f16* kg = kb + (size_t)bh * S_LEN * HD + (size_t)srow * HD + sslot * 8;
    const f16* vg = vt + (size_t)bh * HD * S_LEN + (size_t)srow * S_LEN + sslot * 8;
    const int lds_wbase = wid * 512;
    const int poff = wid * (16 * LD);

    gload16(kg, &Kl[0][lds_wbase]);
    gload16(vg, &Vl[0][lds_wbase]);
    __syncthreads();

    int kbuf = 0;
    int vprev = 2, vcur = 0, vnext = 1;

    for (int kt = 0; kt < NT; kt++) {
        if (kt + 1 < NT) {
            gload16(kg + (size_t)(kt + 1) * 64 * HD, &Kl[kbuf ^ 1][lds_wbase]);
            gload16(vg + (size_t)(kt + 1) * 64,      &Vl[vnext][lds_wbase]);
        }
        const f16* Kc = Kl[kbuf];

        f32x4 sc[4];
        __builtin_amdgcn_s_setprio(1);
        #pragma unroll
        for (int f = 0; f < 4; f++) {
            f16x8 kf0 = *reinterpret_cast<const f16x8*>(&Kc[(f * 16 + q15) * 64 + ((g ^ sw) * 8)]);
            f16x8 kf1 = *reinterpret_cast<const f16x8*>(&Kc[(f * 16 + q15) * 64 + (((g + 4) ^ sw) * 8)]);
            f32x4 z = {0.f, 0.f, 0.f, 0.f};
            z = __builtin_amdgcn_mfma_f32_16x16x32_f16(kf0, qf0, z, 0, 0, 0);
            sc[f] = __builtin_amdgcn_mfma_f32_16x16x32_f16(kf1, qf1, z, 0, 0, 0);
        }
        if (kt > 0) {
            const f16* Vp = Vl[vprev];
            const f16* pr = &Pl[(kt & 1) ^ 1][poff];
            #pragma unroll
            for (int c = 0; c < 2; c++) {
                f16x8 pfr = *reinterpret_cast<const f16x8*>(&pr[q15 * LD + g * 8 + c * 32]);
                #pragma unroll
                for (int n = 0; n < 4; n++) {
                    f16x8 vf = *reinterpret_cast<const f16x8*>(&Vp[(n * 16 + q15) * 64 + (((g + c * 4) ^ sw) * 8)]);
                    ctxa[n] = __builtin_amdgcn_mfma_f32_16x16x32_f16(vf, pfr, ctxa[n], 0, 0, 0);
                }
            }
        }
        __builtin_amdgcn_s_setprio(0);

        float pmf[4];
        #pragma unroll
        for (int f = 0; f < 4; f++)
            pmf[f] = fmaxf(fmaxf(sc[f][0], sc[f][1]), fmaxf(sc[f][2], sc[f][3]));
        float pm = fmaxf(fmaxf(pmf[0], pmf[1]), fmaxf(pmf[2], pmf[3]));
        if (!__all(pm - mrun <= 8.0f)) {
            float pmax = fmaxf(pm, __shfl_xor(pm, 16));
            pmax = fmaxf(pmax, __shfl_xor(pmax, 32));
            float mnew = fmaxf(mrun, pmax);
            float scale = __builtin_amdgcn_exp2f(mrun - mnew);
            lrun *= scale;
            #pragma unroll
            for (int n = 0; n < 4; n++) {
                ctxa[n][0] *= scale; ctxa[n][1] *= scale;
                ctxa[n][2] *= scale; ctxa[n][3] *= scale;
            }
            mrun = mnew;
        }
        float tsum = 0.f;
        #pragma unroll
        for (int f = 0; f < 4; f++)
            #pragma unroll
            for (int rg = 0; rg < 4; rg++) {
                float p = __builtin_amdgcn_exp2f(sc[f][rg] - mrun);
                sc[f][rg] = p;
                tsum += p;
            }
        lrun += tsum;

        f16* pw = &Pl[kt & 1][poff];
        #pragma unroll
        for (int f = 0; f < 4; f++) {
            f16x4 pwv = { (f16)sc[f][0], (f16)sc[f][1], (f16)sc[f][2], (f16)sc[f][3] };
            *reinterpret_cast<f16x4*>(&pw[q15 * LD + f * 16 + g * 4]) = pwv;
        }

        __syncthreads();
        kbuf ^= 1;
        int tmp = vprev; vprev = vcur; vcur = vnext; vnext = tmp;
    }

    // epilogue: PV(NT-1)
    {
        const f16* Vp = Vl[vprev];
        const f16* pr = &Pl[(NT - 1) & 1][poff];
        #pragma unroll
        for (int c = 0; c < 2; c++) {
            f16x8 pfr = *reinterpret_cast<const f16x8*>(&pr[q15 * LD + g * 8 + c * 32]);
            #pragma unroll
            for (int n = 0; n < 4; n++) {
                f16x8 vf = *reinterpret_cast<const f16x8*>(&Vp[(n * 16 + q15) * 64 + (((g + c * 4) ^ sw) * 8)]);
                ctxa[n] = __builtin_amdgcn_mfma_f32_16x16x32_f16(vf, pfr, ctxa[n], 0, 0, 0);
            }
        }
    }

    lrun += __shfl_xor(lrun, 16);
    lrun += __shfl_xor(lrun, 32);
    const int bi = bh >> 4, h = bh & 15;
    const int s = q0 + q15;
    float inv = 1.0f / lrun;
    f16* outp = &ctx[((size_t)s * BATCH + bi) * DMODEL + h * HD];
    #pragma unroll
    for (int n = 0; n < 4; n++) {
        f16x4 o = { (f16)(ctxa[n][0] * inv), (f16)(ctxa[n][1] * inv),
                    (f16)(ctxa[n][2] * inv), (f16)(ctxa[n][3] * inv) };
        *reinterpret_cast<f16x4*>(&outp[n * 16 + g * 4]) = o;
    }
}

// ---------------- launch ----------------
extern "C" void kernel_launch(void* const* d_in, const int* in_sizes, int n_in,
                              void* d_out, int out_size, void* d_ws, size_t ws_size,
                              hipStream_t stream)
{
    const float* Q  = (const float*)d_in[0];
    const float* K  = (const float*)d_in[1];
    const float* V  = (const float*)d_in[2];
    const float* Wq = (const float*)d_in[3];
    const float* bq = (const float*)d_in[4];
    const float* Wk = (const float*)d_in[5];
    const float* bk = (const float*)d_in[6];
    const float* Wv = (const float*)d_in[7];
    const float* bv = (const float*)d_in[8];
    const float* Wo = (const float*)d_in[9];
    const float* bo = (const float*)d_in[10];
    float* out = (float*)d_out;

    char* w = (char*)d_ws;
    const size_t MBc = 1024 * 1024;
    const size_t NEED_FAST = 40 * MBc + 256 * 1024;   // 40.25 MiB

    if (ws_size >= NEED_FAST) {
        // FAST layout:
        //   [0,8M)       f16 weights: Wq,Wk,Wv,Wo (2M ea)
        //   [8M,8.25M)   rc, rs
        //   [8.25M,40.25M) qbuf, kbuf, vtb, ctxb (8M ea)
        f16* Wqh = (f16*)w;
        f16* Wkh = Wqh + 1048576;
        f16* Wvh = Wqh + 2097152;
        f16* Woh = Wqh + 3145728;
        float* rc = (float*)(w + 8 * MBc);
        float* rs = rc + 32768;
        f16* qbuf = (f16*)(w + 8 * MBc + 256 * 1024);
        f16* kbuf = qbuf + 4194304;
        f16* vtb  = kbuf + 4194304;
        f16* ctxb = vtb + 4194304;

        rope_table<<<(S_LEN * 16) / 256, 256, 0, stream>>>(rc, rs);
        cvt_w<<<dim3(512, 4), 256, 0, stream>>>(Wq, Wk, Wv, Wo, Wqh);
        proj_gemm_h<<<dim3(MROWS / 128, DMODEL / 128, 3), 256, 0, stream>>>(
            Q, K, V, Wqh, Wkh, Wvh, bq, bk, bv, qbuf, kbuf, vtb, rc, rs);
        attn_fwd<<<dim3(S_LEN / 128, BATCH * NHEADS), 512, 0, stream>>>(qbuf, kbuf, vtb, ctxb);
        out_gemm_h<<<dim3(MROWS / 128, DMODEL / 128), 256, 0, stream>>>(ctxb, Woh, bo, out);
    } else {
        const size_t szT = (size_t)S_LEN * 16 * sizeof(float);
        const size_t szQ = (size_t)MROWS * DMODEL * sizeof(f16);
        float* rc  = (float*)(w);
        float* rs  = (float*)(w + szT);
        f16* qbuf = (f16*)(w + 2 * szT);
        f16* kbuf = (f16*)(w + 2 * szT + szQ);
        f16* vtb  = (f16*)(w + 2 * szT + 2 * szQ);
        f16* ctxb = (f16*)(w + 2 * szT + 3 * szQ);

        rope_table<<<(S_LEN * 16) / 256, 256, 0, stream>>>(rc, rs);
        proj_gemm<<<dim3(MROWS / 128, DMODEL / 128, 3), 256, 0, stream>>>(
            Q, K, V, Wq, Wk, Wv, bq, bk, bv, qbuf, kbuf, vtb, rc, rs);
        attn_fwd<<<dim3(S_LEN / 128, BATCH * NHEADS), 512, 0, stream>>>(qbuf, kbuf, vtb, ctxb);
        out_gemm<<<dim3(MROWS / 128, DMODEL / 128), 256, 0, stream>>>(ctxb, Wo, bo, out);
    }
}